// Round 9
// baseline (18945.358 us; speedup 1.0000x reference)
//
#include <hip/hip_runtime.h>

// ---------------------------------------------------------------------------
// RAE forward, split-f16 MFMA GEMMs + deterministic split-K.
//   v ~= hi + lo * 2^-12  (lo pre-scaled by 2^12)
//   C = A@W ~= Ah@Wh + (Al@Wh + Ah@Wl) * 2^-12   (3 MFMA products)
// Two GEMM kernels sharing the same proven per-wave structure (64x64 subtile,
// 2-phase LDS double-buffer, drain-after-compute):
//   gemm_split : 128x128 tile, 4 waves, 64KB static LDS  (R6-proven, untouched)
//   gemm_w256  : 128x256 tile, 8 waves, 96KB dynamic LDS (halves A-panel
//                staging traffic; used when N%256==0 && M>=512)
// The forward is staging-BW-bound (~81 GB at 128^2 tiles ~= 5 TB/s sustained);
// wide tiles cut ~19 GB.
// Failed experiments (do not repeat): A-in-registers (R5 -27%, R7 -330%:
// uncoalesced row-strided loads + VGPR pressure); split-K target 512/cap 16
// (R8 +4%).
// ---------------------------------------------------------------------------

typedef _Float16 f16;
typedef _Float16 half8 __attribute__((ext_vector_type(8)));
typedef float floatx4 __attribute__((ext_vector_type(4)));

#define LO_SC   4096.0f
#define LO_ISC  2.44140625e-4f

__device__ __forceinline__ void gld_lds16(const f16* g, f16* l) {
    __builtin_amdgcn_global_load_lds(
        (const __attribute__((address_space(1))) void*)g,
        (__attribute__((address_space(3))) void*)l, 16, 0, 0);
}

// --------------------- GEMM, 128x128 tile (R6-proven) -----------------------
// MODE 0: plain A. MODE 1: enc-cat (row b*Li+l; k>=kbound -> ts table).
// MODE 2: dec-cat. OUT 0: bias+pair; 1: bias+relu+pair; 2: bias+fp32;
// 3: f32 partial-slice (no bias).
template<int MODE, int OUT>
__global__ __launch_bounds__(256, 2) void gemm_split(
    const f16* __restrict__ Ahi, const f16* __restrict__ Alo, int lda,
    const f16* __restrict__ Whi, const f16* __restrict__ Wlo,   // [N][K] transposed
    const float* __restrict__ bias,
    f16* __restrict__ Chi, f16* __restrict__ Clo, float* __restrict__ Cf,
    float* __restrict__ Pf, int ksplit,
    int M, int N, int K, int Kpad, int kbound, int Lo, int Li,
    const f16* __restrict__ tsrow, const f16* __restrict__ zrow,
    int gy, int q, int r)
{
    __shared__ __align__(16) f16 sm[2][4][4][128][8];   // 64 KiB

    const int tid  = threadIdx.x;
    const int lane = tid & 63;
    const int wid  = tid >> 6;

    const int bid = blockIdx.x;
    const int xcd = bid & 7, jj = bid >> 3;
    const int rank = (xcd < r) ? xcd * (q + 1) + jj
                               : r * (q + 1) + (xcd - r) * q + jj;
    const int t  = rank / ksplit;
    const int kz = rank - t * ksplit;
    const int bx = t / gy, by = t - bx * gy;
    const int bm = by * 128;
    const int bn = bx * 128;

    const f16* aph[2]; const f16* apl[2];
    const f16* wph[2]; const f16* wpl[2];
    #pragma unroll
    for (int it = 0; it < 2; it++) {
        int rr = bm + it * 64 + lane;
        if (rr > M - 1) rr = M - 1;
        int arow;
        if (MODE == 1) { int b = rr / Lo; int l = rr - b * Lo; arow = b * Li + l; }
        else arow = rr;
        aph[it] = Ahi + (size_t)arow * lda;
        apl[it] = Alo + (size_t)arow * lda;
        int col = bn + it * 64 + lane;
        wph[it] = Whi + (size_t)col * K;
        wpl[it] = Wlo + (size_t)col * K;
    }

    const int kw0 = wid * 8;
    auto stage = [&](int buf, int k0) {
        const int ka = k0 + kw0;
        int kwc = ka; if (kwc > K - 8) kwc = K - 8;
        #pragma unroll
        for (int it = 0; it < 2; it++) {
            const f16* sh; const f16* sl;
            if (MODE == 0 || ka < kbound) { sh = aph[it] + ka; sl = apl[it] + ka; }
            else { sh = tsrow + (ka - kbound); sl = zrow; }
            gld_lds16(sh,            &sm[buf][0][wid][it * 64][0]);
            gld_lds16(sl,            &sm[buf][1][wid][it * 64][0]);
            gld_lds16(wph[it] + kwc, &sm[buf][2][wid][it * 64][0]);
            gld_lds16(wpl[it] + kwc, &sm[buf][3][wid][it * 64][0]);
        }
    };

    floatx4 acc1[4][4] = {};
    floatx4 acc2[4][4] = {};

    const int nst = Kpad >> 5;
    const int sps = (nst + ksplit - 1) / ksplit;
    const int s0  = kz * sps;
    int s1 = s0 + sps; if (s1 > nst) s1 = nst;

    const int kc = lane >> 4;
    const int fr = lane & 15;
    const int wr = (wid >> 1) * 64;
    const int wc = (wid & 1) * 64;

    if (s0 < s1) {
        stage(0, s0 << 5);
        __syncthreads();
        for (int s = s0; s < s1; s++) {
            const int buf = (s - s0) & 1;
            if (s + 1 < s1) stage(buf ^ 1, (s + 1) << 5);

            half8 ah[4], al[4], wh[4], wl[4];
            #pragma unroll
            for (int m = 0; m < 4; m++) {
                ah[m] = *(const half8*)&sm[buf][0][kc][wr + m * 16 + fr][0];
                al[m] = *(const half8*)&sm[buf][1][kc][wr + m * 16 + fr][0];
            }
            #pragma unroll
            for (int n = 0; n < 4; n++) {
                wh[n] = *(const half8*)&sm[buf][2][kc][wc + n * 16 + fr][0];
                wl[n] = *(const half8*)&sm[buf][3][kc][wc + n * 16 + fr][0];
            }
            #pragma unroll
            for (int m = 0; m < 4; m++)
                #pragma unroll
                for (int n = 0; n < 4; n++) {
                    acc1[m][n] = __builtin_amdgcn_mfma_f32_16x16x32_f16(ah[m], wh[n], acc1[m][n], 0, 0, 0);
                    acc2[m][n] = __builtin_amdgcn_mfma_f32_16x16x32_f16(al[m], wh[n], acc2[m][n], 0, 0, 0);
                    acc2[m][n] = __builtin_amdgcn_mfma_f32_16x16x32_f16(ah[m], wl[n], acc2[m][n], 0, 0, 0);
                }
            __syncthreads();
        }
    }

    const int q4 = (lane >> 4) * 4;
    const size_t MN = (size_t)M * N;
    #pragma unroll
    for (int n = 0; n < 4; n++) {
        const int gcol = bn + wc + n * 16 + fr;
        const float bv = (OUT == 3) ? 0.0f : bias[gcol];
        #pragma unroll
        for (int m = 0; m < 4; m++) {
            #pragma unroll
            for (int j = 0; j < 4; j++) {
                const int grow = bm + wr + m * 16 + q4 + j;
                if (grow < M) {
                    float v = acc1[m][n][j] + acc2[m][n][j] * LO_ISC + bv;
                    const size_t o = (size_t)grow * N + gcol;
                    if (OUT == 3) {
                        Pf[(size_t)kz * MN + o] = v;
                    } else if (OUT == 2) {
                        Cf[o] = v;
                    } else {
                        if (OUT == 1) v = fmaxf(v, 0.0f);
                        f16 h = (f16)v;
                        Chi[o] = h;
                        Clo[o] = (f16)((v - (float)h) * LO_SC);
                    }
                }
            }
        }
    }
}

// --------------------- GEMM, 128x256 tile (wide, 8 waves) -------------------
// Same per-wave structure; waves 0-3 stage A (kc=wid), waves 4-7 stage W
// (kc=wid-4). 96KB dynamic LDS -> 1 block/CU (2 waves/SIMD, same as narrow).
template<int MODE, int OUT>
__global__ __launch_bounds__(512, 1) void gemm_w256(
    const f16* __restrict__ Ahi, const f16* __restrict__ Alo, int lda,
    const f16* __restrict__ Whi, const f16* __restrict__ Wlo,
    const float* __restrict__ bias,
    f16* __restrict__ Chi, f16* __restrict__ Clo, float* __restrict__ Cf,
    float* __restrict__ Pf, int ksplit,
    int M, int N, int K, int Kpad, int kbound, int Lo, int Li,
    const f16* __restrict__ tsrow, const f16* __restrict__ zrow,
    int gy, int q, int r)
{
    extern __shared__ __align__(16) f16 dyn[];
    // sA: [buf][arr][kc][row 0..127][8] = 16384 f16 (32 KiB)
    // sW: [buf][arr][kc][col 0..255][8] = 32768 f16 (64 KiB)
    f16* sA = dyn;
    f16* sW = dyn + 16384;

    const int tid  = threadIdx.x;
    const int lane = tid & 63;
    const int wid  = tid >> 6;            // 0..7

    const int bid = blockIdx.x;
    const int xcd = bid & 7, jj = bid >> 3;
    const int rank = (xcd < r) ? xcd * (q + 1) + jj
                               : r * (q + 1) + (xcd - r) * q + jj;
    const int t  = rank / ksplit;
    const int kz = rank - t * ksplit;
    const int bx = t / gy, by = t - bx * gy;
    const int bm = by * 128;
    const int bn = bx * 256;

    const bool aw  = (wid < 4);           // wave-uniform role
    const int  skc = aw ? wid : (wid - 4);

    const f16* aph[2]; const f16* apl[2];
    const f16* wph[4]; const f16* wpl[4];
    if (aw) {
        #pragma unroll
        for (int it = 0; it < 2; it++) {
            int rr = bm + it * 64 + lane;
            if (rr > M - 1) rr = M - 1;
            int arow;
            if (MODE == 1) { int b = rr / Lo; int l = rr - b * Lo; arow = b * Li + l; }
            else arow = rr;
            aph[it] = Ahi + (size_t)arow * lda;
            apl[it] = Alo + (size_t)arow * lda;
        }
    } else {
        #pragma unroll
        for (int it = 0; it < 4; it++) {
            int col = bn + it * 64 + lane;        // N % 256 == 0 -> in range
            wph[it] = Whi + (size_t)col * K;
            wpl[it] = Wlo + (size_t)col * K;
        }
    }

    auto stage = [&](int buf, int k0) {
        const int ka = k0 + skc * 8;
        if (aw) {
            #pragma unroll
            for (int it = 0; it < 2; it++) {
                const f16* sh; const f16* sl;
                if (MODE == 0 || ka < kbound) { sh = aph[it] + ka; sl = apl[it] + ka; }
                else { sh = tsrow + (ka - kbound); sl = zrow; }
                gld_lds16(sh, &sA[((size_t)(buf * 2 + 0) * 4 + skc) * 1024 + (size_t)(it * 64) * 8]);
                gld_lds16(sl, &sA[((size_t)(buf * 2 + 1) * 4 + skc) * 1024 + (size_t)(it * 64) * 8]);
            }
        } else {
            int kwc = ka; if (kwc > K - 8) kwc = K - 8;
            #pragma unroll
            for (int it = 0; it < 4; it++) {
                gld_lds16(wph[it] + kwc, &sW[((size_t)(buf * 2 + 0) * 4 + skc) * 2048 + (size_t)(it * 64) * 8]);
                gld_lds16(wpl[it] + kwc, &sW[((size_t)(buf * 2 + 1) * 4 + skc) * 2048 + (size_t)(it * 64) * 8]);
            }
        }
    };

    floatx4 acc1[4][4] = {};
    floatx4 acc2[4][4] = {};

    const int nst = Kpad >> 5;
    const int sps = (nst + ksplit - 1) / ksplit;
    const int s0  = kz * sps;
    int s1 = s0 + sps; if (s1 > nst) s1 = nst;

    const int kc = lane >> 4;
    const int fr = lane & 15;
    const int wr = (wid >> 2) * 64;       // 0 or 64
    const int wc = (wid & 3) * 64;        // 0,64,128,192

    if (s0 < s1) {
        stage(0, s0 << 5);
        __syncthreads();
        for (int s = s0; s < s1; s++) {
            const int buf = (s - s0) & 1;
            if (s + 1 < s1) stage(buf ^ 1, (s + 1) << 5);

            half8 ah[4], al[4], wh[4], wl[4];
            #pragma unroll
            for (int m = 0; m < 4; m++) {
                ah[m] = *(const half8*)&sA[((size_t)(buf * 2 + 0) * 4 + kc) * 1024 + (size_t)(wr + m * 16 + fr) * 8];
                al[m] = *(const half8*)&sA[((size_t)(buf * 2 + 1) * 4 + kc) * 1024 + (size_t)(wr + m * 16 + fr) * 8];
            }
            #pragma unroll
            for (int n = 0; n < 4; n++) {
                wh[n] = *(const half8*)&sW[((size_t)(buf * 2 + 0) * 4 + kc) * 2048 + (size_t)(wc + n * 16 + fr) * 8];
                wl[n] = *(const half8*)&sW[((size_t)(buf * 2 + 1) * 4 + kc) * 2048 + (size_t)(wc + n * 16 + fr) * 8];
            }
            #pragma unroll
            for (int m = 0; m < 4; m++)
                #pragma unroll
                for (int n = 0; n < 4; n++) {
                    acc1[m][n] = __builtin_amdgcn_mfma_f32_16x16x32_f16(ah[m], wh[n], acc1[m][n], 0, 0, 0);
                    acc2[m][n] = __builtin_amdgcn_mfma_f32_16x16x32_f16(al[m], wh[n], acc2[m][n], 0, 0, 0);
                    acc2[m][n] = __builtin_amdgcn_mfma_f32_16x16x32_f16(ah[m], wl[n], acc2[m][n], 0, 0, 0);
                }
            __syncthreads();
        }
    }

    const int q4 = (lane >> 4) * 4;
    const size_t MN = (size_t)M * N;
    #pragma unroll
    for (int n = 0; n < 4; n++) {
        const int gcol = bn + wc + n * 16 + fr;
        const float bv = (OUT == 3) ? 0.0f : bias[gcol];
        #pragma unroll
        for (int m = 0; m < 4; m++) {
            #pragma unroll
            for (int j = 0; j < 4; j++) {
                const int grow = bm + wr + m * 16 + q4 + j;
                if (grow < M) {
                    float v = acc1[m][n][j] + acc2[m][n][j] * LO_ISC + bv;
                    const size_t o = (size_t)grow * N + gcol;
                    if (OUT == 3) {
                        Pf[(size_t)kz * MN + o] = v;
                    } else if (OUT == 2) {
                        Cf[o] = v;
                    } else {
                        if (OUT == 1) v = fmaxf(v, 0.0f);
                        f16 h = (f16)v;
                        Chi[o] = h;
                        Clo[o] = (f16)((v - (float)h) * LO_SC);
                    }
                }
            }
        }
    }
}

// ------- sum-of-slices + bias -> LayerNorm -> ReLU -> pair store ------------
__global__ void ln_pf(
    const float* __restrict__ P, size_t MN, int ksplit,
    const float* __restrict__ bias, int dual,
    const float* __restrict__ gw, const float* __restrict__ bw,
    f16* __restrict__ oh, f16* __restrict__ ol, int Wd)
{
    const int row = blockIdx.x;
    const size_t base = (size_t)row * Wd;
    const int i8 = threadIdx.x * 8;
    const float* bp = bias + (dual ? ((row & 1) << 10) : 0);

    float v[8];
    {
        const float4 a0 = *(const float4*)(P + base + i8);
        const float4 a1 = *(const float4*)(P + base + i8 + 4);
        v[0]=a0.x; v[1]=a0.y; v[2]=a0.z; v[3]=a0.w;
        v[4]=a1.x; v[5]=a1.y; v[6]=a1.z; v[7]=a1.w;
    }
    for (int z = 1; z < ksplit; z++) {
        const float* Pz = P + (size_t)z * MN + base + i8;
        const float4 c0 = *(const float4*)(Pz);
        const float4 c1 = *(const float4*)(Pz + 4);
        v[0]+=c0.x; v[1]+=c0.y; v[2]+=c0.z; v[3]+=c0.w;
        v[4]+=c1.x; v[5]+=c1.y; v[6]+=c1.z; v[7]+=c1.w;
    }
    float s = 0.f, s2 = 0.f;
    #pragma unroll
    for (int k = 0; k < 8; k++) {
        v[k] += bp[i8 + k];
        s += v[k]; s2 += v[k] * v[k];
    }
    #pragma unroll
    for (int o = 1; o < 64; o <<= 1) { s += __shfl_xor(s, o); s2 += __shfl_xor(s2, o); }
    __shared__ float red[2][4];
    const int nw = blockDim.x >> 6;
    if ((threadIdx.x & 63) == 0) { red[0][threadIdx.x >> 6] = s; red[1][threadIdx.x >> 6] = s2; }
    __syncthreads();
    s = 0.f; s2 = 0.f;
    for (int w = 0; w < nw; w++) { s += red[0][w]; s2 += red[1][w]; }
    const float inv = 1.0f / (float)Wd;
    const float mean = s * inv;
    const float rstd = rsqrtf(s2 * inv - mean * mean + 1e-5f);
    const float4 g0 = *(const float4*)(gw + i8), g1 = *(const float4*)(gw + i8 + 4);
    const float4 b0 = *(const float4*)(bw + i8), b1 = *(const float4*)(bw + i8 + 4);
    const float gg[8] = {g0.x, g0.y, g0.z, g0.w, g1.x, g1.y, g1.z, g1.w};
    const float bb[8] = {b0.x, b0.y, b0.z, b0.w, b1.x, b1.y, b1.z, b1.w};
    half8 ho, lo_;
    #pragma unroll
    for (int k = 0; k < 8; k++) {
        float y = fmaxf((v[k] - mean) * rstd * gg[k] + bb[k], 0.0f);
        f16 h = (f16)y;
        ho[k] = h; lo_[k] = (f16)((y - (float)h) * LO_SC);
    }
    *(half8*)(oh + base + i8) = ho;
    *(half8*)(ol + base + i8) = lo_;
}

// ----- decode combine from f32 partial G (+bias) -> LN -> ReLU -> pairs -----
__global__ void comb_pf(
    const float* __restrict__ P, size_t MN, int ksplit,
    const float* __restrict__ bias,   // dec_b2 [2048]
    const float* __restrict__ gw, const float* __restrict__ bw,
    f16* __restrict__ oh, f16* __restrict__ ol, int Liv)
{
    const int row = blockIdx.x;
    const int Lp = Liv + 1;
    const int b = row / Lp, j = row - b * Lp;
    const int i8 = threadIdx.x * 8;

    auto sum8 = [&](size_t off, float* acc) {
        const float4 a0 = *(const float4*)(P + off);
        const float4 a1 = *(const float4*)(P + off + 4);
        acc[0]=a0.x; acc[1]=a0.y; acc[2]=a0.z; acc[3]=a0.w;
        acc[4]=a1.x; acc[5]=a1.y; acc[6]=a1.z; acc[7]=a1.w;
        for (int z = 1; z < ksplit; z++) {
            const float* Pz = P + (size_t)z * MN + off;
            const float4 c0 = *(const float4*)(Pz);
            const float4 c1 = *(const float4*)(Pz + 4);
            acc[0]+=c0.x; acc[1]+=c0.y; acc[2]+=c0.z; acc[3]+=c0.w;
            acc[4]+=c1.x; acc[5]+=c1.y; acc[6]+=c1.z; acc[7]+=c1.w;
        }
    };

    float v[8];
    if (j == 0) {
        sum8((size_t)(b * Liv) * 2048 + i8, v);
        #pragma unroll
        for (int k = 0; k < 8; k++) v[k] += bias[i8 + k];
    } else if (j == Liv) {
        sum8((size_t)(b * Liv + Liv - 1) * 2048 + 1024 + i8, v);
        #pragma unroll
        for (int k = 0; k < 8; k++) v[k] += bias[1024 + i8 + k];
    } else {
        float u[8];
        sum8((size_t)(b * Liv + j - 1) * 2048 + 1024 + i8, v);
        sum8((size_t)(b * Liv + j) * 2048 + i8, u);
        #pragma unroll
        for (int k = 0; k < 8; k++)
            v[k] = 0.5f * ((v[k] + bias[1024 + i8 + k]) + (u[k] + bias[i8 + k]));
    }
    float s = 0.f, s2 = 0.f;
    #pragma unroll
    for (int k = 0; k < 8; k++) { s += v[k]; s2 += v[k] * v[k]; }
    #pragma unroll
    for (int o = 1; o < 64; o <<= 1) { s += __shfl_xor(s, o); s2 += __shfl_xor(s2, o); }
    __shared__ float red[2][2];
    if ((threadIdx.x & 63) == 0) { red[0][threadIdx.x >> 6] = s; red[1][threadIdx.x >> 6] = s2; }
    __syncthreads();
    s = red[0][0] + red[0][1]; s2 = red[1][0] + red[1][1];
    const float mean = s * 9.765625e-4f;
    const float rstd = rsqrtf(s2 * 9.765625e-4f - mean * mean + 1e-5f);
    const float4 g0 = *(const float4*)(gw + i8), g1 = *(const float4*)(gw + i8 + 4);
    const float4 b0 = *(const float4*)(bw + i8), b1 = *(const float4*)(bw + i8 + 4);
    const float gg[8] = {g0.x, g0.y, g0.z, g0.w, g1.x, g1.y, g1.z, g1.w};
    const float bb[8] = {b0.x, b0.y, b0.z, b0.w, b1.x, b1.y, b1.z, b1.w};
    const size_t ob = (size_t)row * 1024 + i8;
    half8 ho, lo_;
    #pragma unroll
    for (int k = 0; k < 8; k++) {
        float y = fmaxf((v[k] - mean) * rstd * gg[k] + bb[k], 0.0f);
        f16 h = (f16)y;
        ho[k] = h; lo_[k] = (f16)((y - (float)h) * LO_SC);
    }
    *(half8*)(oh + ob) = ho;
    *(half8*)(ol + ob) = lo_;
}

// ----------------- pair LayerNorm (tier-B encode path) ----------------------
__global__ void ln_pair_v(
    const f16* __restrict__ ih, const f16* __restrict__ il,
    f16* __restrict__ oh, f16* __restrict__ ol,
    const float* __restrict__ gw, const float* __restrict__ bw, int Wd)
{
    const size_t base = (size_t)blockIdx.x * Wd;
    const int i8 = threadIdx.x * 8;
    half8 hv = *(const half8*)(ih + base + i8);
    half8 lv = *(const half8*)(il + base + i8);
    float v[8], s = 0.f, s2 = 0.f;
    #pragma unroll
    for (int k = 0; k < 8; k++) {
        v[k] = (float)hv[k] + (float)lv[k] * LO_ISC;
        s += v[k]; s2 += v[k] * v[k];
    }
    #pragma unroll
    for (int o = 1; o < 64; o <<= 1) { s += __shfl_xor(s, o); s2 += __shfl_xor(s2, o); }
    __shared__ float red[2][4];
    const int nw = blockDim.x >> 6;
    if ((threadIdx.x & 63) == 0) { red[0][threadIdx.x >> 6] = s; red[1][threadIdx.x >> 6] = s2; }
    __syncthreads();
    s = 0.f; s2 = 0.f;
    for (int w = 0; w < nw; w++) { s += red[0][w]; s2 += red[1][w]; }
    const float inv = 1.0f / (float)Wd;
    const float mean = s * inv;
    const float rstd = rsqrtf(s2 * inv - mean * mean + 1e-5f);
    const float4 g0 = *(const float4*)(gw + i8), g1 = *(const float4*)(gw + i8 + 4);
    const float4 b0 = *(const float4*)(bw + i8), b1 = *(const float4*)(bw + i8 + 4);
    const float gg[8] = {g0.x, g0.y, g0.z, g0.w, g1.x, g1.y, g1.z, g1.w};
    const float bb[8] = {b0.x, b0.y, b0.z, b0.w, b1.x, b1.y, b1.z, b1.w};
    half8 ho, lo_;
    #pragma unroll
    for (int k = 0; k < 8; k++) {
        float y = fmaxf((v[k] - mean) * rstd * gg[k] + bb[k], 0.0f);
        f16 h = (f16)y;
        ho[k] = h; lo_[k] = (f16)((y - (float)h) * LO_SC);
    }
    *(half8*)(oh + base + i8) = ho;
    *(half8*)(ol + base + i8) = lo_;
}

// ---------------- weight transpose + split: W[K][N] -> Wt[N][K] -------------
__global__ __launch_bounds__(256) void wt_split_k(
    const float* __restrict__ W, f16* __restrict__ Th, f16* __restrict__ Tl,
    int K, int N)
{
    __shared__ float t[64][65];
    const int k0 = blockIdx.x * 64, n0 = blockIdx.y * 64;
    {
        const int j = threadIdx.x & 63, i0 = (threadIdx.x >> 6) * 16;
        for (int ii = 0; ii < 16; ii++) {
            int k = k0 + i0 + ii;
            t[i0 + ii][j] = (k < K) ? W[(size_t)k * N + n0 + j] : 0.f;
        }
    }
    __syncthreads();
    const int i = threadIdx.x & 63, j0 = (threadIdx.x >> 6) * 16;
    const int k = k0 + i;
    if (k < K) {
        for (int jj = 0; jj < 16; jj++) {
            float v = t[i][j0 + jj];
            f16 h = (f16)v;
            const size_t o = (size_t)(n0 + j0 + jj) * K + k;
            Th[o] = h;
            Tl[o] = (f16)((v - (float)h) * LO_SC);
        }
    }
}

// --------------------------- misc small kernels -----------------------------
__global__ void split_x_v(const float* __restrict__ x, f16* __restrict__ h,
                          f16* __restrict__ l, int n8) {
    int i = blockIdx.x * 256 + threadIdx.x;
    if (i >= n8) return;
    const int i8 = i * 8;
    const float4 f0 = *(const float4*)(x + i8), f1 = *(const float4*)(x + i8 + 4);
    const float vv[8] = {f0.x, f0.y, f0.z, f0.w, f1.x, f1.y, f1.z, f1.w};
    half8 ho, lo_;
    #pragma unroll
    for (int k = 0; k < 8; k++) {
        f16 hh = (f16)vv[k];
        ho[k] = hh; lo_[k] = (f16)((vv[k] - (float)hh) * LO_SC);
    }
    *(half8*)(h + i8) = ho;
    *(half8*)(l + i8) = lo_;
}

__global__ void ts_init_k(f16* __restrict__ ts, f16* __restrict__ z) {
    int e = blockIdx.x * 256 + threadIdx.x;
    if (e < 2048) {
        int rc = e >> 5, c = e & 31;
        float v = 0.f;
        if (rc >= 1) {
            int idx = (rc == 1) ? 1 : (rc == 2) ? 2 : (rc <= 4) ? 3 : ((rc + 10) / 3 - 1);
            if (c == 0) v = (float)rc;
            else if (c == idx) v = 1.f;
        }
        ts[e] = (f16)v;
    }
    if (e < 32) z[e] = (f16)0.f;
}

// ------------------------------ orchestration -------------------------------
extern "C" void kernel_launch(void* const* d_in, const int* in_sizes, int n_in,
                              void* d_out, int out_size, void* d_ws, size_t ws_size,
                              hipStream_t stream)
{
    const float* xin    = (const float*)d_in[0];
    const float* se_w1  = (const float*)d_in[1];
    const float* se_b1  = (const float*)d_in[2];
    const float* se_w2  = (const float*)d_in[3];
    const float* se_b2  = (const float*)d_in[4];
    const float* enc_w1 = (const float*)d_in[5];
    const float* enc_b1 = (const float*)d_in[6];
    const float* enc_g1 = (const float*)d_in[7];
    const float* enc_bb1= (const float*)d_in[8];
    const float* enc_w2 = (const float*)d_in[9];
    const float* enc_b2 = (const float*)d_in[10];
    const float* enc_g2 = (const float*)d_in[11];
    const float* enc_bb2= (const float*)d_in[12];
    const float* dec_w1 = (const float*)d_in[13];
    const float* dec_b1 = (const float*)d_in[14];
    const float* dec_g1 = (const float*)d_in[15];
    const float* dec_bb1= (const float*)d_in[16];
    const float* dec_w2 = (const float*)d_in[17];
    const float* dec_b2 = (const float*)d_in[18];
    const float* d2_g   = (const float*)d_in[19];
    const float* d2_b   = (const float*)d_in[20];
    const float* de_w1  = (const float*)d_in[21];
    const float* de_b1  = (const float*)d_in[22];
    const float* de_w2  = (const float*)d_in[23];
    const float* de_b2  = (const float*)d_in[24];

    const size_t ws_f16 = ws_size / 2;
    f16* ws = (f16*)d_ws;
    f16* Xh = ws;
    f16* Xl = Xh + 4194304;
    f16* WR = ws + (ws_f16 - 9512992);
    f16* TS = WR + 9510912;
    f16* ZB = TS + 2048;

    const size_t headA = 8388608ull + 12386304ull;
    const long long pcapA = (long long)(ws_f16 - 9512992 - headA) / 2;
    const bool tierA = pcapA >= 8257536ll;

    f16 *Hh, *Hl; float* PF; size_t pcap;
    f16* SC;
    if (tierA) {
        Hh = Xl + 4194304; Hl = Hh + 6193152;
        PF = (float*)(Hh + 12386304);
        pcap = (size_t)pcapA;
        SC = Hh;
    } else {
        Hh = Xl + 4194304;
        Hl = Hh + 6193152;
        PF = (float*)(Xl + 4194304 + 6193152);
        pcap = (14450688 - 6193152) / 2;
        SC = Xl + 4194304;
    }

    ts_init_k<<<8, 256, 0, stream>>>(TS, ZB);

    auto wt = [&](const float* W, int K, int N, f16* Th, f16* Tl) {
        wt_split_k<<<dim3((K + 63) / 64, N / 64), 256, 0, stream>>>(W, Th, Tl, K, N);
    };
    // R6 policy (448 / cap 8), grid width depends on wide-vs-narrow tile.
    auto pick_ks2 = [&](int M, int N, int nst, size_t MN) {
        const bool wide = ((N & 255) == 0) && (M >= 512);
        const int gx = N / (wide ? 256 : 128);
        const int gy = (M + 127) / 128;
        const int nat = gx * gy;
        const int target = wide ? 256 : 448;
        int ks = (nat >= target) ? 1 : (target + nat - 1) / nat;
        if (ks > 8) ks = 8;
        if (ks > nst) ks = nst;
        while (ks > 1 && (size_t)ks * MN > pcap) ks--;
        return ks;
    };

    #define GEMMX(MODE, OUT, Ah, Al, lda, Wh, Wl, bias, Ch, Cl, Cf, Pfp, ks, M, N, K, Kpad, kb, Lo, Li, tsr) \
        do { \
            const int gy_ = ((M) + 127) / 128;                                     \
            const bool wide_ = (((N) & 255) == 0) && ((M) >= 512);                 \
            if (wide_) {                                                           \
                const int nwg_ = ((N) / 256) * gy_ * (ks);                         \
                gemm_w256<MODE, OUT><<<nwg_, 512, 98304, stream>>>(                \
                    Ah, Al, lda, Wh, Wl, bias, Ch, Cl, Cf, Pfp, (ks),              \
                    M, N, K, Kpad, kb, Lo, Li, tsr, ZB, gy_, nwg_ >> 3, nwg_ & 7); \
            } else {                                                               \
                const int nwg_ = ((N) / 128) * gy_ * (ks);                         \
                gemm_split<MODE, OUT><<<nwg_, 256, 0, stream>>>(                   \
                    Ah, Al, lda, Wh, Wl, bias, Ch, Cl, Cf, Pfp, (ks),              \
                    M, N, K, Kpad, kb, Lo, Li, tsr, ZB, gy_, nwg_ >> 3, nwg_ & 7); \
            }                                                                      \
        } while (0)

    // ---- scale_embedding ----
    {
        f16* W1h = WR;            f16* W1l = W1h + 163840;
        f16* W2h = W1l + 163840;  f16* W2l = W2h + 655360;
        wt(se_w1, 256, 640, W1h, W1l);
        wt(se_w2, 640, 1024, W2h, W2l);
        f16* Sh  = SC;            f16* Sl  = SC + 1048576;
        f16* H1h = SC + 2097152;  f16* H1l = SC + 4718592;
        split_x_v<<<512, 256, 0, stream>>>(xin, Sh, Sl, 131072);
        GEMMX(0, 1, Sh, Sl, 256, W1h, W1l, se_b1, H1h, H1l, (float*)0, (float*)0, 1, 4096, 640, 256, 256, 256, 0, 0, ZB);
        GEMMX(0, 1, H1h, H1l, 640, W2h, W2l, se_b2, Xh, Xl, (float*)0, (float*)0, 1, 4096, 1024, 640, 640, 640, 0, 0, ZB);
    }

    // ---- encode ----
    {
        f16* E1h = WR;             f16* E1l = E1h + 3182592;
        f16* E2h = E1l + 3182592;  f16* E2l = E2h + 1572864;
        wt(enc_w1, 2072, 1536, E1h, E1l);
        wt(enc_w2, 1536, 1024, E2h, E2l);
        for (int rc = 1; rc <= 63; rc++) {
            const int Lo = 64 - rc, Li = Lo + 1, Mc = 64 * Lo;
            if (tierA) {
                const int k1 = pick_ks2(Mc, 1536, 65, (size_t)Mc * 1536);
                GEMMX(1, 3, Xh, Xl, 1024, E1h, E1l, enc_b1, (f16*)0, (f16*)0, (float*)0,
                      PF, k1, Mc, 1536, 2072, 2080, 2048, Lo, Li, TS + rc * 32);
                ln_pf<<<Mc, 192, 0, stream>>>(PF, (size_t)Mc * 1536, k1, enc_b1, 0,
                                              enc_g1, enc_bb1, Hh, Hl, 1536);
                const int k2 = pick_ks2(Mc, 1024, 48, (size_t)Mc * 1024);
                GEMMX(0, 3, Hh, Hl, 1536, E2h, E2l, enc_b2, (f16*)0, (f16*)0, (float*)0,
                      PF, k2, Mc, 1024, 1536, 1536, 1536, 0, 0, ZB);
                ln_pf<<<Mc, 128, 0, stream>>>(PF, (size_t)Mc * 1024, k2, enc_b2, 0,
                                              enc_g2, enc_bb2, Xh, Xl, 1024);
            } else {
                GEMMX(1, 0, Xh, Xl, 1024, E1h, E1l, enc_b1, Hh, Hl, (float*)0, (float*)0, 1,
                      Mc, 1536, 2072, 2080, 2048, Lo, Li, TS + rc * 32);
                ln_pair_v<<<Mc, 192, 0, stream>>>(Hh, Hl, Hh, Hl, enc_g1, enc_bb1, 1536);
                GEMMX(0, 0, Hh, Hl, 1536, E2h, E2l, enc_b2, Xh, Xl, (float*)0, (float*)0, 1,
                      Mc, 1024, 1536, 1536, 1536, 0, 0, ZB);
                ln_pair_v<<<Mc, 128, 0, stream>>>(Xh, Xl, Xh, Xl, enc_g2, enc_bb2, 1024);
            }
        }
    }

    // ---- decode ----
    {
        f16* D1h = WR;             f16* D1l = D1h + 1609728;
        f16* D2h = D1l + 1609728;  f16* D2l = D2h + 3145728;
        wt(dec_w1, 1048, 1536, D1h, D1l);
        wt(dec_w2, 1536, 2048, D2h, D2l);

        f16* Dh = tierA ? Hh : SC;
        f16* Dl = tierA ? Hl : SC + 3096576;

        // first step: [64,1024] -> [64,2048] -> LN over [128,1024] view
        {
            const int k1 = pick_ks2(64, 1536, 33, (size_t)64 * 1536);
            GEMMX(2, 3, Xh, Xl, 1024, D1h, D1l, dec_b1, (f16*)0, (f16*)0, (float*)0,
                  PF, k1, 64, 1536, 1048, 1056, 1024, 0, 0, TS + 63 * 32);
            ln_pf<<<64, 192, 0, stream>>>(PF, (size_t)64 * 1536, k1, dec_b1, 0,
                                          dec_g1, dec_bb1, Dh, Dl, 1536);
            const int k2 = pick_ks2(64, 2048, 48, (size_t)64 * 2048);
            GEMMX(0, 3, Dh, Dl, 1536, D2h, D2l, dec_b2, (f16*)0, (f16*)0, (float*)0,
                  PF, k2, 64, 2048, 1536, 1536, 1536, 0, 0, ZB);
            ln_pf<<<128, 128, 0, stream>>>(PF, (size_t)64 * 2048, k2, dec_b2, 1,
                                           d2_g, d2_b, Xh, Xl, 1024);
        }

        for (int rc = 62; rc >= 1; rc--) {
            const int Li = 64 - rc;
            const int nch = (!tierA && 64 * Li > 2016) ? 2 : 1, nb = 64 / nch;
            for (int c = nch - 1; c >= 0; c--) {
                const int b0 = c * nb, Mc = nb * Li;
                const size_t ai = (size_t)b0 * Li * 1024;
                const size_t oi = (size_t)b0 * (Li + 1) * 1024;
                const int k1 = pick_ks2(Mc, 1536, 33, (size_t)Mc * 1536);
                GEMMX(2, 3, Xh + ai, Xl + ai, 1024, D1h, D1l, dec_b1, (f16*)0, (f16*)0, (float*)0,
                      PF, k1, Mc, 1536, 1048, 1056, 1024, 0, 0, TS + rc * 32);
                ln_pf<<<Mc, 192, 0, stream>>>(PF, (size_t)Mc * 1536, k1, dec_b1, 0,
                                              dec_g1, dec_bb1, Dh, Dl, 1536);
                const int k2 = pick_ks2(Mc, 2048, 48, (size_t)Mc * 2048);
                GEMMX(0, 3, Dh, Dl, 1536, D2h, D2l, dec_b2, (f16*)0, (f16*)0, (float*)0,
                      PF, k2, Mc, 2048, 1536, 1536, 1536, 0, 0, ZB);
                comb_pf<<<nb * (Li + 1), 128, 0, stream>>>(
                    PF, (size_t)Mc * 2048, k2, dec_b2, d2_g, d2_b,
                    Xh + oi, Xl + oi, Li);
            }
        }
    }

    // ---- descale_embedding ----
    {
        f16* W1h = WR;            f16* W1l = W1h + 655360;
        f16* W2h = W1l + 655360;  f16* W2l = W2h + 163840;
        wt(de_w1, 1024, 640, W1h, W1l);
        wt(de_w2, 640, 256, W2h, W2l);
        f16* H1h = SC;            f16* H1l = SC + 2621440;
        GEMMX(0, 1, Xh, Xl, 1024, W1h, W1l, de_b1, H1h, H1l, (float*)0, (float*)0, 1,
              4096, 640, 1024, 1024, 1024, 0, 0, ZB);
        GEMMX(0, 2, H1h, H1l, 640, W2h, W2l, de_b2, (f16*)0, (f16*)0, (float*)d_out, (float*)0, 1,
              4096, 256, 640, 640, 640, 0, 0, ZB);
    }
    #undef GEMMX
}

// Round 10
// 16882.556 us; speedup vs baseline: 1.1222x; 1.1222x over previous
//
#include <hip/hip_runtime.h>

// ---------------------------------------------------------------------------
// RAE forward, split-f16 MFMA GEMMs (R6-proven inner loop) + deterministic
// split-K.  v ~= hi + lo * 2^-12  (lo pre-scaled by 2^12)
//   C = A@W ~= Ah@Wh + (Al@Wh + Ah@Wl) * 2^-12   (3 MFMA products)
// A and W both staged via global_load_lds, LDS double-buffered,
// drain-after-compute, 128x128 tile, 4 waves, 2 blocks/CU (cross-block
// overlap hides the drain). Split-K into P[kz][M][N] f32 slices summed in
// the LN/combine pass (deterministic, no atomics).
//
// FAILED-EXPERIMENT LEDGER (do not repeat):
//  - A streamed global->VGPR (R5: -27%, R7: -330%) — VGPR pressure/scratch,
//    redundant A loads; keep A in LDS via global_load_lds.
//  - split-K target 512 / cap 16 (R8: +4% slower) — keep 448 / cap 8.
//  - 128x256 tile, 8 waves, 96KB LDS (R9: +12% slower) — 1 block/CU loses
//    the cross-block drain overlap; keep 2 blocks/CU.
//  - LDS [kc][row][8] layout audited: bank-balanced (8 dwords/bank), no
//    swizzle needed.
// ---------------------------------------------------------------------------

typedef _Float16 f16;
typedef _Float16 half8 __attribute__((ext_vector_type(8)));
typedef float floatx4 __attribute__((ext_vector_type(4)));

#define LO_SC   4096.0f
#define LO_ISC  2.44140625e-4f

__device__ __forceinline__ void gld_lds16(const f16* g, f16* l) {
    __builtin_amdgcn_global_load_lds(
        (const __attribute__((address_space(1))) void*)g,
        (__attribute__((address_space(3))) void*)l, 16, 0, 0);
}

// ----------------------------- GEMM ----------------------------------------
// MODE 0: plain A. MODE 1: enc-cat (row b*Li+l; k>=kbound -> ts table).
// MODE 2: dec-cat (k>=kbound -> ts table).
// OUT 0: bias+pair store; OUT 1: bias+relu+pair; OUT 2: bias+fp32 store;
// OUT 3: f32 partial-slice store (no bias).
template<int MODE, int OUT>
__global__ __launch_bounds__(256, 2) void gemm_split(
    const f16* __restrict__ Ahi, const f16* __restrict__ Alo, int lda,
    const f16* __restrict__ Whi, const f16* __restrict__ Wlo,   // [N][K] transposed
    const float* __restrict__ bias,
    f16* __restrict__ Chi, f16* __restrict__ Clo, float* __restrict__ Cf,
    float* __restrict__ Pf, int ksplit,
    int M, int N, int K, int Kpad, int kbound, int Lo, int Li,
    const f16* __restrict__ tsrow, const f16* __restrict__ zrow,
    int gy, int q, int r)
{
    __shared__ __align__(16) f16 sm[2][4][4][128][8];   // 64 KiB

    const int tid  = threadIdx.x;
    const int lane = tid & 63;
    const int wid  = tid >> 6;

    // bijective XCD swizzle (m204); rank = (bx*gy + by)*ksplit + kz
    const int bid = blockIdx.x;
    const int xcd = bid & 7, jj = bid >> 3;
    const int rank = (xcd < r) ? xcd * (q + 1) + jj
                               : r * (q + 1) + (xcd - r) * q + jj;
    const int t  = rank / ksplit;
    const int kz = rank - t * ksplit;
    const int bx = t / gy, by = t - bx * gy;
    const int bm = by * 128;
    const int bn = bx * 128;

    // staging: wave `wid` fills kchunk = wid; slots it=0,1 -> row/col = it*64+lane
    const f16* aph[2]; const f16* apl[2];
    const f16* wph[2]; const f16* wpl[2];
    #pragma unroll
    for (int it = 0; it < 2; it++) {
        int rr = bm + it * 64 + lane;
        if (rr > M - 1) rr = M - 1;
        int arow;
        if (MODE == 1) { int b = rr / Lo; int l = rr - b * Lo; arow = b * Li + l; }
        else arow = rr;
        aph[it] = Ahi + (size_t)arow * lda;
        apl[it] = Alo + (size_t)arow * lda;
        int col = bn + it * 64 + lane;          // N % 128 == 0 -> in range
        wph[it] = Whi + (size_t)col * K;
        wpl[it] = Wlo + (size_t)col * K;
    }

    const int kw0 = wid * 8;
    auto stage = [&](int buf, int k0) {
        const int ka = k0 + kw0;
        int kwc = ka; if (kwc > K - 8) kwc = K - 8;   // W k-clamp (A side is 0 there)
        #pragma unroll
        for (int it = 0; it < 2; it++) {
            const f16* sh; const f16* sl;
            if (MODE == 0 || ka < kbound) { sh = aph[it] + ka; sl = apl[it] + ka; }
            else { sh = tsrow + (ka - kbound); sl = zrow; }
            gld_lds16(sh,            &sm[buf][0][wid][it * 64][0]);
            gld_lds16(sl,            &sm[buf][1][wid][it * 64][0]);
            gld_lds16(wph[it] + kwc, &sm[buf][2][wid][it * 64][0]);
            gld_lds16(wpl[it] + kwc, &sm[buf][3][wid][it * 64][0]);
        }
    };

    floatx4 acc1[4][4] = {};
    floatx4 acc2[4][4] = {};

    const int nst = Kpad >> 5;
    const int sps = (nst + ksplit - 1) / ksplit;
    const int s0  = kz * sps;
    int s1 = s0 + sps; if (s1 > nst) s1 = nst;

    const int kc = lane >> 4;
    const int fr = lane & 15;
    const int wr = (wid >> 1) * 64;
    const int wc = (wid & 1) * 64;

    if (s0 < s1) {
        stage(0, s0 << 5);
        __syncthreads();
        for (int s = s0; s < s1; s++) {
            const int buf = (s - s0) & 1;
            if (s + 1 < s1) stage(buf ^ 1, (s + 1) << 5);   // prefetch next tile

            half8 ah[4], al[4], wh[4], wl[4];
            #pragma unroll
            for (int m = 0; m < 4; m++) {
                ah[m] = *(const half8*)&sm[buf][0][kc][wr + m * 16 + fr][0];
                al[m] = *(const half8*)&sm[buf][1][kc][wr + m * 16 + fr][0];
            }
            #pragma unroll
            for (int n = 0; n < 4; n++) {
                wh[n] = *(const half8*)&sm[buf][2][kc][wc + n * 16 + fr][0];
                wl[n] = *(const half8*)&sm[buf][3][kc][wc + n * 16 + fr][0];
            }
            #pragma unroll
            for (int m = 0; m < 4; m++)
                #pragma unroll
                for (int n = 0; n < 4; n++) {
                    acc1[m][n] = __builtin_amdgcn_mfma_f32_16x16x32_f16(ah[m], wh[n], acc1[m][n], 0, 0, 0);
                    acc2[m][n] = __builtin_amdgcn_mfma_f32_16x16x32_f16(al[m], wh[n], acc2[m][n], 0, 0, 0);
                    acc2[m][n] = __builtin_amdgcn_mfma_f32_16x16x32_f16(ah[m], wl[n], acc2[m][n], 0, 0, 0);
                }
            __syncthreads();   // drain after compute: prefetch latency hidden
        }
    }

    // epilogue: C/D frag layout col = lane&15, row = (lane>>4)*4 + j
    const int q4 = (lane >> 4) * 4;
    const size_t MN = (size_t)M * N;
    #pragma unroll
    for (int n = 0; n < 4; n++) {
        const int gcol = bn + wc + n * 16 + fr;
        const float bv = (OUT == 3) ? 0.0f : bias[gcol];
        #pragma unroll
        for (int m = 0; m < 4; m++) {
            #pragma unroll
            for (int j = 0; j < 4; j++) {
                const int grow = bm + wr + m * 16 + q4 + j;
                if (grow < M) {
                    float v = acc1[m][n][j] + acc2[m][n][j] * LO_ISC + bv;
                    const size_t o = (size_t)grow * N + gcol;
                    if (OUT == 3) {
                        Pf[(size_t)kz * MN + o] = v;
                    } else if (OUT == 2) {
                        Cf[o] = v;
                    } else {
                        if (OUT == 1) v = fmaxf(v, 0.0f);
                        f16 h = (f16)v;
                        Chi[o] = h;
                        Clo[o] = (f16)((v - (float)h) * LO_SC);
                    }
                }
            }
        }
    }
}

// ------- sum-of-slices + bias -> LayerNorm -> ReLU -> pair store ------------
// block = Wd/8 threads (128 or 192). dual: bias += (row&1)*1024 (dec reshape).
__global__ void ln_pf(
    const float* __restrict__ P, size_t MN, int ksplit,
    const float* __restrict__ bias, int dual,
    const float* __restrict__ gw, const float* __restrict__ bw,
    f16* __restrict__ oh, f16* __restrict__ ol, int Wd)
{
    const int row = blockIdx.x;
    const size_t base = (size_t)row * Wd;
    const int i8 = threadIdx.x * 8;
    const float* bp = bias + (dual ? ((row & 1) << 10) : 0);

    float v[8];
    {
        const float4 a0 = *(const float4*)(P + base + i8);
        const float4 a1 = *(const float4*)(P + base + i8 + 4);
        v[0]=a0.x; v[1]=a0.y; v[2]=a0.z; v[3]=a0.w;
        v[4]=a1.x; v[5]=a1.y; v[6]=a1.z; v[7]=a1.w;
    }
    for (int z = 1; z < ksplit; z++) {
        const float* Pz = P + (size_t)z * MN + base + i8;
        const float4 c0 = *(const float4*)(Pz);
        const float4 c1 = *(const float4*)(Pz + 4);
        v[0]+=c0.x; v[1]+=c0.y; v[2]+=c0.z; v[3]+=c0.w;
        v[4]+=c1.x; v[5]+=c1.y; v[6]+=c1.z; v[7]+=c1.w;
    }
    float s = 0.f, s2 = 0.f;
    #pragma unroll
    for (int k = 0; k < 8; k++) {
        v[k] += bp[i8 + k];
        s += v[k]; s2 += v[k] * v[k];
    }
    #pragma unroll
    for (int o = 1; o < 64; o <<= 1) { s += __shfl_xor(s, o); s2 += __shfl_xor(s2, o); }
    __shared__ float red[2][4];
    const int nw = blockDim.x >> 6;
    if ((threadIdx.x & 63) == 0) { red[0][threadIdx.x >> 6] = s; red[1][threadIdx.x >> 6] = s2; }
    __syncthreads();
    s = 0.f; s2 = 0.f;
    for (int w = 0; w < nw; w++) { s += red[0][w]; s2 += red[1][w]; }
    const float inv = 1.0f / (float)Wd;
    const float mean = s * inv;
    const float rstd = rsqrtf(s2 * inv - mean * mean + 1e-5f);
    const float4 g0 = *(const float4*)(gw + i8), g1 = *(const float4*)(gw + i8 + 4);
    const float4 b0 = *(const float4*)(bw + i8), b1 = *(const float4*)(bw + i8 + 4);
    const float gg[8] = {g0.x, g0.y, g0.z, g0.w, g1.x, g1.y, g1.z, g1.w};
    const float bb[8] = {b0.x, b0.y, b0.z, b0.w, b1.x, b1.y, b1.z, b1.w};
    half8 ho, lo_;
    #pragma unroll
    for (int k = 0; k < 8; k++) {
        float y = fmaxf((v[k] - mean) * rstd * gg[k] + bb[k], 0.0f);
        f16 h = (f16)y;
        ho[k] = h; lo_[k] = (f16)((y - (float)h) * LO_SC);
    }
    *(half8*)(oh + base + i8) = ho;
    *(half8*)(ol + base + i8) = lo_;
}

// ----- decode combine from f32 partial G (+bias) -> LN -> ReLU -> pairs -----
// P slices hold G[Mc=nb*Liv rows][2048]; output rows nb*(Liv+1) x 1024 pairs.
__global__ void comb_pf(
    const float* __restrict__ P, size_t MN, int ksplit,
    const float* __restrict__ bias,   // dec_b2 [2048]
    const float* __restrict__ gw, const float* __restrict__ bw,
    f16* __restrict__ oh, f16* __restrict__ ol, int Liv)
{
    const int row = blockIdx.x;
    const int Lp = Liv + 1;
    const int b = row / Lp, j = row - b * Lp;
    const int i8 = threadIdx.x * 8;

    auto sum8 = [&](size_t off, float* acc) {
        const float4 a0 = *(const float4*)(P + off);
        const float4 a1 = *(const float4*)(P + off + 4);
        acc[0]=a0.x; acc[1]=a0.y; acc[2]=a0.z; acc[3]=a0.w;
        acc[4]=a1.x; acc[5]=a1.y; acc[6]=a1.z; acc[7]=a1.w;
        for (int z = 1; z < ksplit; z++) {
            const float* Pz = P + (size_t)z * MN + off;
            const float4 c0 = *(const float4*)(Pz);
            const float4 c1 = *(const float4*)(Pz + 4);
            acc[0]+=c0.x; acc[1]+=c0.y; acc[2]+=c0.z; acc[3]+=c0.w;
            acc[4]+=c1.x; acc[5]+=c1.y; acc[6]+=c1.z; acc[7]+=c1.w;
        }
    };

    float v[8];
    if (j == 0) {
        sum8((size_t)(b * Liv) * 2048 + i8, v);
        #pragma unroll
        for (int k = 0; k < 8; k++) v[k] += bias[i8 + k];
    } else if (j == Liv) {
        sum8((size_t)(b * Liv + Liv - 1) * 2048 + 1024 + i8, v);
        #pragma unroll
        for (int k = 0; k < 8; k++) v[k] += bias[1024 + i8 + k];
    } else {
        float u[8];
        sum8((size_t)(b * Liv + j - 1) * 2048 + 1024 + i8, v);
        sum8((size_t)(b * Liv + j) * 2048 + i8, u);
        #pragma unroll
        for (int k = 0; k < 8; k++)
            v[k] = 0.5f * ((v[k] + bias[1024 + i8 + k]) + (u[k] + bias[i8 + k]));
    }
    float s = 0.f, s2 = 0.f;
    #pragma unroll
    for (int k = 0; k < 8; k++) { s += v[k]; s2 += v[k] * v[k]; }
    #pragma unroll
    for (int o = 1; o < 64; o <<= 1) { s += __shfl_xor(s, o); s2 += __shfl_xor(s2, o); }
    __shared__ float red[2][2];
    if ((threadIdx.x & 63) == 0) { red[0][threadIdx.x >> 6] = s; red[1][threadIdx.x >> 6] = s2; }
    __syncthreads();
    s = red[0][0] + red[0][1]; s2 = red[1][0] + red[1][1];
    const float mean = s * 9.765625e-4f;
    const float rstd = rsqrtf(s2 * 9.765625e-4f - mean * mean + 1e-5f);
    const float4 g0 = *(const float4*)(gw + i8), g1 = *(const float4*)(gw + i8 + 4);
    const float4 b0 = *(const float4*)(bw + i8), b1 = *(const float4*)(bw + i8 + 4);
    const float gg[8] = {g0.x, g0.y, g0.z, g0.w, g1.x, g1.y, g1.z, g1.w};
    const float bb[8] = {b0.x, b0.y, b0.z, b0.w, b1.x, b1.y, b1.z, b1.w};
    const size_t ob = (size_t)row * 1024 + i8;
    half8 ho, lo_;
    #pragma unroll
    for (int k = 0; k < 8; k++) {
        float y = fmaxf((v[k] - mean) * rstd * gg[k] + bb[k], 0.0f);
        f16 h = (f16)y;
        ho[k] = h; lo_[k] = (f16)((y - (float)h) * LO_SC);
    }
    *(half8*)(oh + ob) = ho;
    *(half8*)(ol + ob) = lo_;
}

// ----------------- pair LayerNorm (tier-B encode path) ----------------------
__global__ void ln_pair_v(
    const f16* __restrict__ ih, const f16* __restrict__ il,
    f16* __restrict__ oh, f16* __restrict__ ol,
    const float* __restrict__ gw, const float* __restrict__ bw, int Wd)
{
    const size_t base = (size_t)blockIdx.x * Wd;
    const int i8 = threadIdx.x * 8;
    half8 hv = *(const half8*)(ih + base + i8);
    half8 lv = *(const half8*)(il + base + i8);
    float v[8], s = 0.f, s2 = 0.f;
    #pragma unroll
    for (int k = 0; k < 8; k++) {
        v[k] = (float)hv[k] + (float)lv[k] * LO_ISC;
        s += v[k]; s2 += v[k] * v[k];
    }
    #pragma unroll
    for (int o = 1; o < 64; o <<= 1) { s += __shfl_xor(s, o); s2 += __shfl_xor(s2, o); }
    __shared__ float red[2][4];
    const int nw = blockDim.x >> 6;
    if ((threadIdx.x & 63) == 0) { red[0][threadIdx.x >> 6] = s; red[1][threadIdx.x >> 6] = s2; }
    __syncthreads();
    s = 0.f; s2 = 0.f;
    for (int w = 0; w < nw; w++) { s += red[0][w]; s2 += red[1][w]; }
    const float inv = 1.0f / (float)Wd;
    const float mean = s * inv;
    const float rstd = rsqrtf(s2 * inv - mean * mean + 1e-5f);
    const float4 g0 = *(const float4*)(gw + i8), g1 = *(const float4*)(gw + i8 + 4);
    const float4 b0 = *(const float4*)(bw + i8), b1 = *(const float4*)(bw + i8 + 4);
    const float gg[8] = {g0.x, g0.y, g0.z, g0.w, g1.x, g1.y, g1.z, g1.w};
    const float bb[8] = {b0.x, b0.y, b0.z, b0.w, b1.x, b1.y, b1.z, b1.w};
    half8 ho, lo_;
    #pragma unroll
    for (int k = 0; k < 8; k++) {
        float y = fmaxf((v[k] - mean) * rstd * gg[k] + bb[k], 0.0f);
        f16 h = (f16)y;
        ho[k] = h; lo_[k] = (f16)((y - (float)h) * LO_SC);
    }
    *(half8*)(oh + base + i8) = ho;
    *(half8*)(ol + base + i8) = lo_;
}

// ---------------- weight transpose + split: W[K][N] -> Wt[N][K] -------------
__global__ __launch_bounds__(256) void wt_split_k(
    const float* __restrict__ W, f16* __restrict__ Th, f16* __restrict__ Tl,
    int K, int N)
{
    __shared__ float t[64][65];
    const int k0 = blockIdx.x * 64, n0 = blockIdx.y * 64;
    {
        const int j = threadIdx.x & 63, i0 = (threadIdx.x >> 6) * 16;
        for (int ii = 0; ii < 16; ii++) {
            int k = k0 + i0 + ii;
            t[i0 + ii][j] = (k < K) ? W[(size_t)k * N + n0 + j] : 0.f;
        }
    }
    __syncthreads();
    const int i = threadIdx.x & 63, j0 = (threadIdx.x >> 6) * 16;
    const int k = k0 + i;
    if (k < K) {
        for (int jj = 0; jj < 16; jj++) {
            float v = t[i][j0 + jj];
            f16 h = (f16)v;
            const size_t o = (size_t)(n0 + j0 + jj) * K + k;
            Th[o] = h;
            Tl[o] = (f16)((v - (float)h) * LO_SC);
        }
    }
}

// --------------------------- misc small kernels -----------------------------
__global__ void split_x_v(const float* __restrict__ x, f16* __restrict__ h,
                          f16* __restrict__ l, int n8) {
    int i = blockIdx.x * 256 + threadIdx.x;
    if (i >= n8) return;
    const int i8 = i * 8;
    const float4 f0 = *(const float4*)(x + i8), f1 = *(const float4*)(x + i8 + 4);
    const float vv[8] = {f0.x, f0.y, f0.z, f0.w, f1.x, f1.y, f1.z, f1.w};
    half8 ho, lo_;
    #pragma unroll
    for (int k = 0; k < 8; k++) {
        f16 hh = (f16)vv[k];
        ho[k] = hh; lo_[k] = (f16)((vv[k] - (float)hh) * LO_SC);
    }
    *(half8*)(h + i8) = ho;
    *(half8*)(l + i8) = lo_;
}

__global__ void ts_init_k(f16* __restrict__ ts, f16* __restrict__ z) {
    int e = blockIdx.x * 256 + threadIdx.x;
    if (e < 2048) {
        int rc = e >> 5, c = e & 31;
        float v = 0.f;
        if (rc >= 1) {
            int idx = (rc == 1) ? 1 : (rc == 2) ? 2 : (rc <= 4) ? 3 : ((rc + 10) / 3 - 1);
            if (c == 0) v = (float)rc;
            else if (c == idx) v = 1.f;
        }
        ts[e] = (f16)v;
    }
    if (e < 32) z[e] = (f16)0.f;
}

// ------------------------------ orchestration -------------------------------
extern "C" void kernel_launch(void* const* d_in, const int* in_sizes, int n_in,
                              void* d_out, int out_size, void* d_ws, size_t ws_size,
                              hipStream_t stream)
{
    const float* xin    = (const float*)d_in[0];
    const float* se_w1  = (const float*)d_in[1];
    const float* se_b1  = (const float*)d_in[2];
    const float* se_w2  = (const float*)d_in[3];
    const float* se_b2  = (const float*)d_in[4];
    const float* enc_w1 = (const float*)d_in[5];
    const float* enc_b1 = (const float*)d_in[6];
    const float* enc_g1 = (const float*)d_in[7];
    const float* enc_bb1= (const float*)d_in[8];
    const float* enc_w2 = (const float*)d_in[9];
    const float* enc_b2 = (const float*)d_in[10];
    const float* enc_g2 = (const float*)d_in[11];
    const float* enc_bb2= (const float*)d_in[12];
    const float* dec_w1 = (const float*)d_in[13];
    const float* dec_b1 = (const float*)d_in[14];
    const float* dec_g1 = (const float*)d_in[15];
    const float* dec_bb1= (const float*)d_in[16];
    const float* dec_w2 = (const float*)d_in[17];
    const float* dec_b2 = (const float*)d_in[18];
    const float* d2_g   = (const float*)d_in[19];
    const float* d2_b   = (const float*)d_in[20];
    const float* de_w1  = (const float*)d_in[21];
    const float* de_b1  = (const float*)d_in[22];
    const float* de_w2  = (const float*)d_in[23];
    const float* de_b2  = (const float*)d_in[24];

    // ------------- workspace layout (f16 units), tail-carved WR -------------
    const size_t ws_f16 = ws_size / 2;
    f16* ws = (f16*)d_ws;
    f16* Xh = ws;                                  // 4,194,304
    f16* Xl = Xh + 4194304;                        // 4,194,304
    f16* WR = ws + (ws_f16 - 9512992);             // 9,510,912 + TS/ZB
    f16* TS = WR + 9510912;
    f16* ZB = TS + 2048;

    // tier A: H pairs (12,386,304) + P region (>= 8,257,536 f32)
    const size_t headA = 8388608ull + 12386304ull;
    const long long pcapA = (long long)(ws_f16 - 9512992 - headA) / 2;
    const bool tierA = pcapA >= 8257536ll;         // 4032x2048 f32

    f16 *Hh, *Hl; float* PF; size_t pcap;
    f16* SC;                                        // scale/descale scratch
    if (tierA) {
        Hh = Xl + 4194304; Hl = Hh + 6193152;
        PF = (float*)(Hh + 12386304);
        pcap = (size_t)pcapA;
        SC = Hh;
    } else {
        Hh = Xl + 4194304;                          // encode: full H pairs
        Hl = Hh + 6193152;
        PF = (float*)(Xl + 4194304 + 6193152);      // decode: after chunked Hc
        pcap = (14450688 - 6193152) / 2;            // 4,128,768 f32
        SC = Xl + 4194304;
    }

    ts_init_k<<<8, 256, 0, stream>>>(TS, ZB);

    auto wt = [&](const float* W, int K, int N, f16* Th, f16* Tl) {
        wt_split_k<<<dim3((K + 63) / 64, N / 64), 256, 0, stream>>>(W, Th, Tl, K, N);
    };
    auto pick_ks = [&](int natural, int nst, size_t MN) {
        int ks = (natural >= 448) ? 1 : (448 + natural - 1) / natural;
        if (ks > 8) ks = 8;
        if (ks > nst) ks = nst;
        while (ks > 1 && (size_t)ks * MN > pcap) ks--;
        return ks;
    };

    #define GEMM(MODE, OUT, Ah, Al, lda, Wh, Wl, bias, Ch, Cl, Cf, Pfp, ks, M, N, K, Kpad, kb, Lo, Li, tsr) \
        do { \
            const int gx_ = (N) / 128, gy_ = ((M) + 127) / 128;                \
            const int nwg_ = gx_ * gy_ * (ks);                                 \
            gemm_split<MODE, OUT><<<nwg_, 256, 0, stream>>>(                   \
                Ah, Al, lda, Wh, Wl, bias, Ch, Cl, Cf, Pfp, (ks),              \
                M, N, K, Kpad, kb, Lo, Li, tsr, ZB, gy_, nwg_ >> 3, nwg_ & 7); \
        } while (0)

    // ---- scale_embedding ----
    {
        f16* W1h = WR;            f16* W1l = W1h + 163840;
        f16* W2h = W1l + 163840;  f16* W2l = W2h + 655360;
        wt(se_w1, 256, 640, W1h, W1l);
        wt(se_w2, 640, 1024, W2h, W2l);
        f16* Sh  = SC;            f16* Sl  = SC + 1048576;
        f16* H1h = SC + 2097152;  f16* H1l = SC + 4718592;
        split_x_v<<<512, 256, 0, stream>>>(xin, Sh, Sl, 131072);
        GEMM(0, 1, Sh, Sl, 256, W1h, W1l, se_b1, H1h, H1l, (float*)0, (float*)0, 1, 4096, 640, 256, 256, 256, 0, 0, ZB);
        GEMM(0, 1, H1h, H1l, 640, W2h, W2l, se_b2, Xh, Xl, (float*)0, (float*)0, 1, 4096, 1024, 640, 640, 640, 0, 0, ZB);
    }

    // ---- encode ----
    {
        f16* E1h = WR;             f16* E1l = E1h + 3182592;
        f16* E2h = E1l + 3182592;  f16* E2l = E2h + 1572864;
        wt(enc_w1, 2072, 1536, E1h, E1l);
        wt(enc_w2, 1536, 1024, E2h, E2l);
        for (int rc = 1; rc <= 63; rc++) {
            const int Lo = 64 - rc, Li = Lo + 1, Mc = 64 * Lo;
            if (tierA) {
                const int g1 = 12 * ((Mc + 127) / 128);
                const int k1 = pick_ks(g1, 65, (size_t)Mc * 1536);
                GEMM(1, 3, Xh, Xl, 1024, E1h, E1l, enc_b1, (f16*)0, (f16*)0, (float*)0,
                     PF, k1, Mc, 1536, 2072, 2080, 2048, Lo, Li, TS + rc * 32);
                ln_pf<<<Mc, 192, 0, stream>>>(PF, (size_t)Mc * 1536, k1, enc_b1, 0,
                                              enc_g1, enc_bb1, Hh, Hl, 1536);
                const int g2 = 8 * ((Mc + 127) / 128);
                const int k2 = pick_ks(g2, 48, (size_t)Mc * 1024);
                GEMM(0, 3, Hh, Hl, 1536, E2h, E2l, enc_b2, (f16*)0, (f16*)0, (float*)0,
                     PF, k2, Mc, 1024, 1536, 1536, 1536, 0, 0, ZB);
                ln_pf<<<Mc, 128, 0, stream>>>(PF, (size_t)Mc * 1024, k2, enc_b2, 0,
                                              enc_g2, enc_bb2, Xh, Xl, 1024);
            } else {
                GEMM(1, 0, Xh, Xl, 1024, E1h, E1l, enc_b1, Hh, Hl, (float*)0, (float*)0, 1,
                     Mc, 1536, 2072, 2080, 2048, Lo, Li, TS + rc * 32);
                ln_pair_v<<<Mc, 192, 0, stream>>>(Hh, Hl, Hh, Hl, enc_g1, enc_bb1, 1536);
                GEMM(0, 0, Hh, Hl, 1536, E2h, E2l, enc_b2, Xh, Xl, (float*)0, (float*)0, 1,
                     Mc, 1024, 1536, 1536, 1536, 0, 0, ZB);
                ln_pair_v<<<Mc, 128, 0, stream>>>(Xh, Xl, Xh, Xl, enc_g2, enc_bb2, 1024);
            }
        }
    }

    // ---- decode ----
    {
        f16* D1h = WR;             f16* D1l = D1h + 1609728;
        f16* D2h = D1l + 1609728;  f16* D2l = D2h + 3145728;
        wt(dec_w1, 1048, 1536, D1h, D1l);
        wt(dec_w2, 1536, 2048, D2h, D2l);

        f16* Dh = tierA ? Hh : SC;
        f16* Dl = tierA ? Hl : SC + 3096576;

        // first step: [64,1024] -> [64,2048] -> LN over [128,1024] view
        {
            const int k1 = pick_ks(12, 33, (size_t)64 * 1536);
            GEMM(2, 3, Xh, Xl, 1024, D1h, D1l, dec_b1, (f16*)0, (f16*)0, (float*)0,
                 PF, k1, 64, 1536, 1048, 1056, 1024, 0, 0, TS + 63 * 32);
            ln_pf<<<64, 192, 0, stream>>>(PF, (size_t)64 * 1536, k1, dec_b1, 0,
                                          dec_g1, dec_bb1, Dh, Dl, 1536);
            const int k2 = pick_ks(16, 48, (size_t)64 * 2048);
            GEMM(0, 3, Dh, Dl, 1536, D2h, D2l, dec_b2, (f16*)0, (f16*)0, (float*)0,
                 PF, k2, 64, 2048, 1536, 1536, 1536, 0, 0, ZB);
            // 64x2048 flat == 128x1024 flat; dual-bias by row parity
            ln_pf<<<128, 128, 0, stream>>>(PF, (size_t)64 * 2048, k2, dec_b2, 1,
                                           d2_g, d2_b, Xh, Xl, 1024);
        }

        for (int rc = 62; rc >= 1; rc--) {
            const int Li = 64 - rc;
            const int nch = (!tierA && 64 * Li > 2016) ? 2 : 1, nb = 64 / nch;
            for (int c = nch - 1; c >= 0; c--) {        // high batches first
                const int b0 = c * nb, Mc = nb * Li;
                const size_t ai = (size_t)b0 * Li * 1024;
                const size_t oi = (size_t)b0 * (Li + 1) * 1024;
                const int g1 = 12 * ((Mc + 127) / 128);
                const int k1 = pick_ks(g1, 33, (size_t)Mc * 1536);
                GEMM(2, 3, Xh + ai, Xl + ai, 1024, D1h, D1l, dec_b1, (f16*)0, (f16*)0, (float*)0,
                     PF, k1, Mc, 1536, 1048, 1056, 1024, 0, 0, TS + rc * 32);
                ln_pf<<<Mc, 192, 0, stream>>>(PF, (size_t)Mc * 1536, k1, dec_b1, 0,
                                              dec_g1, dec_bb1, Dh, Dl, 1536);
                const int g2 = 16 * ((Mc + 127) / 128);
                const int k2 = pick_ks(g2, 48, (size_t)Mc * 2048);
                GEMM(0, 3, Dh, Dl, 1536, D2h, D2l, dec_b2, (f16*)0, (f16*)0, (float*)0,
                     PF, k2, Mc, 2048, 1536, 1536, 1536, 0, 0, ZB);
                comb_pf<<<nb * (Li + 1), 128, 0, stream>>>(
                    PF, (size_t)Mc * 2048, k2, dec_b2, d2_g, d2_b,
                    Xh + oi, Xl + oi, Li);
            }
        }
    }

    // ---- descale_embedding ----
    {
        f16* W1h = WR;            f16* W1l = W1h + 655360;
        f16* W2h = W1l + 655360;  f16* W2l = W2h + 163840;
        wt(de_w1, 1024, 640, W1h, W1l);
        wt(de_w2, 640, 256, W2h, W2l);
        f16* H1h = SC;            f16* H1l = SC + 2621440;
        GEMM(0, 1, Xh, Xl, 1024, W1h, W1l, de_b1, H1h, H1l, (float*)0, (float*)0, 1,
             4096, 640, 1024, 1024, 1024, 0, 0, ZB);
        GEMM(0, 2, H1h, H1l, 640, W2h, W2l, de_b2, (f16*)0, (f16*)0, (float*)d_out, (float*)0, 1,
             4096, 256, 640, 640, 640, 0, 0, ZB);
    }
    #undef GEMM
}

// Round 11
// 13214.546 us; speedup vs baseline: 1.4337x; 1.2776x over previous
//
#include <hip/hip_runtime.h>

// ---------------------------------------------------------------------------
// RAE forward, 2-product split-f16 MFMA GEMMs + deterministic split-K.
// Weights: W ~= Wh + Wl*2^-12 (f16 pair). Activations: single f16.
//   C = A@W ~= A@Wh + (A@Wl)*2^-12   (2 MFMA products)
// Error: A carried in f16 (2^-12 rel, per-step-varying -> random-walk across
// layers); W near-f32. R10's 3-product version measured absmax 0.00195
// (= bf16 compare floor) with threshold 0.01023 -> headroom spent here.
// GEMM structure byte-identical to R6: 128x128 tile, 4 waves, A+W via
// global_load_lds, LDS double-buffer (48KB), drain-after-compute,
// 2 blocks/CU, split-K into P[kz][M][N] f32 summed in LN pass.
//
// FAILED-EXPERIMENT LEDGER (do not repeat):
//  - A streamed global->VGPR (R5: -27%, R7: -330%)
//  - split-K target 512 / cap 16 (R8: +4% slower) — keep 448 / cap 8
//  - 128x256 tile, 8 waves, 96KB LDS (R9: +12% slower) — 1 block/CU loses
//    cross-block drain overlap
//  - LDS [kc][row][8] layout: bank-balanced, no swizzle needed
// ---------------------------------------------------------------------------

typedef _Float16 f16;
typedef _Float16 half8 __attribute__((ext_vector_type(8)));
typedef float floatx4 __attribute__((ext_vector_type(4)));

#define LO_SC   4096.0f
#define LO_ISC  2.44140625e-4f

__device__ __forceinline__ void gld_lds16(const f16* g, f16* l) {
    __builtin_amdgcn_global_load_lds(
        (const __attribute__((address_space(1))) void*)g,
        (__attribute__((address_space(3))) void*)l, 16, 0, 0);
}

// ----------------------------- GEMM ----------------------------------------
// MODE 0: plain A. MODE 1: enc-cat (row b*Li+l; k>=kbound -> ts table).
// MODE 2: dec-cat (k>=kbound -> ts table).
// OUT 1: bias+relu+f16 store; OUT 2: bias+fp32 store; OUT 3: f32 partial
// slice store (no bias).
template<int MODE, int OUT>
__global__ __launch_bounds__(256, 2) void gemm_s2(
    const f16* __restrict__ Ahi, int lda,
    const f16* __restrict__ Whi, const f16* __restrict__ Wlo,   // [N][K] transposed
    const float* __restrict__ bias,
    f16* __restrict__ Chi, float* __restrict__ Cf,
    float* __restrict__ Pf, int ksplit,
    int M, int N, int K, int Kpad, int kbound, int Lo, int Li,
    const f16* __restrict__ tsrow,
    int gy, int q, int r)
{
    // [buf][arr: A,Wh,Wl][kchunk][row][8]  -> 48 KiB
    __shared__ __align__(16) f16 sm[2][3][4][128][8];

    const int tid  = threadIdx.x;
    const int lane = tid & 63;
    const int wid  = tid >> 6;

    // bijective XCD swizzle (m204); rank = (bx*gy + by)*ksplit + kz
    const int bid = blockIdx.x;
    const int xcd = bid & 7, jj = bid >> 3;
    const int rank = (xcd < r) ? xcd * (q + 1) + jj
                               : r * (q + 1) + (xcd - r) * q + jj;
    const int t  = rank / ksplit;
    const int kz = rank - t * ksplit;
    const int bx = t / gy, by = t - bx * gy;
    const int bm = by * 128;
    const int bn = bx * 128;

    // staging: wave `wid` fills kchunk = wid; slots it=0,1 -> row/col = it*64+lane
    const f16* aph[2];
    const f16* wph[2]; const f16* wpl[2];
    #pragma unroll
    for (int it = 0; it < 2; it++) {
        int rr = bm + it * 64 + lane;
        if (rr > M - 1) rr = M - 1;
        int arow;
        if (MODE == 1) { int b = rr / Lo; int l = rr - b * Lo; arow = b * Li + l; }
        else arow = rr;
        aph[it] = Ahi + (size_t)arow * lda;
        int col = bn + it * 64 + lane;          // N % 128 == 0 -> in range
        wph[it] = Whi + (size_t)col * K;
        wpl[it] = Wlo + (size_t)col * K;
    }

    const int kw0 = wid * 8;
    auto stage = [&](int buf, int k0) {
        const int ka = k0 + kw0;
        int kwc = ka; if (kwc > K - 8) kwc = K - 8;   // W k-clamp (A side is 0 there)
        #pragma unroll
        for (int it = 0; it < 2; it++) {
            const f16* sh;
            if (MODE == 0 || ka < kbound) sh = aph[it] + ka;
            else                          sh = tsrow + (ka - kbound);
            gld_lds16(sh,            &sm[buf][0][wid][it * 64][0]);
            gld_lds16(wph[it] + kwc, &sm[buf][1][wid][it * 64][0]);
            gld_lds16(wpl[it] + kwc, &sm[buf][2][wid][it * 64][0]);
        }
    };

    floatx4 acc1[4][4] = {};
    floatx4 acc2[4][4] = {};

    const int nst = Kpad >> 5;
    const int sps = (nst + ksplit - 1) / ksplit;
    const int s0  = kz * sps;
    int s1 = s0 + sps; if (s1 > nst) s1 = nst;

    const int kc = lane >> 4;
    const int fr = lane & 15;
    const int wr = (wid >> 1) * 64;
    const int wc = (wid & 1) * 64;

    if (s0 < s1) {
        stage(0, s0 << 5);
        __syncthreads();
        for (int s = s0; s < s1; s++) {
            const int buf = (s - s0) & 1;
            if (s + 1 < s1) stage(buf ^ 1, (s + 1) << 5);   // prefetch next tile

            half8 ah[4], wh[4], wl[4];
            #pragma unroll
            for (int m = 0; m < 4; m++)
                ah[m] = *(const half8*)&sm[buf][0][kc][wr + m * 16 + fr][0];
            #pragma unroll
            for (int n = 0; n < 4; n++) {
                wh[n] = *(const half8*)&sm[buf][1][kc][wc + n * 16 + fr][0];
                wl[n] = *(const half8*)&sm[buf][2][kc][wc + n * 16 + fr][0];
            }
            #pragma unroll
            for (int m = 0; m < 4; m++)
                #pragma unroll
                for (int n = 0; n < 4; n++) {
                    acc1[m][n] = __builtin_amdgcn_mfma_f32_16x16x32_f16(ah[m], wh[n], acc1[m][n], 0, 0, 0);
                    acc2[m][n] = __builtin_amdgcn_mfma_f32_16x16x32_f16(ah[m], wl[n], acc2[m][n], 0, 0, 0);
                }
            __syncthreads();   // drain after compute: prefetch latency hidden
        }
    }

    // epilogue: C/D frag layout col = lane&15, row = (lane>>4)*4 + j
    const int q4 = (lane >> 4) * 4;
    const size_t MN = (size_t)M * N;
    #pragma unroll
    for (int n = 0; n < 4; n++) {
        const int gcol = bn + wc + n * 16 + fr;
        const float bv = (OUT == 3) ? 0.0f : bias[gcol];
        #pragma unroll
        for (int m = 0; m < 4; m++) {
            #pragma unroll
            for (int j = 0; j < 4; j++) {
                const int grow = bm + wr + m * 16 + q4 + j;
                if (grow < M) {
                    float v = acc1[m][n][j] + acc2[m][n][j] * LO_ISC + bv;
                    const size_t o = (size_t)grow * N + gcol;
                    if (OUT == 3) {
                        Pf[(size_t)kz * MN + o] = v;
                    } else if (OUT == 2) {
                        Cf[o] = v;
                    } else {
                        Chi[o] = (f16)fmaxf(v, 0.0f);
                    }
                }
            }
        }
    }
}

// ------- sum-of-slices + bias -> LayerNorm -> ReLU -> f16 store -------------
// block = Wd/8 threads (128 or 192). dual: bias += (row&1)*1024 (dec reshape).
__global__ void ln_pf(
    const float* __restrict__ P, size_t MN, int ksplit,
    const float* __restrict__ bias, int dual,
    const float* __restrict__ gw, const float* __restrict__ bw,
    f16* __restrict__ oh, int Wd)
{
    const int row = blockIdx.x;
    const size_t base = (size_t)row * Wd;
    const int i8 = threadIdx.x * 8;
    const float* bp = bias + (dual ? ((row & 1) << 10) : 0);

    float v[8];
    {
        const float4 a0 = *(const float4*)(P + base + i8);
        const float4 a1 = *(const float4*)(P + base + i8 + 4);
        v[0]=a0.x; v[1]=a0.y; v[2]=a0.z; v[3]=a0.w;
        v[4]=a1.x; v[5]=a1.y; v[6]=a1.z; v[7]=a1.w;
    }
    for (int z = 1; z < ksplit; z++) {
        const float* Pz = P + (size_t)z * MN + base + i8;
        const float4 c0 = *(const float4*)(Pz);
        const float4 c1 = *(const float4*)(Pz + 4);
        v[0]+=c0.x; v[1]+=c0.y; v[2]+=c0.z; v[3]+=c0.w;
        v[4]+=c1.x; v[5]+=c1.y; v[6]+=c1.z; v[7]+=c1.w;
    }
    float s = 0.f, s2 = 0.f;
    #pragma unroll
    for (int k = 0; k < 8; k++) {
        v[k] += bp[i8 + k];
        s += v[k]; s2 += v[k] * v[k];
    }
    #pragma unroll
    for (int o = 1; o < 64; o <<= 1) { s += __shfl_xor(s, o); s2 += __shfl_xor(s2, o); }
    __shared__ float red[2][4];
    const int nw = blockDim.x >> 6;
    if ((threadIdx.x & 63) == 0) { red[0][threadIdx.x >> 6] = s; red[1][threadIdx.x >> 6] = s2; }
    __syncthreads();
    s = 0.f; s2 = 0.f;
    for (int w = 0; w < nw; w++) { s += red[0][w]; s2 += red[1][w]; }
    const float inv = 1.0f / (float)Wd;
    const float mean = s * inv;
    const float rstd = rsqrtf(s2 * inv - mean * mean + 1e-5f);
    const float4 g0 = *(const float4*)(gw + i8), g1 = *(const float4*)(gw + i8 + 4);
    const float4 b0 = *(const float4*)(bw + i8), b1 = *(const float4*)(bw + i8 + 4);
    const float gg[8] = {g0.x, g0.y, g0.z, g0.w, g1.x, g1.y, g1.z, g1.w};
    const float bb[8] = {b0.x, b0.y, b0.z, b0.w, b1.x, b1.y, b1.z, b1.w};
    half8 ho;
    #pragma unroll
    for (int k = 0; k < 8; k++)
        ho[k] = (f16)fmaxf((v[k] - mean) * rstd * gg[k] + bb[k], 0.0f);
    *(half8*)(oh + base + i8) = ho;
}

// ----- decode combine from f32 partial G (+bias) -> LN -> ReLU -> f16 -------
// P slices hold G[Mc=nb*Liv rows][2048]; output rows nb*(Liv+1) x 1024.
__global__ void comb_pf(
    const float* __restrict__ P, size_t MN, int ksplit,
    const float* __restrict__ bias,   // dec_b2 [2048]
    const float* __restrict__ gw, const float* __restrict__ bw,
    f16* __restrict__ oh, int Liv)
{
    const int row = blockIdx.x;
    const int Lp = Liv + 1;
    const int b = row / Lp, j = row - b * Lp;
    const int i8 = threadIdx.x * 8;

    auto sum8 = [&](size_t off, float* acc) {
        const float4 a0 = *(const float4*)(P + off);
        const float4 a1 = *(const float4*)(P + off + 4);
        acc[0]=a0.x; acc[1]=a0.y; acc[2]=a0.z; acc[3]=a0.w;
        acc[4]=a1.x; acc[5]=a1.y; acc[6]=a1.z; acc[7]=a1.w;
        for (int z = 1; z < ksplit; z++) {
            const float* Pz = P + (size_t)z * MN + off;
            const float4 c0 = *(const float4*)(Pz);
            const float4 c1 = *(const float4*)(Pz + 4);
            acc[0]+=c0.x; acc[1]+=c0.y; acc[2]+=c0.z; acc[3]+=c0.w;
            acc[4]+=c1.x; acc[5]+=c1.y; acc[6]+=c1.z; acc[7]+=c1.w;
        }
    };

    float v[8];
    if (j == 0) {
        sum8((size_t)(b * Liv) * 2048 + i8, v);
        #pragma unroll
        for (int k = 0; k < 8; k++) v[k] += bias[i8 + k];
    } else if (j == Liv) {
        sum8((size_t)(b * Liv + Liv - 1) * 2048 + 1024 + i8, v);
        #pragma unroll
        for (int k = 0; k < 8; k++) v[k] += bias[1024 + i8 + k];
    } else {
        float u[8];
        sum8((size_t)(b * Liv + j - 1) * 2048 + 1024 + i8, v);
        sum8((size_t)(b * Liv + j) * 2048 + i8, u);
        #pragma unroll
        for (int k = 0; k < 8; k++)
            v[k] = 0.5f * ((v[k] + bias[1024 + i8 + k]) + (u[k] + bias[i8 + k]));
    }
    float s = 0.f, s2 = 0.f;
    #pragma unroll
    for (int k = 0; k < 8; k++) { s += v[k]; s2 += v[k] * v[k]; }
    #pragma unroll
    for (int o = 1; o < 64; o <<= 1) { s += __shfl_xor(s, o); s2 += __shfl_xor(s2, o); }
    __shared__ float red[2][2];
    if ((threadIdx.x & 63) == 0) { red[0][threadIdx.x >> 6] = s; red[1][threadIdx.x >> 6] = s2; }
    __syncthreads();
    s = red[0][0] + red[0][1]; s2 = red[1][0] + red[1][1];
    const float mean = s * 9.765625e-4f;
    const float rstd = rsqrtf(s2 * 9.765625e-4f - mean * mean + 1e-5f);
    const float4 g0 = *(const float4*)(gw + i8), g1 = *(const float4*)(gw + i8 + 4);
    const float4 b0 = *(const float4*)(bw + i8), b1 = *(const float4*)(bw + i8 + 4);
    const float gg[8] = {g0.x, g0.y, g0.z, g0.w, g1.x, g1.y, g1.z, g1.w};
    const float bb[8] = {b0.x, b0.y, b0.z, b0.w, b1.x, b1.y, b1.z, b1.w};
    const size_t ob = (size_t)row * 1024 + i8;
    half8 ho;
    #pragma unroll
    for (int k = 0; k < 8; k++)
        ho[k] = (f16)fmaxf((v[k] - mean) * rstd * gg[k] + bb[k], 0.0f);
    *(half8*)(oh + ob) = ho;
}

// ---------------- weight transpose + split: W[K][N] -> Wt[N][K] -------------
__global__ __launch_bounds__(256) void wt_split_k(
    const float* __restrict__ W, f16* __restrict__ Th, f16* __restrict__ Tl,
    int K, int N)
{
    __shared__ float t[64][65];
    const int k0 = blockIdx.x * 64, n0 = blockIdx.y * 64;
    {
        const int j = threadIdx.x & 63, i0 = (threadIdx.x >> 6) * 16;
        for (int ii = 0; ii < 16; ii++) {
            int k = k0 + i0 + ii;
            t[i0 + ii][j] = (k < K) ? W[(size_t)k * N + n0 + j] : 0.f;
        }
    }
    __syncthreads();
    const int i = threadIdx.x & 63, j0 = (threadIdx.x >> 6) * 16;
    const int k = k0 + i;
    if (k < K) {
        for (int jj = 0; jj < 16; jj++) {
            float v = t[i][j0 + jj];
            f16 h = (f16)v;
            const size_t o = (size_t)(n0 + j0 + jj) * K + k;
            Th[o] = h;
            Tl[o] = (f16)((v - (float)h) * LO_SC);
        }
    }
}

// --------------------------- misc small kernels -----------------------------
__global__ void split_x_v(const float* __restrict__ x, f16* __restrict__ h, int n8) {
    int i = blockIdx.x * 256 + threadIdx.x;
    if (i >= n8) return;
    const int i8 = i * 8;
    const float4 f0 = *(const float4*)(x + i8), f1 = *(const float4*)(x + i8 + 4);
    const float vv[8] = {f0.x, f0.y, f0.z, f0.w, f1.x, f1.y, f1.z, f1.w};
    half8 ho;
    #pragma unroll
    for (int k = 0; k < 8; k++) ho[k] = (f16)vv[k];
    *(half8*)(h + i8) = ho;
}

__global__ void ts_init_k(f16* __restrict__ ts) {
    int e = blockIdx.x * 256 + threadIdx.x;
    if (e < 2048) {
        int rc = e >> 5, c = e & 31;
        float v = 0.f;
        if (rc >= 1) {
            int idx = (rc == 1) ? 1 : (rc == 2) ? 2 : (rc <= 4) ? 3 : ((rc + 10) / 3 - 1);
            if (c == 0) v = (float)rc;
            else if (c == idx) v = 1.f;
        }
        ts[e] = (f16)v;
    }
}

// ------------------------------ orchestration -------------------------------
extern "C" void kernel_launch(void* const* d_in, const int* in_sizes, int n_in,
                              void* d_out, int out_size, void* d_ws, size_t ws_size,
                              hipStream_t stream)
{
    const float* xin    = (const float*)d_in[0];
    const float* se_w1  = (const float*)d_in[1];
    const float* se_b1  = (const float*)d_in[2];
    const float* se_w2  = (const float*)d_in[3];
    const float* se_b2  = (const float*)d_in[4];
    const float* enc_w1 = (const float*)d_in[5];
    const float* enc_b1 = (const float*)d_in[6];
    const float* enc_g1 = (const float*)d_in[7];
    const float* enc_bb1= (const float*)d_in[8];
    const float* enc_w2 = (const float*)d_in[9];
    const float* enc_b2 = (const float*)d_in[10];
    const float* enc_g2 = (const float*)d_in[11];
    const float* enc_bb2= (const float*)d_in[12];
    const float* dec_w1 = (const float*)d_in[13];
    const float* dec_b1 = (const float*)d_in[14];
    const float* dec_g1 = (const float*)d_in[15];
    const float* dec_bb1= (const float*)d_in[16];
    const float* dec_w2 = (const float*)d_in[17];
    const float* dec_b2 = (const float*)d_in[18];
    const float* d2_g   = (const float*)d_in[19];
    const float* d2_b   = (const float*)d_in[20];
    const float* de_w1  = (const float*)d_in[21];
    const float* de_b1  = (const float*)d_in[22];
    const float* de_w2  = (const float*)d_in[23];
    const float* de_b2  = (const float*)d_in[24];

    // ------------- workspace layout (f16 units), tail-carved WR -------------
    const size_t ws_f16 = ws_size / 2;
    f16* ws = (f16*)d_ws;
    f16* Xh = ws;                                  // 4,194,304 (64*64*1024)
    f16* Hh = Xh + 4194304;                        // 6,193,152 (4032*1536)
    f16* WR = ws + (ws_f16 - 9512960);             // 9,510,912 + TS 2048
    f16* TS = WR + 9510912;
    float* PF = (float*)(Hh + 6193152);
    const long long pcap_ll = ((long long)ws_f16 - 9512960ll - 4194304ll - 6193152ll) / 2;
    const size_t pcap = (pcap_ll > 0) ? (size_t)pcap_ll : 0;
    const bool dec_unchunk = pcap >= 8257536ull;   // 4032x2048 f32 G-slice

    ts_init_k<<<8, 256, 0, stream>>>(TS);

    auto wt = [&](const float* W, int K, int N, f16* Th, f16* Tl) {
        wt_split_k<<<dim3((K + 63) / 64, N / 64), 256, 0, stream>>>(W, Th, Tl, K, N);
    };
    auto pick_ks = [&](int natural, int nst, size_t MN) {
        int ks = (natural >= 448) ? 1 : (448 + natural - 1) / natural;
        if (ks > 8) ks = 8;
        if (ks > nst) ks = nst;
        while (ks > 1 && (size_t)ks * MN > pcap) ks--;
        return ks;
    };

    #define GEMM(MODE, OUT, Ah, lda, Wh, Wl, bias, Ch, Cf, Pfp, ks, M, N, K, Kpad, kb, Lo, Li, tsr) \
        do { \
            const int gx_ = (N) / 128, gy_ = ((M) + 127) / 128;                \
            const int nwg_ = gx_ * gy_ * (ks);                                 \
            gemm_s2<MODE, OUT><<<nwg_, 256, 0, stream>>>(                      \
                Ah, lda, Wh, Wl, bias, Ch, Cf, Pfp, (ks),                      \
                M, N, K, Kpad, kb, Lo, Li, tsr, gy_, nwg_ >> 3, nwg_ & 7);     \
        } while (0)

    // ---- scale_embedding (scratch inside PF region) ----
    {
        f16* W1h = WR;            f16* W1l = W1h + 163840;
        f16* W2h = W1l + 163840;  f16* W2l = W2h + 655360;
        wt(se_w1, 256, 640, W1h, W1l);
        wt(se_w2, 640, 1024, W2h, W2l);
        f16* Sh  = (f16*)PF;               // 1,048,576
        f16* H1h = Sh + 1048576;           // 2,621,440 (4096x640)
        split_x_v<<<512, 256, 0, stream>>>(xin, Sh, 131072);
        GEMM(0, 1, Sh, 256, W1h, W1l, se_b1, H1h, (float*)0, (float*)0, 1,
             4096, 640, 256, 256, 256, 0, 0, TS);
        GEMM(0, 1, H1h, 640, W2h, W2l, se_b2, Xh, (float*)0, (float*)0, 1,
             4096, 1024, 640, 640, 640, 0, 0, TS);
    }

    // ---- encode ----
    {
        f16* E1h = WR;             f16* E1l = E1h + 3182592;
        f16* E2h = E1l + 3182592;  f16* E2l = E2h + 1572864;
        wt(enc_w1, 2072, 1536, E1h, E1l);
        wt(enc_w2, 1536, 1024, E2h, E2l);
        for (int rc = 1; rc <= 63; rc++) {
            const int Lo = 64 - rc, Li = Lo + 1, Mc = 64 * Lo;
            const int gy = (Mc + 127) / 128;
            const int k1 = pick_ks(12 * gy, 65, (size_t)Mc * 1536);
            GEMM(1, 3, Xh, 1024, E1h, E1l, enc_b1, (f16*)0, (float*)0,
                 PF, k1, Mc, 1536, 2072, 2080, 2048, Lo, Li, TS + rc * 32);
            ln_pf<<<Mc, 192, 0, stream>>>(PF, (size_t)Mc * 1536, k1, enc_b1, 0,
                                          enc_g1, enc_bb1, Hh, 1536);
            const int k2 = pick_ks(8 * gy, 48, (size_t)Mc * 1024);
            GEMM(0, 3, Hh, 1536, E2h, E2l, enc_b2, (f16*)0, (float*)0,
                 PF, k2, Mc, 1024, 1536, 1536, 1536, 0, 0, TS);
            ln_pf<<<Mc, 128, 0, stream>>>(PF, (size_t)Mc * 1024, k2, enc_b2, 0,
                                          enc_g2, enc_bb2, Xh, 1024);
        }
    }

    // ---- decode ----
    {
        f16* D1h = WR;             f16* D1l = D1h + 1609728;
        f16* D2h = D1l + 1609728;  f16* D2l = D2h + 3145728;
        wt(dec_w1, 1048, 1536, D1h, D1l);
        wt(dec_w2, 1536, 2048, D2h, D2l);

        // first step: [64,1024] -> [64,2048] -> LN over [128,1024] view
        {
            const int k1 = pick_ks(12, 33, (size_t)64 * 1536);
            GEMM(2, 3, Xh, 1024, D1h, D1l, dec_b1, (f16*)0, (float*)0,
                 PF, k1, 64, 1536, 1048, 1056, 1024, 0, 0, TS + 63 * 32);
            ln_pf<<<64, 192, 0, stream>>>(PF, (size_t)64 * 1536, k1, dec_b1, 0,
                                          dec_g1, dec_bb1, Hh, 1536);
            const int k2 = pick_ks(16, 48, (size_t)64 * 2048);
            GEMM(0, 3, Hh, 1536, D2h, D2l, dec_b2, (f16*)0, (float*)0,
                 PF, k2, 64, 2048, 1536, 1536, 1536, 0, 0, TS);
            // 64x2048 flat == 128x1024 flat; dual-bias by row parity
            ln_pf<<<128, 128, 0, stream>>>(PF, (size_t)64 * 2048, k2, dec_b2, 1,
                                           d2_g, d2_b, Xh, 1024);
        }

        for (int rc = 62; rc >= 1; rc--) {
            const int Li = 64 - rc;
            const int nch = (!dec_unchunk && 64 * Li > 2016) ? 2 : 1, nb = 64 / nch;
            for (int c = nch - 1; c >= 0; c--) {        // high batches first
                const int b0 = c * nb, Mc = nb * Li;
                const size_t ai = (size_t)b0 * Li * 1024;
                const size_t oi = (size_t)b0 * (Li + 1) * 1024;
                const int gy = (Mc + 127) / 128;
                const int k1 = pick_ks(12 * gy, 33, (size_t)Mc * 1536);
                GEMM(2, 3, Xh + ai, 1024, D1h, D1l, dec_b1, (f16*)0, (float*)0,
                     PF, k1, Mc, 1536, 1048, 1056, 1024, 0, 0, TS + rc * 32);
                ln_pf<<<Mc, 192, 0, stream>>>(PF, (size_t)Mc * 1536, k1, dec_b1, 0,
                                              dec_g1, dec_bb1, Hh, 1536);
                const int k2 = pick_ks(16 * gy, 48, (size_t)Mc * 2048);
                GEMM(0, 3, Hh, 1536, D2h, D2l, dec_b2, (f16*)0, (float*)0,
                     PF, k2, Mc, 2048, 1536, 1536, 1536, 0, 0, TS);
                comb_pf<<<nb * (Li + 1), 128, 0, stream>>>(
                    PF, (size_t)Mc * 2048, k2, dec_b2, d2_g, d2_b,
                    Xh + oi, Li);
            }
        }
    }

    // ---- descale_embedding ----
    {
        f16* W1h = WR;            f16* W1l = W1h + 655360;
        f16* W2h = W1l + 655360;  f16* W2l = W2h + 163840;
        wt(de_w1, 1024, 640, W1h, W1l);
        wt(de_w2, 640, 256, W2h, W2l);
        f16* H1h = (f16*)PF;               // 2,621,440 (4096x640)
        GEMM(0, 1, Xh, 1024, W1h, W1l, de_b1, H1h, (float*)0, (float*)0, 1,
             4096, 640, 1024, 1024, 1024, 0, 0, TS);
        GEMM(0, 2, H1h, 640, W2h, W2l, de_b2, (f16*)0, (float*)d_out, (float*)0, 1,
             4096, 256, 640, 640, 640, 0, 0, TS);
    }
    #undef GEMM
}

// Round 12
// 12969.125 us; speedup vs baseline: 1.4608x; 1.0189x over previous
//
#include <hip/hip_runtime.h>

// ---------------------------------------------------------------------------
// RAE forward, 2-product split-f16 MFMA GEMMs + deterministic split-K.
// Weights: W ~= Wh + Wl*2^-12 (f16 pair). Activations: single f16.
//   C = A@W ~= A@Wh + (A@Wl)*2^-12   (2 MFMA products)
// GEMM: 128x128 tile, 4 waves, A+W via global_load_lds, 2 blocks/CU,
// split-K into P[kz][M][N] f32 summed in LN pass.
// NEW (R12): 3-buffer LDS, 2-deep software pipeline with counted
// s_waitcnt vmcnt(6) + raw s_barrier (T3/T4 minimum). Invariant: wave passes
// barrier(s) only after its own stage(s) loads landed (vmcnt) and after its
// step s-1 reads (program order) -> buf[s%3] globally valid after barrier;
// stage(s+2) targets the buffer last read at s-1. Numerics bit-identical.
//
// FAILED-EXPERIMENT LEDGER (do not repeat):
//  - A streamed global->VGPR (R5: -27%, R7: -330%)
//  - split-K target 512 / cap 16 (R8: +4% slower) — keep 448 / cap 8
//  - 128x256 tile, 8 waves, 96KB LDS (R9: +12% slower)
//  - LDS [kc][row][8] layout: bank-balanced, no swizzle needed
// ---------------------------------------------------------------------------

typedef _Float16 f16;
typedef _Float16 half8 __attribute__((ext_vector_type(8)));
typedef float floatx4 __attribute__((ext_vector_type(4)));

#define LO_SC   4096.0f
#define LO_ISC  2.44140625e-4f

__device__ __forceinline__ void gld_lds16(const f16* g, f16* l) {
    __builtin_amdgcn_global_load_lds(
        (const __attribute__((address_space(1))) void*)g,
        (__attribute__((address_space(3))) void*)l, 16, 0, 0);
}

// ----------------------------- GEMM ----------------------------------------
// MODE 0: plain A. MODE 1: enc-cat (row b*Li+l; k>=kbound -> ts table).
// MODE 2: dec-cat (k>=kbound -> ts table).
// OUT 1: bias+relu+f16 store; OUT 2: bias+fp32 store; OUT 3: f32 partial
// slice store (no bias).
template<int MODE, int OUT>
__global__ __launch_bounds__(256, 2) void gemm_s2(
    const f16* __restrict__ Ahi, int lda,
    const f16* __restrict__ Whi, const f16* __restrict__ Wlo,   // [N][K] transposed
    const float* __restrict__ bias,
    f16* __restrict__ Chi, float* __restrict__ Cf,
    float* __restrict__ Pf, int ksplit,
    int M, int N, int K, int Kpad, int kbound, int Lo, int Li,
    const f16* __restrict__ tsrow,
    int gy, int q, int r)
{
    // [buf 0..2][arr: A,Wh,Wl][kchunk][row][8]  -> 72 KiB (3 x 24 KiB)
    __shared__ __align__(16) f16 sm[3][3][4][128][8];

    const int tid  = threadIdx.x;
    const int lane = tid & 63;
    const int wid  = tid >> 6;

    // bijective XCD swizzle (m204); rank = (bx*gy + by)*ksplit + kz
    const int bid = blockIdx.x;
    const int xcd = bid & 7, jj = bid >> 3;
    const int rank = (xcd < r) ? xcd * (q + 1) + jj
                               : r * (q + 1) + (xcd - r) * q + jj;
    const int t  = rank / ksplit;
    const int kz = rank - t * ksplit;
    const int bx = t / gy, by = t - bx * gy;
    const int bm = by * 128;
    const int bn = bx * 128;

    // staging: wave `wid` fills kchunk = wid; slots it=0,1 -> row/col = it*64+lane
    const f16* aph[2];
    const f16* wph[2]; const f16* wpl[2];
    #pragma unroll
    for (int it = 0; it < 2; it++) {
        int rr = bm + it * 64 + lane;
        if (rr > M - 1) rr = M - 1;
        int arow;
        if (MODE == 1) { int b = rr / Lo; int l = rr - b * Lo; arow = b * Li + l; }
        else arow = rr;
        aph[it] = Ahi + (size_t)arow * lda;
        int col = bn + it * 64 + lane;          // N % 128 == 0 -> in range
        wph[it] = Whi + (size_t)col * K;
        wpl[it] = Wlo + (size_t)col * K;
    }

    const int kw0 = wid * 8;
    // exactly 6 global_load_lds per wave per stage (vmcnt arithmetic relies on it)
    auto stage = [&](int buf, int sstep) {
        const int ka = (sstep << 5) + kw0;
        int kwc = ka; if (kwc > K - 8) kwc = K - 8;   // W k-clamp (A side is 0 there)
        #pragma unroll
        for (int it = 0; it < 2; it++) {
            const f16* sh;
            if (MODE == 0 || ka < kbound) sh = aph[it] + ka;
            else                          sh = tsrow + (ka - kbound);
            gld_lds16(sh,            &sm[buf][0][wid][it * 64][0]);
            gld_lds16(wph[it] + kwc, &sm[buf][1][wid][it * 64][0]);
            gld_lds16(wpl[it] + kwc, &sm[buf][2][wid][it * 64][0]);
        }
    };

    floatx4 acc1[4][4] = {};
    floatx4 acc2[4][4] = {};

    const int nst = Kpad >> 5;
    const int sps = (nst + ksplit - 1) / ksplit;
    const int s0  = kz * sps;
    int s1 = s0 + sps; if (s1 > nst) s1 = nst;

    const int kc = lane >> 4;
    const int fr = lane & 15;
    const int wr = (wid >> 1) * 64;
    const int wc = (wid & 1) * 64;

    if (s0 < s1) {
        const int n = s1 - s0;
        // prologue: 2 stages in flight (second clamped if chain is length 1)
        stage(0, s0);
        stage(1, s0 + ((n > 1) ? 1 : 0));
        for (int j = 0; j < n; j++) {
            // wait for own stage(j) loads (6 newest outstanding = stage(j+1))
            asm volatile("s_waitcnt vmcnt(6)" ::: "memory");
            asm volatile("s_barrier" ::: "memory");
            // issue stage(j+2) (clamped dummy at tail keeps 6-load cadence;
            // its buffer was last read at step j-1 -> all waves done with it)
            {
                int jt = j + 2; if (jt > n - 1) jt = n - 1;
                stage((j + 2) % 3, s0 + jt);
            }
            const int buf = j % 3;
            half8 ah[4], wh[4], wl[4];
            #pragma unroll
            for (int m = 0; m < 4; m++)
                ah[m] = *(const half8*)&sm[buf][0][kc][wr + m * 16 + fr][0];
            #pragma unroll
            for (int nn = 0; nn < 4; nn++) {
                wh[nn] = *(const half8*)&sm[buf][1][kc][wc + nn * 16 + fr][0];
                wl[nn] = *(const half8*)&sm[buf][2][kc][wc + nn * 16 + fr][0];
            }
            #pragma unroll
            for (int m = 0; m < 4; m++)
                #pragma unroll
                for (int nn = 0; nn < 4; nn++) {
                    acc1[m][nn] = __builtin_amdgcn_mfma_f32_16x16x32_f16(ah[m], wh[nn], acc1[m][nn], 0, 0, 0);
                    acc2[m][nn] = __builtin_amdgcn_mfma_f32_16x16x32_f16(ah[m], wl[nn], acc2[m][nn], 0, 0, 0);
                }
        }
        // drain remaining loads before epilogue stores reuse the wave
        asm volatile("s_waitcnt vmcnt(0)" ::: "memory");
    }

    // epilogue: C/D frag layout col = lane&15, row = (lane>>4)*4 + j
    const int q4 = (lane >> 4) * 4;
    const size_t MN = (size_t)M * N;
    #pragma unroll
    for (int nn = 0; nn < 4; nn++) {
        const int gcol = bn + wc + nn * 16 + fr;
        const float bv = (OUT == 3) ? 0.0f : bias[gcol];
        #pragma unroll
        for (int m = 0; m < 4; m++) {
            #pragma unroll
            for (int j = 0; j < 4; j++) {
                const int grow = bm + wr + m * 16 + q4 + j;
                if (grow < M) {
                    float v = acc1[m][nn][j] + acc2[m][nn][j] * LO_ISC + bv;
                    const size_t o = (size_t)grow * N + gcol;
                    if (OUT == 3) {
                        Pf[(size_t)kz * MN + o] = v;
                    } else if (OUT == 2) {
                        Cf[o] = v;
                    } else {
                        Chi[o] = (f16)fmaxf(v, 0.0f);
                    }
                }
            }
        }
    }
}

// ------- sum-of-slices + bias -> LayerNorm -> ReLU -> f16 store -------------
// block = Wd/8 threads (128 or 192). dual: bias += (row&1)*1024 (dec reshape).
__global__ void ln_pf(
    const float* __restrict__ P, size_t MN, int ksplit,
    const float* __restrict__ bias, int dual,
    const float* __restrict__ gw, const float* __restrict__ bw,
    f16* __restrict__ oh, int Wd)
{
    const int row = blockIdx.x;
    const size_t base = (size_t)row * Wd;
    const int i8 = threadIdx.x * 8;
    const float* bp = bias + (dual ? ((row & 1) << 10) : 0);

    float v[8];
    {
        const float4 a0 = *(const float4*)(P + base + i8);
        const float4 a1 = *(const float4*)(P + base + i8 + 4);
        v[0]=a0.x; v[1]=a0.y; v[2]=a0.z; v[3]=a0.w;
        v[4]=a1.x; v[5]=a1.y; v[6]=a1.z; v[7]=a1.w;
    }
    for (int z = 1; z < ksplit; z++) {
        const float* Pz = P + (size_t)z * MN + base + i8;
        const float4 c0 = *(const float4*)(Pz);
        const float4 c1 = *(const float4*)(Pz + 4);
        v[0]+=c0.x; v[1]+=c0.y; v[2]+=c0.z; v[3]+=c0.w;
        v[4]+=c1.x; v[5]+=c1.y; v[6]+=c1.z; v[7]+=c1.w;
    }
    float s = 0.f, s2 = 0.f;
    #pragma unroll
    for (int k = 0; k < 8; k++) {
        v[k] += bp[i8 + k];
        s += v[k]; s2 += v[k] * v[k];
    }
    #pragma unroll
    for (int o = 1; o < 64; o <<= 1) { s += __shfl_xor(s, o); s2 += __shfl_xor(s2, o); }
    __shared__ float red[2][4];
    const int nw = blockDim.x >> 6;
    if ((threadIdx.x & 63) == 0) { red[0][threadIdx.x >> 6] = s; red[1][threadIdx.x >> 6] = s2; }
    __syncthreads();
    s = 0.f; s2 = 0.f;
    for (int w = 0; w < nw; w++) { s += red[0][w]; s2 += red[1][w]; }
    const float inv = 1.0f / (float)Wd;
    const float mean = s * inv;
    const float rstd = rsqrtf(s2 * inv - mean * mean + 1e-5f);
    const float4 g0 = *(const float4*)(gw + i8), g1 = *(const float4*)(gw + i8 + 4);
    const float4 b0 = *(const float4*)(bw + i8), b1 = *(const float4*)(bw + i8 + 4);
    const float gg[8] = {g0.x, g0.y, g0.z, g0.w, g1.x, g1.y, g1.z, g1.w};
    const float bb[8] = {b0.x, b0.y, b0.z, b0.w, b1.x, b1.y, b1.z, b1.w};
    half8 ho;
    #pragma unroll
    for (int k = 0; k < 8; k++)
        ho[k] = (f16)fmaxf((v[k] - mean) * rstd * gg[k] + bb[k], 0.0f);
    *(half8*)(oh + base + i8) = ho;
}

// ----- decode combine from f32 partial G (+bias) -> LN -> ReLU -> f16 -------
// P slices hold G[Mc=nb*Liv rows][2048]; output rows nb*(Liv+1) x 1024.
__global__ void comb_pf(
    const float* __restrict__ P, size_t MN, int ksplit,
    const float* __restrict__ bias,   // dec_b2 [2048]
    const float* __restrict__ gw, const float* __restrict__ bw,
    f16* __restrict__ oh, int Liv)
{
    const int row = blockIdx.x;
    const int Lp = Liv + 1;
    const int b = row / Lp, j = row - b * Lp;
    const int i8 = threadIdx.x * 8;

    auto sum8 = [&](size_t off, float* acc) {
        const float4 a0 = *(const float4*)(P + off);
        const float4 a1 = *(const float4*)(P + off + 4);
        acc[0]=a0.x; acc[1]=a0.y; acc[2]=a0.z; acc[3]=a0.w;
        acc[4]=a1.x; acc[5]=a1.y; acc[6]=a1.z; acc[7]=a1.w;
        for (int z = 1; z < ksplit; z++) {
            const float* Pz = P + (size_t)z * MN + off;
            const float4 c0 = *(const float4*)(Pz);
            const float4 c1 = *(const float4*)(Pz + 4);
            acc[0]+=c0.x; acc[1]+=c0.y; acc[2]+=c0.z; acc[3]+=c0.w;
            acc[4]+=c1.x; acc[5]+=c1.y; acc[6]+=c1.z; acc[7]+=c1.w;
        }
    };

    float v[8];
    if (j == 0) {
        sum8((size_t)(b * Liv) * 2048 + i8, v);
        #pragma unroll
        for (int k = 0; k < 8; k++) v[k] += bias[i8 + k];
    } else if (j == Liv) {
        sum8((size_t)(b * Liv + Liv - 1) * 2048 + 1024 + i8, v);
        #pragma unroll
        for (int k = 0; k < 8; k++) v[k] += bias[1024 + i8 + k];
    } else {
        float u[8];
        sum8((size_t)(b * Liv + j - 1) * 2048 + 1024 + i8, v);
        sum8((size_t)(b * Liv + j) * 2048 + i8, u);
        #pragma unroll
        for (int k = 0; k < 8; k++)
            v[k] = 0.5f * ((v[k] + bias[1024 + i8 + k]) + (u[k] + bias[i8 + k]));
    }
    float s = 0.f, s2 = 0.f;
    #pragma unroll
    for (int k = 0; k < 8; k++) { s += v[k]; s2 += v[k] * v[k]; }
    #pragma unroll
    for (int o = 1; o < 64; o <<= 1) { s += __shfl_xor(s, o); s2 += __shfl_xor(s2, o); }
    __shared__ float red[2][2];
    if ((threadIdx.x & 63) == 0) { red[0][threadIdx.x >> 6] = s; red[1][threadIdx.x >> 6] = s2; }
    __syncthreads();
    s = red[0][0] + red[0][1]; s2 = red[1][0] + red[1][1];
    const float mean = s * 9.765625e-4f;
    const float rstd = rsqrtf(s2 * 9.765625e-4f - mean * mean + 1e-5f);
    const float4 g0 = *(const float4*)(gw + i8), g1 = *(const float4*)(gw + i8 + 4);
    const float4 b0 = *(const float4*)(bw + i8), b1 = *(const float4*)(bw + i8 + 4);
    const float gg[8] = {g0.x, g0.y, g0.z, g0.w, g1.x, g1.y, g1.z, g1.w};
    const float bb[8] = {b0.x, b0.y, b0.z, b0.w, b1.x, b1.y, b1.z, b1.w};
    const size_t ob = (size_t)row * 1024 + i8;
    half8 ho;
    #pragma unroll
    for (int k = 0; k < 8; k++)
        ho[k] = (f16)fmaxf((v[k] - mean) * rstd * gg[k] + bb[k], 0.0f);
    *(half8*)(oh + ob) = ho;
}

// ---------------- weight transpose + split: W[K][N] -> Wt[N][K] -------------
__global__ __launch_bounds__(256) void wt_split_k(
    const float* __restrict__ W, f16* __restrict__ Th, f16* __restrict__ Tl,
    int K, int N)
{
    __shared__ float t[64][65];
    const int k0 = blockIdx.x * 64, n0 = blockIdx.y * 64;
    {
        const int j = threadIdx.x & 63, i0 = (threadIdx.x >> 6) * 16;
        for (int ii = 0; ii < 16; ii++) {
            int k = k0 + i0 + ii;
            t[i0 + ii][j] = (k < K) ? W[(size_t)k * N + n0 + j] : 0.f;
        }
    }
    __syncthreads();
    const int i = threadIdx.x & 63, j0 = (threadIdx.x >> 6) * 16;
    const int k = k0 + i;
    if (k < K) {
        for (int jj = 0; jj < 16; jj++) {
            float v = t[i][j0 + jj];
            f16 h = (f16)v;
            const size_t o = (size_t)(n0 + j0 + jj) * K + k;
            Th[o] = h;
            Tl[o] = (f16)((v - (float)h) * LO_SC);
        }
    }
}

// --------------------------- misc small kernels -----------------------------
__global__ void split_x_v(const float* __restrict__ x, f16* __restrict__ h, int n8) {
    int i = blockIdx.x * 256 + threadIdx.x;
    if (i >= n8) return;
    const int i8 = i * 8;
    const float4 f0 = *(const float4*)(x + i8), f1 = *(const float4*)(x + i8 + 4);
    const float vv[8] = {f0.x, f0.y, f0.z, f0.w, f1.x, f1.y, f1.z, f1.w};
    half8 ho;
    #pragma unroll
    for (int k = 0; k < 8; k++) ho[k] = (f16)vv[k];
    *(half8*)(h + i8) = ho;
}

__global__ void ts_init_k(f16* __restrict__ ts) {
    int e = blockIdx.x * 256 + threadIdx.x;
    if (e < 2048) {
        int rc = e >> 5, c = e & 31;
        float v = 0.f;
        if (rc >= 1) {
            int idx = (rc == 1) ? 1 : (rc == 2) ? 2 : (rc <= 4) ? 3 : ((rc + 10) / 3 - 1);
            if (c == 0) v = (float)rc;
            else if (c == idx) v = 1.f;
        }
        ts[e] = (f16)v;
    }
}

// ------------------------------ orchestration -------------------------------
extern "C" void kernel_launch(void* const* d_in, const int* in_sizes, int n_in,
                              void* d_out, int out_size, void* d_ws, size_t ws_size,
                              hipStream_t stream)
{
    const float* xin    = (const float*)d_in[0];
    const float* se_w1  = (const float*)d_in[1];
    const float* se_b1  = (const float*)d_in[2];
    const float* se_w2  = (const float*)d_in[3];
    const float* se_b2  = (const float*)d_in[4];
    const float* enc_w1 = (const float*)d_in[5];
    const float* enc_b1 = (const float*)d_in[6];
    const float* enc_g1 = (const float*)d_in[7];
    const float* enc_bb1= (const float*)d_in[8];
    const float* enc_w2 = (const float*)d_in[9];
    const float* enc_b2 = (const float*)d_in[10];
    const float* enc_g2 = (const float*)d_in[11];
    const float* enc_bb2= (const float*)d_in[12];
    const float* dec_w1 = (const float*)d_in[13];
    const float* dec_b1 = (const float*)d_in[14];
    const float* dec_g1 = (const float*)d_in[15];
    const float* dec_bb1= (const float*)d_in[16];
    const float* dec_w2 = (const float*)d_in[17];
    const float* dec_b2 = (const float*)d_in[18];
    const float* d2_g   = (const float*)d_in[19];
    const float* d2_b   = (const float*)d_in[20];
    const float* de_w1  = (const float*)d_in[21];
    const float* de_b1  = (const float*)d_in[22];
    const float* de_w2  = (const float*)d_in[23];
    const float* de_b2  = (const float*)d_in[24];

    // ------------- workspace layout (f16 units), tail-carved WR -------------
    const size_t ws_f16 = ws_size / 2;
    f16* ws = (f16*)d_ws;
    f16* Xh = ws;                                  // 4,194,304 (64*64*1024)
    f16* Hh = Xh + 4194304;                        // 6,193,152 (4032*1536)
    f16* WR = ws + (ws_f16 - 9512960);             // 9,510,912 + TS 2048
    f16* TS = WR + 9510912;
    float* PF = (float*)(Hh + 6193152);
    const long long pcap_ll = ((long long)ws_f16 - 9512960ll - 4194304ll - 6193152ll) / 2;
    const size_t pcap = (pcap_ll > 0) ? (size_t)pcap_ll : 0;
    const bool dec_unchunk = pcap >= 8257536ull;   // 4032x2048 f32 G-slice

    ts_init_k<<<8, 256, 0, stream>>>(TS);

    auto wt = [&](const float* W, int K, int N, f16* Th, f16* Tl) {
        wt_split_k<<<dim3((K + 63) / 64, N / 64), 256, 0, stream>>>(W, Th, Tl, K, N);
    };
    auto pick_ks = [&](int natural, int nst, size_t MN) {
        int ks = (natural >= 448) ? 1 : (448 + natural - 1) / natural;
        if (ks > 8) ks = 8;
        if (ks > nst) ks = nst;
        while (ks > 1 && (size_t)ks * MN > pcap) ks--;
        return ks;
    };

    #define GEMM(MODE, OUT, Ah, lda, Wh, Wl, bias, Ch, Cf, Pfp, ks, M, N, K, Kpad, kb, Lo, Li, tsr) \
        do { \
            const int gx_ = (N) / 128, gy_ = ((M) + 127) / 128;                \
            const int nwg_ = gx_ * gy_ * (ks);                                 \
            gemm_s2<MODE, OUT><<<nwg_, 256, 0, stream>>>(                      \
                Ah, lda, Wh, Wl, bias, Ch, Cf, Pfp, (ks),                      \
                M, N, K, Kpad, kb, Lo, Li, tsr, gy_, nwg_ >> 3, nwg_ & 7);     \
        } while (0)

    // ---- scale_embedding (scratch inside PF region) ----
    {
        f16* W1h = WR;            f16* W1l = W1h + 163840;
        f16* W2h = W1l + 163840;  f16* W2l = W2h + 655360;
        wt(se_w1, 256, 640, W1h, W1l);
        wt(se_w2, 640, 1024, W2h, W2l);
        f16* Sh  = (f16*)PF;               // 1,048,576
        f16* H1h = Sh + 1048576;           // 2,621,440 (4096x640)
        split_x_v<<<512, 256, 0, stream>>>(xin, Sh, 131072);
        GEMM(0, 1, Sh, 256, W1h, W1l, se_b1, H1h, (float*)0, (float*)0, 1,
             4096, 640, 256, 256, 256, 0, 0, TS);
        GEMM(0, 1, H1h, 640, W2h, W2l, se_b2, Xh, (float*)0, (float*)0, 1,
             4096, 1024, 640, 640, 640, 0, 0, TS);
    }

    // ---- encode ----
    {
        f16* E1h = WR;             f16* E1l = E1h + 3182592;
        f16* E2h = E1l + 3182592;  f16* E2l = E2h + 1572864;
        wt(enc_w1, 2072, 1536, E1h, E1l);
        wt(enc_w2, 1536, 1024, E2h, E2l);
        for (int rc = 1; rc <= 63; rc++) {
            const int Lo = 64 - rc, Li = Lo + 1, Mc = 64 * Lo;
            const int gy = (Mc + 127) / 128;
            const int k1 = pick_ks(12 * gy, 65, (size_t)Mc * 1536);
            GEMM(1, 3, Xh, 1024, E1h, E1l, enc_b1, (f16*)0, (float*)0,
                 PF, k1, Mc, 1536, 2072, 2080, 2048, Lo, Li, TS + rc * 32);
            ln_pf<<<Mc, 192, 0, stream>>>(PF, (size_t)Mc * 1536, k1, enc_b1, 0,
                                          enc_g1, enc_bb1, Hh, 1536);
            const int k2 = pick_ks(8 * gy, 48, (size_t)Mc * 1024);
            GEMM(0, 3, Hh, 1536, E2h, E2l, enc_b2, (f16*)0, (float*)0,
                 PF, k2, Mc, 1024, 1536, 1536, 1536, 0, 0, TS);
            ln_pf<<<Mc, 128, 0, stream>>>(PF, (size_t)Mc * 1024, k2, enc_b2, 0,
                                          enc_g2, enc_bb2, Xh, 1024);
        }
    }

    // ---- decode ----
    {
        f16* D1h = WR;             f16* D1l = D1h + 1609728;
        f16* D2h = D1l + 1609728;  f16* D2l = D2h + 3145728;
        wt(dec_w1, 1048, 1536, D1h, D1l);
        wt(dec_w2, 1536, 2048, D2h, D2l);

        // first step: [64,1024] -> [64,2048] -> LN over [128,1024] view
        {
            const int k1 = pick_ks(12, 33, (size_t)64 * 1536);
            GEMM(2, 3, Xh, 1024, D1h, D1l, dec_b1, (f16*)0, (float*)0,
                 PF, k1, 64, 1536, 1048, 1056, 1024, 0, 0, TS + 63 * 32);
            ln_pf<<<64, 192, 0, stream>>>(PF, (size_t)64 * 1536, k1, dec_b1, 0,
                                          dec_g1, dec_bb1, Hh, 1536);
            const int k2 = pick_ks(16, 48, (size_t)64 * 2048);
            GEMM(0, 3, Hh, 1536, D2h, D2l, dec_b2, (f16*)0, (float*)0,
                 PF, k2, 64, 2048, 1536, 1536, 1536, 0, 0, TS);
            // 64x2048 flat == 128x1024 flat; dual-bias by row parity
            ln_pf<<<128, 128, 0, stream>>>(PF, (size_t)64 * 2048, k2, dec_b2, 1,
                                           d2_g, d2_b, Xh, 1024);
        }

        for (int rc = 62; rc >= 1; rc--) {
            const int Li = 64 - rc;
            const int nch = (!dec_unchunk && 64 * Li > 2016) ? 2 : 1, nb = 64 / nch;
            for (int c = nch - 1; c >= 0; c--) {        // high batches first
                const int b0 = c * nb, Mc = nb * Li;
                const size_t ai = (size_t)b0 * Li * 1024;
                const size_t oi = (size_t)b0 * (Li + 1) * 1024;
                const int gy = (Mc + 127) / 128;
                const int k1 = pick_ks(12 * gy, 33, (size_t)Mc * 1536);
                GEMM(2, 3, Xh + ai, 1024, D1h, D1l, dec_b1, (f16*)0, (float*)0,
                     PF, k1, Mc, 1536, 1048, 1056, 1024, 0, 0, TS + rc * 32);
                ln_pf<<<Mc, 192, 0, stream>>>(PF, (size_t)Mc * 1536, k1, dec_b1, 0,
                                              dec_g1, dec_bb1, Hh, 1536);
                const int k2 = pick_ks(16 * gy, 48, (size_t)Mc * 2048);
                GEMM(0, 3, Hh, 1536, D2h, D2l, dec_b2, (f16*)0, (float*)0,
                     PF, k2, Mc, 2048, 1536, 1536, 1536, 0, 0, TS);
                comb_pf<<<nb * (Li + 1), 128, 0, stream>>>(
                    PF, (size_t)Mc * 2048, k2, dec_b2, d2_g, d2_b,
                    Xh + oi, Li);
            }
        }
    }

    // ---- descale_embedding ----
    {
        f16* W1h = WR;            f16* W1l = W1h + 655360;
        f16* W2h = W1l + 655360;  f16* W2l = W2h + 163840;
        wt(de_w1, 1024, 640, W1h, W1l);
        wt(de_w2, 640, 256, W2h, W2l);
        f16* H1h = (f16*)PF;               // 2,621,440 (4096x640)
        GEMM(0, 1, Xh, 1024, W1h, W1l, de_b1, H1h, (float*)0, (float*)0, 1,
             4096, 640, 1024, 1024, 1024, 0, 0, TS);
        GEMM(0, 2, H1h, 640, W2h, W2l, de_b2, (f16*)0, (float*)d_out, (float*)0, 1,
             4096, 256, 640, 640, 640, 0, 0, TS);
    }
    #undef GEMM
}

// Round 13
// 10255.760 us; speedup vs baseline: 1.8473x; 1.2646x over previous
//
#include <hip/hip_runtime.h>

// ---------------------------------------------------------------------------
// RAE forward, 2-product split-f16 MFMA GEMMs + deterministic split-K.
// Weights: W ~= Wh + Wl*2^-12 (f16 pair). Activations: single f16.
//   C = A@W ~= A@Wh + (A@Wl)*2^-12   (2 MFMA products)
// GEMM: 128x128 tile, 4 waves, A+W via global_load_lds, 2 blocks/CU,
// 3-buffer LDS + counted s_waitcnt vmcnt(6) 2-deep pipeline (R12),
// split-K into P[kz][M][N] f32 summed in LN pass.
// NEW (R13): contiguous-line staging. LDS tile [row][32k]; 4 consecutive
// lanes load 64B contiguous of one row/col (16 cache lines per gld_lds
// instead of 64 scattered). k-part pre-swizzled on the GLOBAL side
// (kp^(rl&3)), LDS linear, reader applies kc^(fr&3) -> same data in same
// logical slots, bank-spread 2-way (free). Bit-identical numerics.
//
// FAILED-EXPERIMENT LEDGER (do not repeat):
//  - A streamed global->VGPR (R5: -27%, R7: -330%)
//  - split-K target 512 / cap 16 (R8: +4% slower) — keep 448 / cap 8
//  - 128x256 tile, 8 waves, 96KB LDS (R9: +12% slower)
//  - counted-vmcnt pipeline alone (R12: +2% only — not latency-bound)
// ---------------------------------------------------------------------------

typedef _Float16 f16;
typedef _Float16 half8 __attribute__((ext_vector_type(8)));
typedef float floatx4 __attribute__((ext_vector_type(4)));

#define LO_SC   4096.0f
#define LO_ISC  2.44140625e-4f

__device__ __forceinline__ void gld_lds16(const f16* g, f16* l) {
    __builtin_amdgcn_global_load_lds(
        (const __attribute__((address_space(1))) void*)g,
        (__attribute__((address_space(3))) void*)l, 16, 0, 0);
}

// ----------------------------- GEMM ----------------------------------------
// MODE 0: plain A. MODE 1: enc-cat (row b*Li+l; k>=kbound -> ts table).
// MODE 2: dec-cat (k>=kbound -> ts table).
// OUT 1: bias+relu+f16 store; OUT 2: bias+fp32 store; OUT 3: f32 partial
// slice store (no bias).
template<int MODE, int OUT>
__global__ __launch_bounds__(256, 2) void gemm_s2(
    const f16* __restrict__ Ahi, int lda,
    const f16* __restrict__ Whi, const f16* __restrict__ Wlo,   // [N][K] transposed
    const float* __restrict__ bias,
    f16* __restrict__ Chi, float* __restrict__ Cf,
    float* __restrict__ Pf, int ksplit,
    int M, int N, int K, int Kpad, int kbound, int Lo, int Li,
    const f16* __restrict__ tsrow,
    int gy, int q, int r)
{
    // [buf 0..2][arr: A,Wh,Wl][row/col 0..127][32 k]  -> 72 KiB
    __shared__ __align__(16) f16 sm[3][3][128][32];

    const int tid  = threadIdx.x;
    const int lane = tid & 63;
    const int wid  = tid >> 6;

    // bijective XCD swizzle (m204); rank = (bx*gy + by)*ksplit + kz
    const int bid = blockIdx.x;
    const int xcd = bid & 7, jj = bid >> 3;
    const int rank = (xcd < r) ? xcd * (q + 1) + jj
                               : r * (q + 1) + (xcd - r) * q + jj;
    const int t  = rank / ksplit;
    const int kz = rank - t * ksplit;
    const int bx = t / gy, by = t - bx * gy;
    const int bm = by * 128;
    const int bn = bx * 128;

    // staging geometry: wave wid covers tile rows/cols [wid*32, wid*32+32),
    // slot it covers 16 of them; lane = rl*4 + kp loads the row's 16B at
    // k-part (kp ^ (rl&3))  -> 4 consecutive lanes = 64B contiguous.
    const int rl   = lane >> 2;
    const int kp   = lane & 3;
    const int kofs = ((kp ^ (rl & 3)) << 3);     // f16 offset within row

    const f16* aph[2];          // A row base (global), no kofs
    const f16* wph[2]; const f16* wpl[2];
    #pragma unroll
    for (int it = 0; it < 2; it++) {
        const int trow = wid * 32 + it * 16 + rl;   // tile-local 0..127
        int gr = bm + trow; if (gr > M - 1) gr = M - 1;
        int arow;
        if (MODE == 1) { int b = gr / Lo; int l = gr - b * Lo; arow = b * Li + l; }
        else arow = gr;
        aph[it] = Ahi + (size_t)arow * lda;
        const int col = bn + trow;                  // N % 128 == 0 -> in range
        wph[it] = Whi + (size_t)col * K;
        wpl[it] = Wlo + (size_t)col * K;
    }

    // exactly 6 global_load_lds per wave per stage (vmcnt cadence relies on it)
    auto stage = [&](int buf, int sstep) {
        const int k0 = sstep << 5;
        #pragma unroll
        for (int it = 0; it < 2; it++) {
            const int lbase = wid * 32 + it * 16;
            // A (or ts tail): condition uniform per step since kbound%32==0
            const f16* sh;
            if (MODE == 0 || k0 < kbound) sh = aph[it] + (k0 + kofs);
            else                          sh = tsrow + (k0 - kbound) + kofs;
            gld_lds16(sh, &sm[buf][0][lbase][0] + (size_t)lane * 8);
            // W hi/lo with per-lane tail clamp (A is 0/ts-0 at clamped k)
            int kw = k0 + kofs; if (kw > K - 8) kw = K - 8;
            gld_lds16(wph[it] + kw, &sm[buf][1][lbase][0] + (size_t)lane * 8);
            gld_lds16(wpl[it] + kw, &sm[buf][2][lbase][0] + (size_t)lane * 8);
        }
    };

    floatx4 acc1[4][4] = {};
    floatx4 acc2[4][4] = {};

    const int nst = Kpad >> 5;
    const int sps = (nst + ksplit - 1) / ksplit;
    const int s0  = kz * sps;
    int s1 = s0 + sps; if (s1 > nst) s1 = nst;

    const int kc  = lane >> 4;
    const int fr  = lane & 15;
    const int wr  = (wid >> 1) * 64;
    const int wc  = (wid & 1) * 64;
    const int ksw = ((kc ^ (fr & 3)) << 3);      // read-side swizzled k slot

    if (s0 < s1) {
        const int n = s1 - s0;
        stage(0, s0);
        stage(1, s0 + ((n > 1) ? 1 : 0));
        for (int j = 0; j < n; j++) {
            asm volatile("s_waitcnt vmcnt(6)" ::: "memory");
            asm volatile("s_barrier" ::: "memory");
            {
                int jt = j + 2; if (jt > n - 1) jt = n - 1;
                stage((j + 2) % 3, s0 + jt);
            }
            const int buf = j % 3;
            half8 ah[4], wh[4], wl[4];
            #pragma unroll
            for (int m = 0; m < 4; m++)
                ah[m] = *(const half8*)&sm[buf][0][wr + m * 16 + fr][ksw];
            #pragma unroll
            for (int nn = 0; nn < 4; nn++) {
                wh[nn] = *(const half8*)&sm[buf][1][wc + nn * 16 + fr][ksw];
                wl[nn] = *(const half8*)&sm[buf][2][wc + nn * 16 + fr][ksw];
            }
            #pragma unroll
            for (int m = 0; m < 4; m++)
                #pragma unroll
                for (int nn = 0; nn < 4; nn++) {
                    acc1[m][nn] = __builtin_amdgcn_mfma_f32_16x16x32_f16(ah[m], wh[nn], acc1[m][nn], 0, 0, 0);
                    acc2[m][nn] = __builtin_amdgcn_mfma_f32_16x16x32_f16(ah[m], wl[nn], acc2[m][nn], 0, 0, 0);
                }
        }
        asm volatile("s_waitcnt vmcnt(0)" ::: "memory");
    }

    // epilogue: C/D frag layout col = lane&15, row = (lane>>4)*4 + j
    const int q4 = (lane >> 4) * 4;
    const size_t MN = (size_t)M * N;
    #pragma unroll
    for (int nn = 0; nn < 4; nn++) {
        const int gcol = bn + wc + nn * 16 + fr;
        const float bv = (OUT == 3) ? 0.0f : bias[gcol];
        #pragma unroll
        for (int m = 0; m < 4; m++) {
            #pragma unroll
            for (int j = 0; j < 4; j++) {
                const int grow = bm + wr + m * 16 + q4 + j;
                if (grow < M) {
                    float v = acc1[m][nn][j] + acc2[m][nn][j] * LO_ISC + bv;
                    const size_t o = (size_t)grow * N + gcol;
                    if (OUT == 3) {
                        Pf[(size_t)kz * MN + o] = v;
                    } else if (OUT == 2) {
                        Cf[o] = v;
                    } else {
                        Chi[o] = (f16)fmaxf(v, 0.0f);
                    }
                }
            }
        }
    }
}

// ------- sum-of-slices + bias -> LayerNorm -> ReLU -> f16 store -------------
// block = Wd/8 threads (128 or 192). dual: bias += (row&1)*1024 (dec reshape).
__global__ void ln_pf(
    const float* __restrict__ P, size_t MN, int ksplit,
    const float* __restrict__ bias, int dual,
    const float* __restrict__ gw, const float* __restrict__ bw,
    f16* __restrict__ oh, int Wd)
{
    const int row = blockIdx.x;
    const size_t base = (size_t)row * Wd;
    const int i8 = threadIdx.x * 8;
    const float* bp = bias + (dual ? ((row & 1) << 10) : 0);

    float v[8];
    {
        const float4 a0 = *(const float4*)(P + base + i8);
        const float4 a1 = *(const float4*)(P + base + i8 + 4);
        v[0]=a0.x; v[1]=a0.y; v[2]=a0.z; v[3]=a0.w;
        v[4]=a1.x; v[5]=a1.y; v[6]=a1.z; v[7]=a1.w;
    }
    for (int z = 1; z < ksplit; z++) {
        const float* Pz = P + (size_t)z * MN + base + i8;
        const float4 c0 = *(const float4*)(Pz);
        const float4 c1 = *(const float4*)(Pz + 4);
        v[0]+=c0.x; v[1]+=c0.y; v[2]+=c0.z; v[3]+=c0.w;
        v[4]+=c1.x; v[5]+=c1.y; v[6]+=c1.z; v[7]+=c1.w;
    }
    float s = 0.f, s2 = 0.f;
    #pragma unroll
    for (int k = 0; k < 8; k++) {
        v[k] += bp[i8 + k];
        s += v[k]; s2 += v[k] * v[k];
    }
    #pragma unroll
    for (int o = 1; o < 64; o <<= 1) { s += __shfl_xor(s, o); s2 += __shfl_xor(s2, o); }
    __shared__ float red[2][4];
    const int nw = blockDim.x >> 6;
    if ((threadIdx.x & 63) == 0) { red[0][threadIdx.x >> 6] = s; red[1][threadIdx.x >> 6] = s2; }
    __syncthreads();
    s = 0.f; s2 = 0.f;
    for (int w = 0; w < nw; w++) { s += red[0][w]; s2 += red[1][w]; }
    const float inv = 1.0f / (float)Wd;
    const float mean = s * inv;
    const float rstd = rsqrtf(s2 * inv - mean * mean + 1e-5f);
    const float4 g0 = *(const float4*)(gw + i8), g1 = *(const float4*)(gw + i8 + 4);
    const float4 b0 = *(const float4*)(bw + i8), b1 = *(const float4*)(bw + i8 + 4);
    const float gg[8] = {g0.x, g0.y, g0.z, g0.w, g1.x, g1.y, g1.z, g1.w};
    const float bb[8] = {b0.x, b0.y, b0.z, b0.w, b1.x, b1.y, b1.z, b1.w};
    half8 ho;
    #pragma unroll
    for (int k = 0; k < 8; k++)
        ho[k] = (f16)fmaxf((v[k] - mean) * rstd * gg[k] + bb[k], 0.0f);
    *(half8*)(oh + base + i8) = ho;
}

// ----- decode combine from f32 partial G (+bias) -> LN -> ReLU -> f16 -------
// P slices hold G[Mc=nb*Liv rows][2048]; output rows nb*(Liv+1) x 1024.
__global__ void comb_pf(
    const float* __restrict__ P, size_t MN, int ksplit,
    const float* __restrict__ bias,   // dec_b2 [2048]
    const float* __restrict__ gw, const float* __restrict__ bw,
    f16* __restrict__ oh, int Liv)
{
    const int row = blockIdx.x;
    const int Lp = Liv + 1;
    const int b = row / Lp, j = row - b * Lp;
    const int i8 = threadIdx.x * 8;

    auto sum8 = [&](size_t off, float* acc) {
        const float4 a0 = *(const float4*)(P + off);
        const float4 a1 = *(const float4*)(P + off + 4);
        acc[0]=a0.x; acc[1]=a0.y; acc[2]=a0.z; acc[3]=a0.w;
        acc[4]=a1.x; acc[5]=a1.y; acc[6]=a1.z; acc[7]=a1.w;
        for (int z = 1; z < ksplit; z++) {
            const float* Pz = P + (size_t)z * MN + off;
            const float4 c0 = *(const float4*)(Pz);
            const float4 c1 = *(const float4*)(Pz + 4);
            acc[0]+=c0.x; acc[1]+=c0.y; acc[2]+=c0.z; acc[3]+=c0.w;
            acc[4]+=c1.x; acc[5]+=c1.y; acc[6]+=c1.z; acc[7]+=c1.w;
        }
    };

    float v[8];
    if (j == 0) {
        sum8((size_t)(b * Liv) * 2048 + i8, v);
        #pragma unroll
        for (int k = 0; k < 8; k++) v[k] += bias[i8 + k];
    } else if (j == Liv) {
        sum8((size_t)(b * Liv + Liv - 1) * 2048 + 1024 + i8, v);
        #pragma unroll
        for (int k = 0; k < 8; k++) v[k] += bias[1024 + i8 + k];
    } else {
        float u[8];
        sum8((size_t)(b * Liv + j - 1) * 2048 + 1024 + i8, v);
        sum8((size_t)(b * Liv + j) * 2048 + i8, u);
        #pragma unroll
        for (int k = 0; k < 8; k++)
            v[k] = 0.5f * ((v[k] + bias[1024 + i8 + k]) + (u[k] + bias[i8 + k]));
    }
    float s = 0.f, s2 = 0.f;
    #pragma unroll
    for (int k = 0; k < 8; k++) { s += v[k]; s2 += v[k] * v[k]; }
    #pragma unroll
    for (int o = 1; o < 64; o <<= 1) { s += __shfl_xor(s, o); s2 += __shfl_xor(s2, o); }
    __shared__ float red[2][2];
    if ((threadIdx.x & 63) == 0) { red[0][threadIdx.x >> 6] = s; red[1][threadIdx.x >> 6] = s2; }
    __syncthreads();
    s = red[0][0] + red[0][1]; s2 = red[1][0] + red[1][1];
    const float mean = s * 9.765625e-4f;
    const float rstd = rsqrtf(s2 * 9.765625e-4f - mean * mean + 1e-5f);
    const float4 g0 = *(const float4*)(gw + i8), g1 = *(const float4*)(gw + i8 + 4);
    const float4 b0 = *(const float4*)(bw + i8), b1 = *(const float4*)(bw + i8 + 4);
    const float gg[8] = {g0.x, g0.y, g0.z, g0.w, g1.x, g1.y, g1.z, g1.w};
    const float bb[8] = {b0.x, b0.y, b0.z, b0.w, b1.x, b1.y, b1.z, b1.w};
    const size_t ob = (size_t)row * 1024 + i8;
    half8 ho;
    #pragma unroll
    for (int k = 0; k < 8; k++)
        ho[k] = (f16)fmaxf((v[k] - mean) * rstd * gg[k] + bb[k], 0.0f);
    *(half8*)(oh + ob) = ho;
}

// ---------------- weight transpose + split: W[K][N] -> Wt[N][K] -------------
__global__ __launch_bounds__(256) void wt_split_k(
    const float* __restrict__ W, f16* __restrict__ Th, f16* __restrict__ Tl,
    int K, int N)
{
    __shared__ float t[64][65];
    const int k0 = blockIdx.x * 64, n0 = blockIdx.y * 64;
    {
        const int j = threadIdx.x & 63, i0 = (threadIdx.x >> 6) * 16;
        for (int ii = 0; ii < 16; ii++) {
            int k = k0 + i0 + ii;
            t[i0 + ii][j] = (k < K) ? W[(size_t)k * N + n0 + j] : 0.f;
        }
    }
    __syncthreads();
    const int i = threadIdx.x & 63, j0 = (threadIdx.x >> 6) * 16;
    const int k = k0 + i;
    if (k < K) {
        for (int jj = 0; jj < 16; jj++) {
            float v = t[i][j0 + jj];
            f16 h = (f16)v;
            const size_t o = (size_t)(n0 + j0 + jj) * K + k;
            Th[o] = h;
            Tl[o] = (f16)((v - (float)h) * LO_SC);
        }
    }
}

// --------------------------- misc small kernels -----------------------------
__global__ void split_x_v(const float* __restrict__ x, f16* __restrict__ h, int n8) {
    int i = blockIdx.x * 256 + threadIdx.x;
    if (i >= n8) return;
    const int i8 = i * 8;
    const float4 f0 = *(const float4*)(x + i8), f1 = *(const float4*)(x + i8 + 4);
    const float vv[8] = {f0.x, f0.y, f0.z, f0.w, f1.x, f1.y, f1.z, f1.w};
    half8 ho;
    #pragma unroll
    for (int k = 0; k < 8; k++) ho[k] = (f16)vv[k];
    *(half8*)(h + i8) = ho;
}

__global__ void ts_init_k(f16* __restrict__ ts) {
    int e = blockIdx.x * 256 + threadIdx.x;
    if (e < 2048) {
        int rc = e >> 5, c = e & 31;
        float v = 0.f;
        if (rc >= 1) {
            int idx = (rc == 1) ? 1 : (rc == 2) ? 2 : (rc <= 4) ? 3 : ((rc + 10) / 3 - 1);
            if (c == 0) v = (float)rc;
            else if (c == idx) v = 1.f;
        }
        ts[e] = (f16)v;
    }
}

// ------------------------------ orchestration -------------------------------
extern "C" void kernel_launch(void* const* d_in, const int* in_sizes, int n_in,
                              void* d_out, int out_size, void* d_ws, size_t ws_size,
                              hipStream_t stream)
{
    const float* xin    = (const float*)d_in[0];
    const float* se_w1  = (const float*)d_in[1];
    const float* se_b1  = (const float*)d_in[2];
    const float* se_w2  = (const float*)d_in[3];
    const float* se_b2  = (const float*)d_in[4];
    const float* enc_w1 = (const float*)d_in[5];
    const float* enc_b1 = (const float*)d_in[6];
    const float* enc_g1 = (const float*)d_in[7];
    const float* enc_bb1= (const float*)d_in[8];
    const float* enc_w2 = (const float*)d_in[9];
    const float* enc_b2 = (const float*)d_in[10];
    const float* enc_g2 = (const float*)d_in[11];
    const float* enc_bb2= (const float*)d_in[12];
    const float* dec_w1 = (const float*)d_in[13];
    const float* dec_b1 = (const float*)d_in[14];
    const float* dec_g1 = (const float*)d_in[15];
    const float* dec_bb1= (const float*)d_in[16];
    const float* dec_w2 = (const float*)d_in[17];
    const float* dec_b2 = (const float*)d_in[18];
    const float* d2_g   = (const float*)d_in[19];
    const float* d2_b   = (const float*)d_in[20];
    const float* de_w1  = (const float*)d_in[21];
    const float* de_b1  = (const float*)d_in[22];
    const float* de_w2  = (const float*)d_in[23];
    const float* de_b2  = (const float*)d_in[24];

    // ------------- workspace layout (f16 units), tail-carved WR -------------
    const size_t ws_f16 = ws_size / 2;
    f16* ws = (f16*)d_ws;
    f16* Xh = ws;                                  // 4,194,304 (64*64*1024)
    f16* Hh = Xh + 4194304;                        // 6,193,152 (4032*1536)
    f16* WR = ws + (ws_f16 - 9512960);             // 9,510,912 + TS 2048
    f16* TS = WR + 9510912;
    float* PF = (float*)(Hh + 6193152);
    const long long pcap_ll = ((long long)ws_f16 - 9512960ll - 4194304ll - 6193152ll) / 2;
    const size_t pcap = (pcap_ll > 0) ? (size_t)pcap_ll : 0;
    const bool dec_unchunk = pcap >= 8257536ull;   // 4032x2048 f32 G-slice

    ts_init_k<<<8, 256, 0, stream>>>(TS);

    auto wt = [&](const float* W, int K, int N, f16* Th, f16* Tl) {
        wt_split_k<<<dim3((K + 63) / 64, N / 64), 256, 0, stream>>>(W, Th, Tl, K, N);
    };
    auto pick_ks = [&](int natural, int nst, size_t MN) {
        int ks = (natural >= 448) ? 1 : (448 + natural - 1) / natural;
        if (ks > 8) ks = 8;
        if (ks > nst) ks = nst;
        while (ks > 1 && (size_t)ks * MN > pcap) ks--;
        return ks;
    };

    #define GEMM(MODE, OUT, Ah, lda, Wh, Wl, bias, Ch, Cf, Pfp, ks, M, N, K, Kpad, kb, Lo, Li, tsr) \
        do { \
            const int gx_ = (N) / 128, gy_ = ((M) + 127) / 128;                \
            const int nwg_ = gx_ * gy_ * (ks);                                 \
            gemm_s2<MODE, OUT><<<nwg_, 256, 0, stream>>>(                      \
                Ah, lda, Wh, Wl, bias, Ch, Cf, Pfp, (ks),                      \
                M, N, K, Kpad, kb, Lo, Li, tsr, gy_, nwg_ >> 3, nwg_ & 7);     \
        } while (0)

    // ---- scale_embedding (scratch inside PF region) ----
    {
        f16* W1h = WR;            f16* W1l = W1h + 163840;
        f16* W2h = W1l + 163840;  f16* W2l = W2h + 655360;
        wt(se_w1, 256, 640, W1h, W1l);
        wt(se_w2, 640, 1024, W2h, W2l);
        f16* Sh  = (f16*)PF;               // 1,048,576
        f16* H1h = Sh + 1048576;           // 2,621,440 (4096x640)
        split_x_v<<<512, 256, 0, stream>>>(xin, Sh, 131072);
        GEMM(0, 1, Sh, 256, W1h, W1l, se_b1, H1h, (float*)0, (float*)0, 1,
             4096, 640, 256, 256, 256, 0, 0, TS);
        GEMM(0, 1, H1h, 640, W2h, W2l, se_b2, Xh, (float*)0, (float*)0, 1,
             4096, 1024, 640, 640, 640, 0, 0, TS);
    }

    // ---- encode ----
    {
        f16* E1h = WR;             f16* E1l = E1h + 3182592;
        f16* E2h = E1l + 3182592;  f16* E2l = E2h + 1572864;
        wt(enc_w1, 2072, 1536, E1h, E1l);
        wt(enc_w2, 1536, 1024, E2h, E2l);
        for (int rc = 1; rc <= 63; rc++) {
            const int Lo = 64 - rc, Li = Lo + 1, Mc = 64 * Lo;
            const int gy = (Mc + 127) / 128;
            const int k1 = pick_ks(12 * gy, 65, (size_t)Mc * 1536);
            GEMM(1, 3, Xh, 1024, E1h, E1l, enc_b1, (f16*)0, (float*)0,
                 PF, k1, Mc, 1536, 2072, 2080, 2048, Lo, Li, TS + rc * 32);
            ln_pf<<<Mc, 192, 0, stream>>>(PF, (size_t)Mc * 1536, k1, enc_b1, 0,
                                          enc_g1, enc_bb1, Hh, 1536);
            const int k2 = pick_ks(8 * gy, 48, (size_t)Mc * 1024);
            GEMM(0, 3, Hh, 1536, E2h, E2l, enc_b2, (f16*)0, (float*)0,
                 PF, k2, Mc, 1024, 1536, 1536, 1536, 0, 0, TS);
            ln_pf<<<Mc, 128, 0, stream>>>(PF, (size_t)Mc * 1024, k2, enc_b2, 0,
                                          enc_g2, enc_bb2, Xh, 1024);
        }
    }

    // ---- decode ----
    {
        f16* D1h = WR;             f16* D1l = D1h + 1609728;
        f16* D2h = D1l + 1609728;  f16* D2l = D2h + 3145728;
        wt(dec_w1, 1048, 1536, D1h, D1l);
        wt(dec_w2, 1536, 2048, D2h, D2l);

        // first step: [64,1024] -> [64,2048] -> LN over [128,1024] view
        {
            const int k1 = pick_ks(12, 33, (size_t)64 * 1536);
            GEMM(2, 3, Xh, 1024, D1h, D1l, dec_b1, (f16*)0, (float*)0,
                 PF, k1, 64, 1536, 1048, 1056, 1024, 0, 0, TS + 63 * 32);
            ln_pf<<<64, 192, 0, stream>>>(PF, (size_t)64 * 1536, k1, dec_b1, 0,
                                          dec_g1, dec_bb1, Hh, 1536);
            const int k2 = pick_ks(16, 48, (size_t)64 * 2048);
            GEMM(0, 3, Hh, 1536, D2h, D2l, dec_b2, (f16*)0, (float*)0,
                 PF, k2, 64, 2048, 1536, 1536, 1536, 0, 0, TS);
            // 64x2048 flat == 128x1024 flat; dual-bias by row parity
            ln_pf<<<128, 128, 0, stream>>>(PF, (size_t)64 * 2048, k2, dec_b2, 1,
                                           d2_g, d2_b, Xh, 1024);
        }

        for (int rc = 62; rc >= 1; rc--) {
            const int Li = 64 - rc;
            const int nch = (!dec_unchunk && 64 * Li > 2016) ? 2 : 1, nb = 64 / nch;
            for (int c = nch - 1; c >= 0; c--) {        // high batches first
                const int b0 = c * nb, Mc = nb * Li;
                const size_t ai = (size_t)b0 * Li * 1024;
                const size_t oi = (size_t)b0 * (Li + 1) * 1024;
                const int gy = (Mc + 127) / 128;
                const int k1 = pick_ks(12 * gy, 33, (size_t)Mc * 1536);
                GEMM(2, 3, Xh + ai, 1024, D1h, D1l, dec_b1, (f16*)0, (float*)0,
                     PF, k1, Mc, 1536, 1048, 1056, 1024, 0, 0, TS + rc * 32);
                ln_pf<<<Mc, 192, 0, stream>>>(PF, (size_t)Mc * 1536, k1, dec_b1, 0,
                                              dec_g1, dec_bb1, Hh, 1536);
                const int k2 = pick_ks(16 * gy, 48, (size_t)Mc * 2048);
                GEMM(0, 3, Hh, 1536, D2h, D2l, dec_b2, (f16*)0, (float*)0,
                     PF, k2, Mc, 2048, 1536, 1536, 1536, 0, 0, TS);
                comb_pf<<<nb * (Li + 1), 128, 0, stream>>>(
                    PF, (size_t)Mc * 2048, k2, dec_b2, d2_g, d2_b,
                    Xh + oi, Li);
            }
        }
    }

    // ---- descale_embedding ----
    {
        f16* W1h = WR;            f16* W1l = W1h + 655360;
        f16* W2h = W1l + 655360;  f16* W2l = W2h + 163840;
        wt(de_w1, 1024, 640, W1h, W1l);
        wt(de_w2, 640, 256, W2h, W2l);
        f16* H1h = (f16*)PF;               // 2,621,440 (4096x640)
        GEMM(0, 1, Xh, 1024, W1h, W1l, de_b1, H1h, (float*)0, (float*)0, 1,
             4096, 640, 1024, 1024, 1024, 0, 0, TS);
        GEMM(0, 2, H1h, 640, W2h, W2l, de_b2, (f16*)0, (float*)d_out, (float*)0, 1,
             4096, 256, 640, 640, 640, 0, 0, TS);
    }
    #undef GEMM
}

// Round 14
// 10077.661 us; speedup vs baseline: 1.8799x; 1.0177x over previous
//
#include <hip/hip_runtime.h>

// ---------------------------------------------------------------------------
// RAE forward, 2-product split-f16 MFMA GEMMs + deterministic split-K.
// Weights: W ~= Wh + Wl*2^-12 (f16 pair). Activations: single f16.
//   C = A@W ~= A@Wh + (A@Wl)*2^-12   (2 MFMA products)
// GEMM: 128x128 tile, 4 waves, A+W via global_load_lds (contiguous-line
// staging, R13), 3-buffer LDS + counted s_waitcnt vmcnt(6) 2-deep pipeline
// (R12), 2 blocks/CU, split-K into P[kz][M][N] f32 summed in LN pass.
// NEW (R14): swizzle selector sigma(r) = (r>>1)&3 (was r&3). Old selector
// left a 4-way LDS bank conflict on every fragment read (lanes fr=0,4,8,12
// -> same bank); new one gives 2-way (free, m136). Writer permutes k-parts
// within the same 64B row window -> staging still contiguous; bit-identical.
//
// FAILED-EXPERIMENT LEDGER (do not repeat):
//  - A streamed global->VGPR (R5: -27%, R7: -330%)
//  - split-K target 512 / cap 16 (R8: +4% slower) — keep 448 / cap 8
//  - 128x256 tile, 8 waves, 96KB LDS (R9: +12% slower)
//  - counted-vmcnt pipeline alone (R12: +2% — GEMM not load-latency-bound)
// ---------------------------------------------------------------------------

typedef _Float16 f16;
typedef _Float16 half8 __attribute__((ext_vector_type(8)));
typedef float floatx4 __attribute__((ext_vector_type(4)));

#define LO_SC   4096.0f
#define LO_ISC  2.44140625e-4f

__device__ __forceinline__ void gld_lds16(const f16* g, f16* l) {
    __builtin_amdgcn_global_load_lds(
        (const __attribute__((address_space(1))) void*)g,
        (__attribute__((address_space(3))) void*)l, 16, 0, 0);
}

// ----------------------------- GEMM ----------------------------------------
// MODE 0: plain A. MODE 1: enc-cat (row b*Li+l; k>=kbound -> ts table).
// MODE 2: dec-cat (k>=kbound -> ts table).
// OUT 1: bias+relu+f16 store; OUT 2: bias+fp32 store; OUT 3: f32 partial
// slice store (no bias).
template<int MODE, int OUT>
__global__ __launch_bounds__(256, 2) void gemm_s2(
    const f16* __restrict__ Ahi, int lda,
    const f16* __restrict__ Whi, const f16* __restrict__ Wlo,   // [N][K] transposed
    const float* __restrict__ bias,
    f16* __restrict__ Chi, float* __restrict__ Cf,
    float* __restrict__ Pf, int ksplit,
    int M, int N, int K, int Kpad, int kbound, int Lo, int Li,
    const f16* __restrict__ tsrow,
    int gy, int q, int r)
{
    // [buf 0..2][arr: A,Wh,Wl][row/col 0..127][32 k]  -> 72 KiB
    __shared__ __align__(16) f16 sm[3][3][128][32];

    const int tid  = threadIdx.x;
    const int lane = tid & 63;
    const int wid  = tid >> 6;

    // bijective XCD swizzle (m204); rank = (bx*gy + by)*ksplit + kz
    const int bid = blockIdx.x;
    const int xcd = bid & 7, jj = bid >> 3;
    const int rank = (xcd < r) ? xcd * (q + 1) + jj
                               : r * (q + 1) + (xcd - r) * q + jj;
    const int t  = rank / ksplit;
    const int kz = rank - t * ksplit;
    const int bx = t / gy, by = t - bx * gy;
    const int bm = by * 128;
    const int bn = bx * 128;

    // staging geometry: wave wid covers tile rows/cols [wid*32, wid*32+32),
    // slot it covers 16 of them; lane = rl*4 + kp loads the row's 16B at
    // k-part (kp ^ sigma(rl)), sigma(x) = (x>>1)&3  -> 4 consecutive lanes
    // still cover 64B contiguous of one row; read side conflict-free (2-way).
    const int rl   = lane >> 2;
    const int kp   = lane & 3;
    const int kofs = ((kp ^ ((rl >> 1) & 3)) << 3);  // f16 offset within row

    const f16* aph[2];          // A row base (global), no kofs
    const f16* wph[2]; const f16* wpl[2];
    #pragma unroll
    for (int it = 0; it < 2; it++) {
        const int trow = wid * 32 + it * 16 + rl;   // tile-local 0..127
        int gr = bm + trow; if (gr > M - 1) gr = M - 1;
        int arow;
        if (MODE == 1) { int b = gr / Lo; int l = gr - b * Lo; arow = b * Li + l; }
        else arow = gr;
        aph[it] = Ahi + (size_t)arow * lda;
        const int col = bn + trow;                  // N % 128 == 0 -> in range
        wph[it] = Whi + (size_t)col * K;
        wpl[it] = Wlo + (size_t)col * K;
    }

    // exactly 6 global_load_lds per wave per stage (vmcnt cadence relies on it)
    auto stage = [&](int buf, int sstep) {
        const int k0 = sstep << 5;
        #pragma unroll
        for (int it = 0; it < 2; it++) {
            const int lbase = wid * 32 + it * 16;
            // A (or ts tail): condition uniform per step since kbound%32==0
            const f16* sh;
            if (MODE == 0 || k0 < kbound) sh = aph[it] + (k0 + kofs);
            else                          sh = tsrow + (k0 - kbound) + kofs;
            gld_lds16(sh, &sm[buf][0][lbase][0] + (size_t)lane * 8);
            // W hi/lo with per-lane tail clamp (A is 0/ts-0 at clamped k)
            int kw = k0 + kofs; if (kw > K - 8) kw = K - 8;
            gld_lds16(wph[it] + kw, &sm[buf][1][lbase][0] + (size_t)lane * 8);
            gld_lds16(wpl[it] + kw, &sm[buf][2][lbase][0] + (size_t)lane * 8);
        }
    };

    floatx4 acc1[4][4] = {};
    floatx4 acc2[4][4] = {};

    const int nst = Kpad >> 5;
    const int sps = (nst + ksplit - 1) / ksplit;
    const int s0  = kz * sps;
    int s1 = s0 + sps; if (s1 > nst) s1 = nst;

    const int kc  = lane >> 4;
    const int fr  = lane & 15;
    const int wr  = (wid >> 1) * 64;
    const int wc  = (wid & 1) * 64;
    const int ksw = ((kc ^ ((fr >> 1) & 3)) << 3);   // read-side swizzled slot

    if (s0 < s1) {
        const int n = s1 - s0;
        stage(0, s0);
        stage(1, s0 + ((n > 1) ? 1 : 0));
        for (int j = 0; j < n; j++) {
            asm volatile("s_waitcnt vmcnt(6)" ::: "memory");
            asm volatile("s_barrier" ::: "memory");
            {
                int jt = j + 2; if (jt > n - 1) jt = n - 1;
                stage((j + 2) % 3, s0 + jt);
            }
            const int buf = j % 3;
            half8 ah[4], wh[4], wl[4];
            #pragma unroll
            for (int m = 0; m < 4; m++)
                ah[m] = *(const half8*)&sm[buf][0][wr + m * 16 + fr][ksw];
            #pragma unroll
            for (int nn = 0; nn < 4; nn++) {
                wh[nn] = *(const half8*)&sm[buf][1][wc + nn * 16 + fr][ksw];
                wl[nn] = *(const half8*)&sm[buf][2][wc + nn * 16 + fr][ksw];
            }
            #pragma unroll
            for (int m = 0; m < 4; m++)
                #pragma unroll
                for (int nn = 0; nn < 4; nn++) {
                    acc1[m][nn] = __builtin_amdgcn_mfma_f32_16x16x32_f16(ah[m], wh[nn], acc1[m][nn], 0, 0, 0);
                    acc2[m][nn] = __builtin_amdgcn_mfma_f32_16x16x32_f16(ah[m], wl[nn], acc2[m][nn], 0, 0, 0);
                }
        }
        asm volatile("s_waitcnt vmcnt(0)" ::: "memory");
    }

    // epilogue: C/D frag layout col = lane&15, row = (lane>>4)*4 + j
    const int q4 = (lane >> 4) * 4;
    const size_t MN = (size_t)M * N;
    #pragma unroll
    for (int nn = 0; nn < 4; nn++) {
        const int gcol = bn + wc + nn * 16 + fr;
        const float bv = (OUT == 3) ? 0.0f : bias[gcol];
        #pragma unroll
        for (int m = 0; m < 4; m++) {
            #pragma unroll
            for (int j = 0; j < 4; j++) {
                const int grow = bm + wr + m * 16 + q4 + j;
                if (grow < M) {
                    float v = acc1[m][nn][j] + acc2[m][nn][j] * LO_ISC + bv;
                    const size_t o = (size_t)grow * N + gcol;
                    if (OUT == 3) {
                        Pf[(size_t)kz * MN + o] = v;
                    } else if (OUT == 2) {
                        Cf[o] = v;
                    } else {
                        Chi[o] = (f16)fmaxf(v, 0.0f);
                    }
                }
            }
        }
    }
}

// ------- sum-of-slices + bias -> LayerNorm -> ReLU -> f16 store -------------
// block = Wd/8 threads (128 or 192). dual: bias += (row&1)*1024 (dec reshape).
__global__ void ln_pf(
    const float* __restrict__ P, size_t MN, int ksplit,
    const float* __restrict__ bias, int dual,
    const float* __restrict__ gw, const float* __restrict__ bw,
    f16* __restrict__ oh, int Wd)
{
    const int row = blockIdx.x;
    const size_t base = (size_t)row * Wd;
    const int i8 = threadIdx.x * 8;
    const float* bp = bias + (dual ? ((row & 1) << 10) : 0);

    float v[8];
    {
        const float4 a0 = *(const float4*)(P + base + i8);
        const float4 a1 = *(const float4*)(P + base + i8 + 4);
        v[0]=a0.x; v[1]=a0.y; v[2]=a0.z; v[3]=a0.w;
        v[4]=a1.x; v[5]=a1.y; v[6]=a1.z; v[7]=a1.w;
    }
    for (int z = 1; z < ksplit; z++) {
        const float* Pz = P + (size_t)z * MN + base + i8;
        const float4 c0 = *(const float4*)(Pz);
        const float4 c1 = *(const float4*)(Pz + 4);
        v[0]+=c0.x; v[1]+=c0.y; v[2]+=c0.z; v[3]+=c0.w;
        v[4]+=c1.x; v[5]+=c1.y; v[6]+=c1.z; v[7]+=c1.w;
    }
    float s = 0.f, s2 = 0.f;
    #pragma unroll
    for (int k = 0; k < 8; k++) {
        v[k] += bp[i8 + k];
        s += v[k]; s2 += v[k] * v[k];
    }
    #pragma unroll
    for (int o = 1; o < 64; o <<= 1) { s += __shfl_xor(s, o); s2 += __shfl_xor(s2, o); }
    __shared__ float red[2][4];
    const int nw = blockDim.x >> 6;
    if ((threadIdx.x & 63) == 0) { red[0][threadIdx.x >> 6] = s; red[1][threadIdx.x >> 6] = s2; }
    __syncthreads();
    s = 0.f; s2 = 0.f;
    for (int w = 0; w < nw; w++) { s += red[0][w]; s2 += red[1][w]; }
    const float inv = 1.0f / (float)Wd;
    const float mean = s * inv;
    const float rstd = rsqrtf(s2 * inv - mean * mean + 1e-5f);
    const float4 g0 = *(const float4*)(gw + i8), g1 = *(const float4*)(gw + i8 + 4);
    const float4 b0 = *(const float4*)(bw + i8), b1 = *(const float4*)(bw + i8 + 4);
    const float gg[8] = {g0.x, g0.y, g0.z, g0.w, g1.x, g1.y, g1.z, g1.w};
    const float bb[8] = {b0.x, b0.y, b0.z, b0.w, b1.x, b1.y, b1.z, b1.w};
    half8 ho;
    #pragma unroll
    for (int k = 0; k < 8; k++)
        ho[k] = (f16)fmaxf((v[k] - mean) * rstd * gg[k] + bb[k], 0.0f);
    *(half8*)(oh + base + i8) = ho;
}

// ----- decode combine from f32 partial G (+bias) -> LN -> ReLU -> f16 -------
// P slices hold G[Mc=nb*Liv rows][2048]; output rows nb*(Liv+1) x 1024.
__global__ void comb_pf(
    const float* __restrict__ P, size_t MN, int ksplit,
    const float* __restrict__ bias,   // dec_b2 [2048]
    const float* __restrict__ gw, const float* __restrict__ bw,
    f16* __restrict__ oh, int Liv)
{
    const int row = blockIdx.x;
    const int Lp = Liv + 1;
    const int b = row / Lp, j = row - b * Lp;
    const int i8 = threadIdx.x * 8;

    auto sum8 = [&](size_t off, float* acc) {
        const float4 a0 = *(const float4*)(P + off);
        const float4 a1 = *(const float4*)(P + off + 4);
        acc[0]=a0.x; acc[1]=a0.y; acc[2]=a0.z; acc[3]=a0.w;
        acc[4]=a1.x; acc[5]=a1.y; acc[6]=a1.z; acc[7]=a1.w;
        for (int z = 1; z < ksplit; z++) {
            const float* Pz = P + (size_t)z * MN + off;
            const float4 c0 = *(const float4*)(Pz);
            const float4 c1 = *(const float4*)(Pz + 4);
            acc[0]+=c0.x; acc[1]+=c0.y; acc[2]+=c0.z; acc[3]+=c0.w;
            acc[4]+=c1.x; acc[5]+=c1.y; acc[6]+=c1.z; acc[7]+=c1.w;
        }
    };

    float v[8];
    if (j == 0) {
        sum8((size_t)(b * Liv) * 2048 + i8, v);
        #pragma unroll
        for (int k = 0; k < 8; k++) v[k] += bias[i8 + k];
    } else if (j == Liv) {
        sum8((size_t)(b * Liv + Liv - 1) * 2048 + 1024 + i8, v);
        #pragma unroll
        for (int k = 0; k < 8; k++) v[k] += bias[1024 + i8 + k];
    } else {
        float u[8];
        sum8((size_t)(b * Liv + j - 1) * 2048 + 1024 + i8, v);
        sum8((size_t)(b * Liv + j) * 2048 + i8, u);
        #pragma unroll
        for (int k = 0; k < 8; k++)
            v[k] = 0.5f * ((v[k] + bias[1024 + i8 + k]) + (u[k] + bias[i8 + k]));
    }
    float s = 0.f, s2 = 0.f;
    #pragma unroll
    for (int k = 0; k < 8; k++) { s += v[k]; s2 += v[k] * v[k]; }
    #pragma unroll
    for (int o = 1; o < 64; o <<= 1) { s += __shfl_xor(s, o); s2 += __shfl_xor(s2, o); }
    __shared__ float red[2][2];
    if ((threadIdx.x & 63) == 0) { red[0][threadIdx.x >> 6] = s; red[1][threadIdx.x >> 6] = s2; }
    __syncthreads();
    s = red[0][0] + red[0][1]; s2 = red[1][0] + red[1][1];
    const float mean = s * 9.765625e-4f;
    const float rstd = rsqrtf(s2 * 9.765625e-4f - mean * mean + 1e-5f);
    const float4 g0 = *(const float4*)(gw + i8), g1 = *(const float4*)(gw + i8 + 4);
    const float4 b0 = *(const float4*)(bw + i8), b1 = *(const float4*)(bw + i8 + 4);
    const float gg[8] = {g0.x, g0.y, g0.z, g0.w, g1.x, g1.y, g1.z, g1.w};
    const float bb[8] = {b0.x, b0.y, b0.z, b0.w, b1.x, b1.y, b1.z, b1.w};
    const size_t ob = (size_t)row * 1024 + i8;
    half8 ho;
    #pragma unroll
    for (int k = 0; k < 8; k++)
        ho[k] = (f16)fmaxf((v[k] - mean) * rstd * gg[k] + bb[k], 0.0f);
    *(half8*)(oh + ob) = ho;
}

// ---------------- weight transpose + split: W[K][N] -> Wt[N][K] -------------
__global__ __launch_bounds__(256) void wt_split_k(
    const float* __restrict__ W, f16* __restrict__ Th, f16* __restrict__ Tl,
    int K, int N)
{
    __shared__ float t[64][65];
    const int k0 = blockIdx.x * 64, n0 = blockIdx.y * 64;
    {
        const int j = threadIdx.x & 63, i0 = (threadIdx.x >> 6) * 16;
        for (int ii = 0; ii < 16; ii++) {
            int k = k0 + i0 + ii;
            t[i0 + ii][j] = (k < K) ? W[(size_t)k * N + n0 + j] : 0.f;
        }
    }
    __syncthreads();
    const int i = threadIdx.x & 63, j0 = (threadIdx.x >> 6) * 16;
    const int k = k0 + i;
    if (k < K) {
        for (int jj = 0; jj < 16; jj++) {
            float v = t[i][j0 + jj];
            f16 h = (f16)v;
            const size_t o = (size_t)(n0 + j0 + jj) * K + k;
            Th[o] = h;
            Tl[o] = (f16)((v - (float)h) * LO_SC);
        }
    }
}

// --------------------------- misc small kernels -----------------------------
__global__ void split_x_v(const float* __restrict__ x, f16* __restrict__ h, int n8) {
    int i = blockIdx.x * 256 + threadIdx.x;
    if (i >= n8) return;
    const int i8 = i * 8;
    const float4 f0 = *(const float4*)(x + i8), f1 = *(const float4*)(x + i8 + 4);
    const float vv[8] = {f0.x, f0.y, f0.z, f0.w, f1.x, f1.y, f1.z, f1.w};
    half8 ho;
    #pragma unroll
    for (int k = 0; k < 8; k++) ho[k] = (f16)vv[k];
    *(half8*)(h + i8) = ho;
}

__global__ void ts_init_k(f16* __restrict__ ts) {
    int e = blockIdx.x * 256 + threadIdx.x;
    if (e < 2048) {
        int rc = e >> 5, c = e & 31;
        float v = 0.f;
        if (rc >= 1) {
            int idx = (rc == 1) ? 1 : (rc == 2) ? 2 : (rc <= 4) ? 3 : ((rc + 10) / 3 - 1);
            if (c == 0) v = (float)rc;
            else if (c == idx) v = 1.f;
        }
        ts[e] = (f16)v;
    }
}

// ------------------------------ orchestration -------------------------------
extern "C" void kernel_launch(void* const* d_in, const int* in_sizes, int n_in,
                              void* d_out, int out_size, void* d_ws, size_t ws_size,
                              hipStream_t stream)
{
    const float* xin    = (const float*)d_in[0];
    const float* se_w1  = (const float*)d_in[1];
    const float* se_b1  = (const float*)d_in[2];
    const float* se_w2  = (const float*)d_in[3];
    const float* se_b2  = (const float*)d_in[4];
    const float* enc_w1 = (const float*)d_in[5];
    const float* enc_b1 = (const float*)d_in[6];
    const float* enc_g1 = (const float*)d_in[7];
    const float* enc_bb1= (const float*)d_in[8];
    const float* enc_w2 = (const float*)d_in[9];
    const float* enc_b2 = (const float*)d_in[10];
    const float* enc_g2 = (const float*)d_in[11];
    const float* enc_bb2= (const float*)d_in[12];
    const float* dec_w1 = (const float*)d_in[13];
    const float* dec_b1 = (const float*)d_in[14];
    const float* dec_g1 = (const float*)d_in[15];
    const float* dec_bb1= (const float*)d_in[16];
    const float* dec_w2 = (const float*)d_in[17];
    const float* dec_b2 = (const float*)d_in[18];
    const float* d2_g   = (const float*)d_in[19];
    const float* d2_b   = (const float*)d_in[20];
    const float* de_w1  = (const float*)d_in[21];
    const float* de_b1  = (const float*)d_in[22];
    const float* de_w2  = (const float*)d_in[23];
    const float* de_b2  = (const float*)d_in[24];

    // ------------- workspace layout (f16 units), tail-carved WR -------------
    const size_t ws_f16 = ws_size / 2;
    f16* ws = (f16*)d_ws;
    f16* Xh = ws;                                  // 4,194,304 (64*64*1024)
    f16* Hh = Xh + 4194304;                        // 6,193,152 (4032*1536)
    f16* WR = ws + (ws_f16 - 9512960);             // 9,510,912 + TS 2048
    f16* TS = WR + 9510912;
    float* PF = (float*)(Hh + 6193152);
    const long long pcap_ll = ((long long)ws_f16 - 9512960ll - 4194304ll - 6193152ll) / 2;
    const size_t pcap = (pcap_ll > 0) ? (size_t)pcap_ll : 0;
    const bool dec_unchunk = pcap >= 8257536ull;   // 4032x2048 f32 G-slice

    ts_init_k<<<8, 256, 0, stream>>>(TS);

    auto wt = [&](const float* W, int K, int N, f16* Th, f16* Tl) {
        wt_split_k<<<dim3((K + 63) / 64, N / 64), 256, 0, stream>>>(W, Th, Tl, K, N);
    };
    auto pick_ks = [&](int natural, int nst, size_t MN) {
        int ks = (natural >= 448) ? 1 : (448 + natural - 1) / natural;
        if (ks > 8) ks = 8;
        if (ks > nst) ks = nst;
        while (ks > 1 && (size_t)ks * MN > pcap) ks--;
        return ks;
    };

    #define GEMM(MODE, OUT, Ah, lda, Wh, Wl, bias, Ch, Cf, Pfp, ks, M, N, K, Kpad, kb, Lo, Li, tsr) \
        do { \
            const int gx_ = (N) / 128, gy_ = ((M) + 127) / 128;                \
            const int nwg_ = gx_ * gy_ * (ks);                                 \
            gemm_s2<MODE, OUT><<<nwg_, 256, 0, stream>>>(                      \
                Ah, lda, Wh, Wl, bias, Ch, Cf, Pfp, (ks),                      \
                M, N, K, Kpad, kb, Lo, Li, tsr, gy_, nwg_ >> 3, nwg_ & 7);     \
        } while (0)

    // ---- scale_embedding (scratch inside PF region) ----
    {
        f16* W1h = WR;            f16* W1l = W1h + 163840;
        f16* W2h = W1l + 163840;  f16* W2l = W2h + 655360;
        wt(se_w1, 256, 640, W1h, W1l);
        wt(se_w2, 640, 1024, W2h, W2l);
        f16* Sh  = (f16*)PF;               // 1,048,576
        f16* H1h = Sh + 1048576;           // 2,621,440 (4096x640)
        split_x_v<<<512, 256, 0, stream>>>(xin, Sh, 131072);
        GEMM(0, 1, Sh, 256, W1h, W1l, se_b1, H1h, (float*)0, (float*)0, 1,
             4096, 640, 256, 256, 256, 0, 0, TS);
        GEMM(0, 1, H1h, 640, W2h, W2l, se_b2, Xh, (float*)0, (float*)0, 1,
             4096, 1024, 640, 640, 640, 0, 0, TS);
    }

    // ---- encode ----
    {
        f16* E1h = WR;             f16* E1l = E1h + 3182592;
        f16* E2h = E1l + 3182592;  f16* E2l = E2h + 1572864;
        wt(enc_w1, 2072, 1536, E1h, E1l);
        wt(enc_w2, 1536, 1024, E2h, E2l);
        for (int rc = 1; rc <= 63; rc++) {
            const int Lo = 64 - rc, Li = Lo + 1, Mc = 64 * Lo;
            const int gy = (Mc + 127) / 128;
            const int k1 = pick_ks(12 * gy, 65, (size_t)Mc * 1536);
            GEMM(1, 3, Xh, 1024, E1h, E1l, enc_b1, (f16*)0, (float*)0,
                 PF, k1, Mc, 1536, 2072, 2080, 2048, Lo, Li, TS + rc * 32);
            ln_pf<<<Mc, 192, 0, stream>>>(PF, (size_t)Mc * 1536, k1, enc_b1, 0,
                                          enc_g1, enc_bb1, Hh, 1536);
            const int k2 = pick_ks(8 * gy, 48, (size_t)Mc * 1024);
            GEMM(0, 3, Hh, 1536, E2h, E2l, enc_b2, (f16*)0, (float*)0,
                 PF, k2, Mc, 1024, 1536, 1536, 1536, 0, 0, TS);
            ln_pf<<<Mc, 128, 0, stream>>>(PF, (size_t)Mc * 1024, k2, enc_b2, 0,
                                          enc_g2, enc_bb2, Xh, 1024);
        }
    }

    // ---- decode ----
    {
        f16* D1h = WR;             f16* D1l = D1h + 1609728;
        f16* D2h = D1l + 1609728;  f16* D2l = D2h + 3145728;
        wt(dec_w1, 1048, 1536, D1h, D1l);
        wt(dec_w2, 1536, 2048, D2h, D2l);

        // first step: [64,1024] -> [64,2048] -> LN over [128,1024] view
        {
            const int k1 = pick_ks(12, 33, (size_t)64 * 1536);
            GEMM(2, 3, Xh, 1024, D1h, D1l, dec_b1, (f16*)0, (float*)0,
                 PF, k1, 64, 1536, 1048, 1056, 1024, 0, 0, TS + 63 * 32);
            ln_pf<<<64, 192, 0, stream>>>(PF, (size_t)64 * 1536, k1, dec_b1, 0,
                                          dec_g1, dec_bb1, Hh, 1536);
            const int k2 = pick_ks(16, 48, (size_t)64 * 2048);
            GEMM(0, 3, Hh, 1536, D2h, D2l, dec_b2, (f16*)0, (float*)0,
                 PF, k2, 64, 2048, 1536, 1536, 1536, 0, 0, TS);
            // 64x2048 flat == 128x1024 flat; dual-bias by row parity
            ln_pf<<<128, 128, 0, stream>>>(PF, (size_t)64 * 2048, k2, dec_b2, 1,
                                           d2_g, d2_b, Xh, 1024);
        }

        for (int rc = 62; rc >= 1; rc--) {
            const int Li = 64 - rc;
            const int nch = (!dec_unchunk && 64 * Li > 2016) ? 2 : 1, nb = 64 / nch;
            for (int c = nch - 1; c >= 0; c--) {        // high batches first
                const int b0 = c * nb, Mc = nb * Li;
                const size_t ai = (size_t)b0 * Li * 1024;
                const size_t oi = (size_t)b0 * (Li + 1) * 1024;
                const int gy = (Mc + 127) / 128;
                const int k1 = pick_ks(12 * gy, 33, (size_t)Mc * 1536);
                GEMM(2, 3, Xh + ai, 1024, D1h, D1l, dec_b1, (f16*)0, (float*)0,
                     PF, k1, Mc, 1536, 1048, 1056, 1024, 0, 0, TS + rc * 32);
                ln_pf<<<Mc, 192, 0, stream>>>(PF, (size_t)Mc * 1536, k1, dec_b1, 0,
                                              dec_g1, dec_bb1, Hh, 1536);
                const int k2 = pick_ks(16 * gy, 48, (size_t)Mc * 2048);
                GEMM(0, 3, Hh, 1536, D2h, D2l, dec_b2, (f16*)0, (float*)0,
                     PF, k2, Mc, 2048, 1536, 1536, 1536, 0, 0, TS);
                comb_pf<<<nb * (Li + 1), 128, 0, stream>>>(
                    PF, (size_t)Mc * 2048, k2, dec_b2, d2_g, d2_b,
                    Xh + oi, Li);
            }
        }
    }

    // ---- descale_embedding ----
    {
        f16* W1h = WR;            f16* W1l = W1h + 655360;
        f16* W2h = W1l + 655360;  f16* W2l = W2h + 163840;
        wt(de_w1, 1024, 640, W1h, W1l);
        wt(de_w2, 640, 256, W2h, W2l);
        f16* H1h = (f16*)PF;               // 2,621,440 (4096x640)
        GEMM(0, 1, Xh, 1024, W1h, W1l, de_b1, H1h, (float*)0, (float*)0, 1,
             4096, 640, 1024, 1024, 1024, 0, 0, TS);
        GEMM(0, 2, H1h, 640, W2h, W2l, de_b2, (f16*)0, (float*)d_out, (float*)0, 1,
             4096, 256, 640, 640, 640, 0, 0, TS);
    }
    #undef GEMM
}

// Round 15
// 7849.412 us; speedup vs baseline: 2.4136x; 1.2839x over previous
//
#include <hip/hip_runtime.h>

// ---------------------------------------------------------------------------
// RAE forward, single-product f16 MFMA GEMMs + deterministic split-K.
// Weights AND activations: single f16 (R15).  C = A@W, f32 accumulate.
// Error budget: R11 proved A-pair->f16 (2^-12/elem) left absmax at the bf16
// compare floor (0.00195); W-f16 adds ~2x that -> expected ~0.004-0.006 vs
// threshold 0.01023. Fallback if exceeded: R14 (2-product, 10.08 ms).
// GEMM: 128x128 tile, 4 waves, A+W via global_load_lds (contiguous-line
// staging R13, sigma(r)=(r>>1)&3 swizzle R14), 3-buffer LDS + counted
// s_waitcnt vmcnt(4) 2-deep pipeline (R12), 48KB LDS -> 3 blocks/CU,
// split-K into P[kz][M][N] f32 summed in LN pass.
//
// FAILED-EXPERIMENT LEDGER (do not repeat):
//  - A streamed global->VGPR (R5: -27%, R7: -330%)
//  - split-K target 512 / cap 16 (R8: +4% slower) — keep 448 / cap 8
//  - 128x256 tile, 8 waves, 96KB LDS (R9: +12% slower)
//  - counted-vmcnt alone (R12: +2%); bank-swizzle fix alone (R14: +1.8%)
// ---------------------------------------------------------------------------

typedef _Float16 f16;
typedef _Float16 half8 __attribute__((ext_vector_type(8)));
typedef float floatx4 __attribute__((ext_vector_type(4)));

__device__ __forceinline__ void gld_lds16(const f16* g, f16* l) {
    __builtin_amdgcn_global_load_lds(
        (const __attribute__((address_space(1))) void*)g,
        (__attribute__((address_space(3))) void*)l, 16, 0, 0);
}

// ----------------------------- GEMM ----------------------------------------
// MODE 0: plain A. MODE 1: enc-cat (row b*Li+l; k>=kbound -> ts table).
// MODE 2: dec-cat (k>=kbound -> ts table).
// OUT 1: bias+relu+f16 store; OUT 2: bias+fp32 store; OUT 3: f32 partial
// slice store (no bias).
template<int MODE, int OUT>
__global__ __launch_bounds__(256, 2) void gemm_s1(
    const f16* __restrict__ Ahi, int lda,
    const f16* __restrict__ Whi,                     // [N][K] transposed, f16
    const float* __restrict__ bias,
    f16* __restrict__ Chi, float* __restrict__ Cf,
    float* __restrict__ Pf, int ksplit,
    int M, int N, int K, int Kpad, int kbound, int Lo, int Li,
    const f16* __restrict__ tsrow,
    int gy, int q, int r)
{
    // [buf 0..2][arr: A,W][row/col 0..127][32 k]  -> 48 KiB
    __shared__ __align__(16) f16 sm[3][2][128][32];

    const int tid  = threadIdx.x;
    const int lane = tid & 63;
    const int wid  = tid >> 6;

    // bijective XCD swizzle (m204); rank = (bx*gy + by)*ksplit + kz
    const int bid = blockIdx.x;
    const int xcd = bid & 7, jj = bid >> 3;
    const int rank = (xcd < r) ? xcd * (q + 1) + jj
                               : r * (q + 1) + (xcd - r) * q + jj;
    const int t  = rank / ksplit;
    const int kz = rank - t * ksplit;
    const int bx = t / gy, by = t - bx * gy;
    const int bm = by * 128;
    const int bn = bx * 128;

    // staging: wave wid covers rows/cols [wid*32, wid*32+32); lane = rl*4+kp
    // loads the row's 16B at k-part (kp ^ ((rl>>1)&3)) -> 4 consecutive lanes
    // = 64B contiguous; read side 2-way bank (free).
    const int rl   = lane >> 2;
    const int kp   = lane & 3;
    const int kofs = ((kp ^ ((rl >> 1) & 3)) << 3);  // f16 offset within row

    const f16* aph[2];
    const f16* wph[2];
    #pragma unroll
    for (int it = 0; it < 2; it++) {
        const int trow = wid * 32 + it * 16 + rl;    // tile-local 0..127
        int gr = bm + trow; if (gr > M - 1) gr = M - 1;
        int arow;
        if (MODE == 1) { int b = gr / Lo; int l = gr - b * Lo; arow = b * Li + l; }
        else arow = gr;
        aph[it] = Ahi + (size_t)arow * lda;
        const int col = bn + trow;                   // N % 128 == 0 -> in range
        wph[it] = Whi + (size_t)col * K;
    }

    // exactly 4 global_load_lds per wave per stage (vmcnt cadence relies on it)
    auto stage = [&](int buf, int sstep) {
        const int k0 = sstep << 5;
        #pragma unroll
        for (int it = 0; it < 2; it++) {
            const int lbase = wid * 32 + it * 16;
            const f16* sh;
            if (MODE == 0 || k0 < kbound) sh = aph[it] + (k0 + kofs);
            else                          sh = tsrow + (k0 - kbound) + kofs;
            gld_lds16(sh, &sm[buf][0][lbase][0] + (size_t)lane * 8);
            int kw = k0 + kofs; if (kw > K - 8) kw = K - 8;   // dup tail; A=0 there
            gld_lds16(wph[it] + kw, &sm[buf][1][lbase][0] + (size_t)lane * 8);
        }
    };

    floatx4 acc1[4][4] = {};

    const int nst = Kpad >> 5;
    const int sps = (nst + ksplit - 1) / ksplit;
    const int s0  = kz * sps;
    int s1 = s0 + sps; if (s1 > nst) s1 = nst;

    const int kc  = lane >> 4;
    const int fr  = lane & 15;
    const int wr  = (wid >> 1) * 64;
    const int wc  = (wid & 1) * 64;
    const int ksw = ((kc ^ ((fr >> 1) & 3)) << 3);   // read-side swizzled slot

    if (s0 < s1) {
        const int n = s1 - s0;
        stage(0, s0);
        stage(1, s0 + ((n > 1) ? 1 : 0));
        for (int j = 0; j < n; j++) {
            asm volatile("s_waitcnt vmcnt(4)" ::: "memory");
            asm volatile("s_barrier" ::: "memory");
            {
                int jt = j + 2; if (jt > n - 1) jt = n - 1;
                stage((j + 2) % 3, s0 + jt);
            }
            const int buf = j % 3;
            half8 ah[4], wh[4];
            #pragma unroll
            for (int m = 0; m < 4; m++)
                ah[m] = *(const half8*)&sm[buf][0][wr + m * 16 + fr][ksw];
            #pragma unroll
            for (int nn = 0; nn < 4; nn++)
                wh[nn] = *(const half8*)&sm[buf][1][wc + nn * 16 + fr][ksw];
            #pragma unroll
            for (int m = 0; m < 4; m++)
                #pragma unroll
                for (int nn = 0; nn < 4; nn++)
                    acc1[m][nn] = __builtin_amdgcn_mfma_f32_16x16x32_f16(ah[m], wh[nn], acc1[m][nn], 0, 0, 0);
        }
        asm volatile("s_waitcnt vmcnt(0)" ::: "memory");
    }

    // epilogue: C/D frag layout col = lane&15, row = (lane>>4)*4 + j
    const int q4 = (lane >> 4) * 4;
    const size_t MN = (size_t)M * N;
    #pragma unroll
    for (int nn = 0; nn < 4; nn++) {
        const int gcol = bn + wc + nn * 16 + fr;
        const float bv = (OUT == 3) ? 0.0f : bias[gcol];
        #pragma unroll
        for (int m = 0; m < 4; m++) {
            #pragma unroll
            for (int j = 0; j < 4; j++) {
                const int grow = bm + wr + m * 16 + q4 + j;
                if (grow < M) {
                    float v = acc1[m][nn][j] + bv;
                    const size_t o = (size_t)grow * N + gcol;
                    if (OUT == 3) {
                        Pf[(size_t)kz * MN + o] = v;
                    } else if (OUT == 2) {
                        Cf[o] = v;
                    } else {
                        Chi[o] = (f16)fmaxf(v, 0.0f);
                    }
                }
            }
        }
    }
}

// ------- sum-of-slices + bias -> LayerNorm -> ReLU -> f16 store -------------
// block = Wd/8 threads (128 or 192). dual: bias += (row&1)*1024 (dec reshape).
__global__ void ln_pf(
    const float* __restrict__ P, size_t MN, int ksplit,
    const float* __restrict__ bias, int dual,
    const float* __restrict__ gw, const float* __restrict__ bw,
    f16* __restrict__ oh, int Wd)
{
    const int row = blockIdx.x;
    const size_t base = (size_t)row * Wd;
    const int i8 = threadIdx.x * 8;
    const float* bp = bias + (dual ? ((row & 1) << 10) : 0);

    float v[8];
    {
        const float4 a0 = *(const float4*)(P + base + i8);
        const float4 a1 = *(const float4*)(P + base + i8 + 4);
        v[0]=a0.x; v[1]=a0.y; v[2]=a0.z; v[3]=a0.w;
        v[4]=a1.x; v[5]=a1.y; v[6]=a1.z; v[7]=a1.w;
    }
    for (int z = 1; z < ksplit; z++) {
        const float* Pz = P + (size_t)z * MN + base + i8;
        const float4 c0 = *(const float4*)(Pz);
        const float4 c1 = *(const float4*)(Pz + 4);
        v[0]+=c0.x; v[1]+=c0.y; v[2]+=c0.z; v[3]+=c0.w;
        v[4]+=c1.x; v[5]+=c1.y; v[6]+=c1.z; v[7]+=c1.w;
    }
    float s = 0.f, s2 = 0.f;
    #pragma unroll
    for (int k = 0; k < 8; k++) {
        v[k] += bp[i8 + k];
        s += v[k]; s2 += v[k] * v[k];
    }
    #pragma unroll
    for (int o = 1; o < 64; o <<= 1) { s += __shfl_xor(s, o); s2 += __shfl_xor(s2, o); }
    __shared__ float red[2][4];
    const int nw = blockDim.x >> 6;
    if ((threadIdx.x & 63) == 0) { red[0][threadIdx.x >> 6] = s; red[1][threadIdx.x >> 6] = s2; }
    __syncthreads();
    s = 0.f; s2 = 0.f;
    for (int w = 0; w < nw; w++) { s += red[0][w]; s2 += red[1][w]; }
    const float inv = 1.0f / (float)Wd;
    const float mean = s * inv;
    const float rstd = rsqrtf(s2 * inv - mean * mean + 1e-5f);
    const float4 g0 = *(const float4*)(gw + i8), g1 = *(const float4*)(gw + i8 + 4);
    const float4 b0 = *(const float4*)(bw + i8), b1 = *(const float4*)(bw + i8 + 4);
    const float gg[8] = {g0.x, g0.y, g0.z, g0.w, g1.x, g1.y, g1.z, g1.w};
    const float bb[8] = {b0.x, b0.y, b0.z, b0.w, b1.x, b1.y, b1.z, b1.w};
    half8 ho;
    #pragma unroll
    for (int k = 0; k < 8; k++)
        ho[k] = (f16)fmaxf((v[k] - mean) * rstd * gg[k] + bb[k], 0.0f);
    *(half8*)(oh + base + i8) = ho;
}

// ----- decode combine from f32 partial G (+bias) -> LN -> ReLU -> f16 -------
// P slices hold G[Mc=nb*Liv rows][2048]; output rows nb*(Liv+1) x 1024.
__global__ void comb_pf(
    const float* __restrict__ P, size_t MN, int ksplit,
    const float* __restrict__ bias,   // dec_b2 [2048]
    const float* __restrict__ gw, const float* __restrict__ bw,
    f16* __restrict__ oh, int Liv)
{
    const int row = blockIdx.x;
    const int Lp = Liv + 1;
    const int b = row / Lp, j = row - b * Lp;
    const int i8 = threadIdx.x * 8;

    auto sum8 = [&](size_t off, float* acc) {
        const float4 a0 = *(const float4*)(P + off);
        const float4 a1 = *(const float4*)(P + off + 4);
        acc[0]=a0.x; acc[1]=a0.y; acc[2]=a0.z; acc[3]=a0.w;
        acc[4]=a1.x; acc[5]=a1.y; acc[6]=a1.z; acc[7]=a1.w;
        for (int z = 1; z < ksplit; z++) {
            const float* Pz = P + (size_t)z * MN + off;
            const float4 c0 = *(const float4*)(Pz);
            const float4 c1 = *(const float4*)(Pz + 4);
            acc[0]+=c0.x; acc[1]+=c0.y; acc[2]+=c0.z; acc[3]+=c0.w;
            acc[4]+=c1.x; acc[5]+=c1.y; acc[6]+=c1.z; acc[7]+=c1.w;
        }
    };

    float v[8];
    if (j == 0) {
        sum8((size_t)(b * Liv) * 2048 + i8, v);
        #pragma unroll
        for (int k = 0; k < 8; k++) v[k] += bias[i8 + k];
    } else if (j == Liv) {
        sum8((size_t)(b * Liv + Liv - 1) * 2048 + 1024 + i8, v);
        #pragma unroll
        for (int k = 0; k < 8; k++) v[k] += bias[1024 + i8 + k];
    } else {
        float u[8];
        sum8((size_t)(b * Liv + j - 1) * 2048 + 1024 + i8, v);
        sum8((size_t)(b * Liv + j) * 2048 + i8, u);
        #pragma unroll
        for (int k = 0; k < 8; k++)
            v[k] = 0.5f * ((v[k] + bias[1024 + i8 + k]) + (u[k] + bias[i8 + k]));
    }
    float s = 0.f, s2 = 0.f;
    #pragma unroll
    for (int k = 0; k < 8; k++) { s += v[k]; s2 += v[k] * v[k]; }
    #pragma unroll
    for (int o = 1; o < 64; o <<= 1) { s += __shfl_xor(s, o); s2 += __shfl_xor(s2, o); }
    __shared__ float red[2][2];
    if ((threadIdx.x & 63) == 0) { red[0][threadIdx.x >> 6] = s; red[1][threadIdx.x >> 6] = s2; }
    __syncthreads();
    s = red[0][0] + red[0][1]; s2 = red[1][0] + red[1][1];
    const float mean = s * 9.765625e-4f;
    const float rstd = rsqrtf(s2 * 9.765625e-4f - mean * mean + 1e-5f);
    const float4 g0 = *(const float4*)(gw + i8), g1 = *(const float4*)(gw + i8 + 4);
    const float4 b0 = *(const float4*)(bw + i8), b1 = *(const float4*)(bw + i8 + 4);
    const float gg[8] = {g0.x, g0.y, g0.z, g0.w, g1.x, g1.y, g1.z, g1.w};
    const float bb[8] = {b0.x, b0.y, b0.z, b0.w, b1.x, b1.y, b1.z, b1.w};
    const size_t ob = (size_t)row * 1024 + i8;
    half8 ho;
    #pragma unroll
    for (int k = 0; k < 8; k++)
        ho[k] = (f16)fmaxf((v[k] - mean) * rstd * gg[k] + bb[k], 0.0f);
    *(half8*)(oh + ob) = ho;
}

// ---------------- weight transpose: W[K][N] -> Wt[N][K] f16 -----------------
__global__ __launch_bounds__(256) void wt_f16_k(
    const float* __restrict__ W, f16* __restrict__ Th, int K, int N)
{
    __shared__ float t[64][65];
    const int k0 = blockIdx.x * 64, n0 = blockIdx.y * 64;
    {
        const int j = threadIdx.x & 63, i0 = (threadIdx.x >> 6) * 16;
        for (int ii = 0; ii < 16; ii++) {
            int k = k0 + i0 + ii;
            t[i0 + ii][j] = (k < K) ? W[(size_t)k * N + n0 + j] : 0.f;
        }
    }
    __syncthreads();
    const int i = threadIdx.x & 63, j0 = (threadIdx.x >> 6) * 16;
    const int k = k0 + i;
    if (k < K) {
        for (int jj = 0; jj < 16; jj++)
            Th[(size_t)(n0 + j0 + jj) * K + k] = (f16)t[i][j0 + jj];
    }
}

// --------------------------- misc small kernels -----------------------------
__global__ void split_x_v(const float* __restrict__ x, f16* __restrict__ h, int n8) {
    int i = blockIdx.x * 256 + threadIdx.x;
    if (i >= n8) return;
    const int i8 = i * 8;
    const float4 f0 = *(const float4*)(x + i8), f1 = *(const float4*)(x + i8 + 4);
    const float vv[8] = {f0.x, f0.y, f0.z, f0.w, f1.x, f1.y, f1.z, f1.w};
    half8 ho;
    #pragma unroll
    for (int k = 0; k < 8; k++) ho[k] = (f16)vv[k];
    *(half8*)(h + i8) = ho;
}

__global__ void ts_init_k(f16* __restrict__ ts) {
    int e = blockIdx.x * 256 + threadIdx.x;
    if (e < 2048) {
        int rc = e >> 5, c = e & 31;
        float v = 0.f;
        if (rc >= 1) {
            int idx = (rc == 1) ? 1 : (rc == 2) ? 2 : (rc <= 4) ? 3 : ((rc + 10) / 3 - 1);
            if (c == 0) v = (float)rc;
            else if (c == idx) v = 1.f;
        }
        ts[e] = (f16)v;
    }
}

// ------------------------------ orchestration -------------------------------
extern "C" void kernel_launch(void* const* d_in, const int* in_sizes, int n_in,
                              void* d_out, int out_size, void* d_ws, size_t ws_size,
                              hipStream_t stream)
{
    const float* xin    = (const float*)d_in[0];
    const float* se_w1  = (const float*)d_in[1];
    const float* se_b1  = (const float*)d_in[2];
    const float* se_w2  = (const float*)d_in[3];
    const float* se_b2  = (const float*)d_in[4];
    const float* enc_w1 = (const float*)d_in[5];
    const float* enc_b1 = (const float*)d_in[6];
    const float* enc_g1 = (const float*)d_in[7];
    const float* enc_bb1= (const float*)d_in[8];
    const float* enc_w2 = (const float*)d_in[9];
    const float* enc_b2 = (const float*)d_in[10];
    const float* enc_g2 = (const float*)d_in[11];
    const float* enc_bb2= (const float*)d_in[12];
    const float* dec_w1 = (const float*)d_in[13];
    const float* dec_b1 = (const float*)d_in[14];
    const float* dec_g1 = (const float*)d_in[15];
    const float* dec_bb1= (const float*)d_in[16];
    const float* dec_w2 = (const float*)d_in[17];
    const float* dec_b2 = (const float*)d_in[18];
    const float* d2_g   = (const float*)d_in[19];
    const float* d2_b   = (const float*)d_in[20];
    const float* de_w1  = (const float*)d_in[21];
    const float* de_b1  = (const float*)d_in[22];
    const float* de_w2  = (const float*)d_in[23];
    const float* de_b2  = (const float*)d_in[24];

    // ------------- workspace layout (f16 units), tail-carved WR -------------
    const size_t ws_f16 = ws_size / 2;
    f16* ws = (f16*)d_ws;
    f16* Xh = ws;                                  // 4,194,304 (64*64*1024)
    f16* Hh = Xh + 4194304;                        // 6,193,152 (4032*1536)
    f16* WR = ws + (ws_f16 - 4757504);             // 4,755,456 + TS 2048
    f16* TS = WR + 4755456;
    float* PF = (float*)(Hh + 6193152);
    const long long pcap_ll = ((long long)ws_f16 - 4757504ll - 4194304ll - 6193152ll) / 2;
    const size_t pcap = (pcap_ll > 0) ? (size_t)pcap_ll : 0;
    const bool dec_unchunk = pcap >= 8257536ull;   // 4032x2048 f32 G-slice

    ts_init_k<<<8, 256, 0, stream>>>(TS);

    auto wt = [&](const float* W, int K, int N, f16* Th) {
        wt_f16_k<<<dim3((K + 63) / 64, N / 64), 256, 0, stream>>>(W, Th, K, N);
    };
    auto pick_ks = [&](int natural, int nst, size_t MN) {
        int ks = (natural >= 448) ? 1 : (448 + natural - 1) / natural;
        if (ks > 8) ks = 8;
        if (ks > nst) ks = nst;
        while (ks > 1 && (size_t)ks * MN > pcap) ks--;
        return ks;
    };

    #define GEMM(MODE, OUT, Ah, lda, Wh, bias, Ch, Cf, Pfp, ks, M, N, K, Kpad, kb, Lo, Li, tsr) \
        do { \
            const int gx_ = (N) / 128, gy_ = ((M) + 127) / 128;                \
            const int nwg_ = gx_ * gy_ * (ks);                                 \
            gemm_s1<MODE, OUT><<<nwg_, 256, 0, stream>>>(                      \
                Ah, lda, Wh, bias, Ch, Cf, Pfp, (ks),                          \
                M, N, K, Kpad, kb, Lo, Li, tsr, gy_, nwg_ >> 3, nwg_ & 7);     \
        } while (0)

    // ---- scale_embedding (scratch inside PF region) ----
    {
        f16* W1h = WR;            f16* W2h = W1h + 163840;   // 655,360
        wt(se_w1, 256, 640, W1h);
        wt(se_w2, 640, 1024, W2h);
        f16* Sh  = (f16*)PF;               // 1,048,576
        f16* H1h = Sh + 1048576;           // 2,621,440 (4096x640)
        split_x_v<<<512, 256, 0, stream>>>(xin, Sh, 131072);
        GEMM(0, 1, Sh, 256, W1h, se_b1, H1h, (float*)0, (float*)0, 1,
             4096, 640, 256, 256, 256, 0, 0, TS);
        GEMM(0, 1, H1h, 640, W2h, se_b2, Xh, (float*)0, (float*)0, 1,
             4096, 1024, 640, 640, 640, 0, 0, TS);
    }

    // ---- encode ----
    {
        f16* E1h = WR;             f16* E2h = E1h + 3182592;  // 1,572,864
        wt(enc_w1, 2072, 1536, E1h);
        wt(enc_w2, 1536, 1024, E2h);
        for (int rc = 1; rc <= 63; rc++) {
            const int Lo = 64 - rc, Li = Lo + 1, Mc = 64 * Lo;
            const int gy = (Mc + 127) / 128;
            const int k1 = pick_ks(12 * gy, 65, (size_t)Mc * 1536);
            GEMM(1, 3, Xh, 1024, E1h, enc_b1, (f16*)0, (float*)0,
                 PF, k1, Mc, 1536, 2072, 2080, 2048, Lo, Li, TS + rc * 32);
            ln_pf<<<Mc, 192, 0, stream>>>(PF, (size_t)Mc * 1536, k1, enc_b1, 0,
                                          enc_g1, enc_bb1, Hh, 1536);
            const int k2 = pick_ks(8 * gy, 48, (size_t)Mc * 1024);
            GEMM(0, 3, Hh, 1536, E2h, enc_b2, (f16*)0, (float*)0,
                 PF, k2, Mc, 1024, 1536, 1536, 1536, 0, 0, TS);
            ln_pf<<<Mc, 128, 0, stream>>>(PF, (size_t)Mc * 1024, k2, enc_b2, 0,
                                          enc_g2, enc_bb2, Xh, 1024);
        }
    }

    // ---- decode ----
    {
        f16* D1h = WR;             f16* D2h = D1h + 1609728;  // 3,145,728
        wt(dec_w1, 1048, 1536, D1h);
        wt(dec_w2, 1536, 2048, D2h);

        // first step: [64,1024] -> [64,2048] -> LN over [128,1024] view
        {
            const int k1 = pick_ks(12, 33, (size_t)64 * 1536);
            GEMM(2, 3, Xh, 1024, D1h, dec_b1, (f16*)0, (float*)0,
                 PF, k1, 64, 1536, 1048, 1056, 1024, 0, 0, TS + 63 * 32);
            ln_pf<<<64, 192, 0, stream>>>(PF, (size_t)64 * 1536, k1, dec_b1, 0,
                                          dec_g1, dec_bb1, Hh, 1536);
            const int k2 = pick_ks(16, 48, (size_t)64 * 2048);
            GEMM(0, 3, Hh, 1536, D2h, dec_b2, (f16*)0, (float*)0,
                 PF, k2, 64, 2048, 1536, 1536, 1536, 0, 0, TS);
            // 64x2048 flat == 128x1024 flat; dual-bias by row parity
            ln_pf<<<128, 128, 0, stream>>>(PF, (size_t)64 * 2048, k2, dec_b2, 1,
                                           d2_g, d2_b, Xh, 1024);
        }

        for (int rc = 62; rc >= 1; rc--) {
            const int Li = 64 - rc;
            const int nch = (!dec_unchunk && 64 * Li > 2016) ? 2 : 1, nb = 64 / nch;
            for (int c = nch - 1; c >= 0; c--) {        // high batches first
                const int b0 = c * nb, Mc = nb * Li;
                const size_t ai = (size_t)b0 * Li * 1024;
                const size_t oi = (size_t)b0 * (Li + 1) * 1024;
                const int gy = (Mc + 127) / 128;
                const int k1 = pick_ks(12 * gy, 33, (size_t)Mc * 1536);
                GEMM(2, 3, Xh + ai, 1024, D1h, dec_b1, (f16*)0, (float*)0,
                     PF, k1, Mc, 1536, 1048, 1056, 1024, 0, 0, TS + rc * 32);
                ln_pf<<<Mc, 192, 0, stream>>>(PF, (size_t)Mc * 1536, k1, dec_b1, 0,
                                              dec_g1, dec_bb1, Hh, 1536);
                const int k2 = pick_ks(16 * gy, 48, (size_t)Mc * 2048);
                GEMM(0, 3, Hh, 1536, D2h, dec_b2, (f16*)0, (float*)0,
                     PF, k2, Mc, 2048, 1536, 1536, 1536, 0, 0, TS);
                comb_pf<<<nb * (Li + 1), 128, 0, stream>>>(
                    PF, (size_t)Mc * 2048, k2, dec_b2, d2_g, d2_b,
                    Xh + oi, Li);
            }
        }
    }

    // ---- descale_embedding ----
    {
        f16* W1h = WR;            f16* W2h = W1h + 655360;   // 163,840
        wt(de_w1, 1024, 640, W1h);
        wt(de_w2, 640, 256, W2h);
        f16* H1h = (f16*)PF;               // 2,621,440 (4096x640)
        GEMM(0, 1, Xh, 1024, W1h, de_b1, H1h, (float*)0, (float*)0, 1,
             4096, 640, 1024, 1024, 1024, 0, 0, TS);
        GEMM(0, 2, H1h, 640, W2h, de_b2, (f16*)0, (float*)d_out, (float*)0, 1,
             4096, 256, 640, 640, 640, 0, 0, TS);
    }
    #undef GEMM
}